// Round 1
// baseline (4075.289 us; speedup 1.0000x reference)
//
#include <hip/hip_runtime.h>
#include <math.h>

// Problem constants
//  B=32, C=2048, H*W=N=288 (== PATCH), Q=16, proto tokens NP=2048
#define BK 16
#define BT 64

static constexpr float SCALE = 0.022097086912079612f; // 2048^-0.5

// ---------------- reduction helpers ----------------
__device__ __forceinline__ float wred_sum(float v){
  #pragma unroll
  for (int o=32;o>0;o>>=1) v += __shfl_down(v,o,64);
  return v;
}
__device__ __forceinline__ float wred_max(float v){
  #pragma unroll
  for (int o=32;o>0;o>>=1) v = fmaxf(v, __shfl_down(v,o,64));
  return v;
}
__device__ __forceinline__ float block_sum(float v, float* red){
  int tid=threadIdx.x, w=tid>>6, l=tid&63, nw=(int)(blockDim.x>>6);
  v = wred_sum(v);
  __syncthreads();
  if (l==0) red[w]=v;
  __syncthreads();
  float r=0.f;
  for (int i=0;i<nw;i++) r += red[i];
  return r;
}
__device__ __forceinline__ float block_max(float v, float* red){
  int tid=threadIdx.x, w=tid>>6, l=tid&63, nw=(int)(blockDim.x>>6);
  v = wred_max(v);
  __syncthreads();
  if (l==0) red[w]=v;
  __syncthreads();
  float r=red[0];
  for (int i=1;i<nw;i++) r = fmaxf(r, red[i]);
  return r;
}

// ---------------- generic GEMMs (fp32, bounds-checked) ----------------
// C = alpha * A * B^T   (A: [M,K] lda, B: [N,K] ldb, C: [M,N] ldc), batched via z.
// biasA: optional per-K vector added to A elements (batch stride sBias).
// browidx: optional row-index gather for B: row r -> B[browidx[r]*ldb + k].
__global__ __launch_bounds__(256) void gemm_nt(
    float* __restrict__ Cm, const float* __restrict__ Am, const float* __restrict__ Bm,
    int M, int N, int K, int lda, int ldb, int ldc,
    long sA, long sB, long sC, float alpha,
    const float* __restrict__ biasA, long sBias,
    const int* __restrict__ browidx, long sBrow)
{
  __shared__ float As[BK][BT+4];
  __shared__ float Bs[BK][BT+4];
  int z = blockIdx.z;
  const float* A = Am + (long)z*sA;
  const float* B = Bm + (long)z*sB;
  float* C = Cm + (long)z*sC;
  const float* bias = biasA ? (biasA + (long)z*sBias) : nullptr;
  const int* brow = browidx ? (browidx + (long)z*sBrow) : nullptr;
  int m0 = blockIdx.y*BT, n0 = blockIdx.x*BT;
  int t = threadIdx.x;
  int lrow = t >> 2;          // 0..63
  int lk4  = (t & 3) * 4;     // 0,4,8,12
  int tm = (t & 15) * 4;
  int tn = (t >> 4) * 4;
  float acc[4][4] = {};
  for (int k0 = 0; k0 < K; k0 += BK) {
    float4 av = make_float4(0.f,0.f,0.f,0.f);
    int am = m0 + lrow;
    if (am < M) {
      av = *(const float4*)(A + (long)am*lda + k0 + lk4);
      if (bias) {
        float4 bv = *(const float4*)(bias + k0 + lk4);
        av.x+=bv.x; av.y+=bv.y; av.z+=bv.z; av.w+=bv.w;
      }
    }
    As[lk4+0][lrow]=av.x; As[lk4+1][lrow]=av.y; As[lk4+2][lrow]=av.z; As[lk4+3][lrow]=av.w;
    float4 bv = make_float4(0.f,0.f,0.f,0.f);
    int bn = n0 + lrow;
    if (bn < N) {
      long roff = brow ? (long)brow[bn]*ldb : (long)bn*ldb;
      bv = *(const float4*)(B + roff + k0 + lk4);
    }
    Bs[lk4+0][lrow]=bv.x; Bs[lk4+1][lrow]=bv.y; Bs[lk4+2][lrow]=bv.z; Bs[lk4+3][lrow]=bv.w;
    __syncthreads();
    #pragma unroll
    for (int kk = 0; kk < BK; ++kk) {
      float4 a = *(const float4*)&As[kk][tm];
      float4 b = *(const float4*)&Bs[kk][tn];
      float aa[4]={a.x,a.y,a.z,a.w}, bb[4]={b.x,b.y,b.z,b.w};
      #pragma unroll
      for (int i=0;i<4;++i)
        #pragma unroll
        for (int j=0;j<4;++j) acc[i][j] += aa[i]*bb[j];
    }
    __syncthreads();
  }
  #pragma unroll
  for (int i=0;i<4;++i){
    int m = m0 + tm + i;
    if (m < M){
      long cro = (long)m*ldc;
      #pragma unroll
      for (int j=0;j<4;++j){
        int n = n0 + tn + j;
        if (n < N) C[cro + n] = alpha*acc[i][j];
      }
    }
  }
}

// C = alpha * A * B  (A: [M,K] lda, B: [K,N] ldb, C: [M,N] ldc), batched via z.
// browidx: optional row gather for B's K rows: B[(browidx[k])*ldb + n].
__global__ __launch_bounds__(256) void gemm_nn(
    float* __restrict__ Cm, const float* __restrict__ Am, const float* __restrict__ Bm,
    int M, int N, int K, int lda, int ldb, int ldc,
    long sA, long sB, long sC, float alpha,
    const int* __restrict__ browidx, long sBrow)
{
  __shared__ float As[BK][BT+4];
  __shared__ float Bs[BK][BT+4];
  int z = blockIdx.z;
  const float* A = Am + (long)z*sA;
  const float* B = Bm + (long)z*sB;
  float* C = Cm + (long)z*sC;
  const int* brow = browidx ? (browidx + (long)z*sBrow) : nullptr;
  int m0 = blockIdx.y*BT, n0 = blockIdx.x*BT;
  int t = threadIdx.x;
  int lrow = t >> 2;          // A: 0..63 (m)
  int lk4  = (t & 3) * 4;
  int kr = t >> 4;            // B: 0..15 (k)
  int nq = (t & 15) * 4;      //    0..60 (n)
  int tm = (t & 15) * 4;
  int tn = (t >> 4) * 4;
  float acc[4][4] = {};
  for (int k0 = 0; k0 < K; k0 += BK) {
    float4 av = make_float4(0.f,0.f,0.f,0.f);
    int am = m0 + lrow;
    if (am < M) av = *(const float4*)(A + (long)am*lda + k0 + lk4);
    As[lk4+0][lrow]=av.x; As[lk4+1][lrow]=av.y; As[lk4+2][lrow]=av.z; As[lk4+3][lrow]=av.w;
    long roff = brow ? (long)brow[k0+kr]*ldb : (long)(k0+kr)*ldb;
    const float* bp = B + roff + n0 + nq;
    if (n0 + nq + 3 < N) {
      float4 bv = *(const float4*)bp;
      Bs[kr][nq+0]=bv.x; Bs[kr][nq+1]=bv.y; Bs[kr][nq+2]=bv.z; Bs[kr][nq+3]=bv.w;
    } else {
      #pragma unroll
      for (int j=0;j<4;++j) Bs[kr][nq+j] = (n0+nq+j < N) ? bp[j] : 0.f;
    }
    __syncthreads();
    #pragma unroll
    for (int kk = 0; kk < BK; ++kk) {
      float4 a = *(const float4*)&As[kk][tm];
      float4 b = *(const float4*)&Bs[kk][tn];
      float aa[4]={a.x,a.y,a.z,a.w}, bb[4]={b.x,b.y,b.z,b.w};
      #pragma unroll
      for (int i=0;i<4;++i)
        #pragma unroll
        for (int j=0;j<4;++j) acc[i][j] += aa[i]*bb[j];
    }
    __syncthreads();
  }
  #pragma unroll
  for (int i=0;i<4;++i){
    int m = m0 + tm + i;
    if (m < M){
      long cro = (long)m*ldc;
      #pragma unroll
      for (int j=0;j<4;++j){
        int n = n0 + tn + j;
        if (n < N) C[cro + n] = alpha*acc[i][j];
      }
    }
  }
}

// ---------------- small kernels ----------------
// x: [32][2048][288] -> xs: [32][288][2048]
__global__ void k_transpose(const float* __restrict__ x, float* __restrict__ xs){
  __shared__ float tile[32][33];
  int b = blockIdx.z;
  int n0 = blockIdx.x*32, c0 = blockIdx.y*32;
  int tx = threadIdx.x, ty = threadIdx.y;
  #pragma unroll
  for (int j=0;j<32;j+=8)
    tile[ty+j][tx] = x[((long)b*2048 + c0+ty+j)*288 + n0+tx];
  __syncthreads();
  #pragma unroll
  for (int j=0;j<32;j+=8)
    xs[((long)b*288 + n0+ty+j)*2048 + c0+tx] = tile[tx][ty+j];
}

// per-row sum/sumsq: mu[r]=sum/cols, m2[r]=sumsq
__global__ __launch_bounds__(256) void k_rowstats(const float* __restrict__ X, long ldx, int cols,
                                                  float* __restrict__ mu, float* __restrict__ m2){
  int r = blockIdx.x;
  const float* row = X + (long)r*ldx;
  float s=0.f, s2=0.f;
  for (int c = threadIdx.x*4; c < cols; c += 1024){
    float4 v = *(const float4*)(row+c);
    s  += v.x+v.y+v.z+v.w;
    s2 += v.x*v.x+v.y*v.y+v.z*v.z+v.w*v.w;
  }
  __shared__ float red[8];
  s  = block_sum(s,  red);
  s2 = block_sum(s2, red);
  if (threadIdx.x==0){ mu[r]=s/(float)cols; m2[r]=s2; }
}

// in-place: S[r][q] = softmax_q( S[r][q] / (|xs_p| * |xs_q|) ), r=(b,p), L=288
__global__ __launch_bounds__(256) void k_softmax_gram(float* __restrict__ S, const float* __restrict__ m2xs){
  int r = blockIdx.x;
  int b = r / 288, p = r % 288;
  float* row = S + (long)r * 288;
  const float* m2 = m2xs + (long)b*288;
  float rp = 1.f / fmaxf(sqrtf(m2[p]), 1e-12f);
  int tid = threadIdx.x;
  __shared__ float red[8];
  float lv[2];
  #pragma unroll
  for (int i=0;i<2;++i){
    int q = tid + i*256;
    lv[i] = (q<288) ? row[q]*rp/fmaxf(sqrtf(m2[q]),1e-12f) : -1e30f;
  }
  float mx = fmaxf(lv[0], lv[1]);
  mx = block_max(mx, red);
  float s = 0.f;
  #pragma unroll
  for (int i=0;i<2;++i){
    int q = tid + i*256;
    float e = (q<288) ? expf(lv[i]-mx) : 0.f;
    lv[i]=e; s+=e;
  }
  s = block_sum(s, red);
  float inv = 1.f/s;
  #pragma unroll
  for (int i=0;i<2;++i){ int q = tid + i*256; if (q<288) row[q]=lv[i]*inv; }
}

// generic in-place row softmax, row length L (<=2048), rows dense with stride L
__global__ __launch_bounds__(256) void k_softmax_plain(float* __restrict__ X, int L){
  int r = blockIdx.x;
  float* row = X + (long)r * L;
  int tid = threadIdx.x;
  __shared__ float red[8];
  float lv[8];
  #pragma unroll
  for (int i=0;i<8;++i){ int q = tid + i*256; lv[i] = (q<L) ? row[q] : -1e30f; }
  float mx = -1e30f;
  #pragma unroll
  for (int i=0;i<8;++i) mx = fmaxf(mx, lv[i]);
  mx = block_max(mx, red);
  float s = 0.f;
  #pragma unroll
  for (int i=0;i<8;++i){ int q = tid + i*256; float e = (q<L)?expf(lv[i]-mx):0.f; lv[i]=e; s+=e; }
  s = block_sum(s, red);
  float inv = 1.f/s;
  #pragma unroll
  for (int i=0;i<8;++i){ int q = tid + i*256; if (q<L) row[q]=lv[i]*inv; }
}

__global__ void k_ln_apply(const float* __restrict__ X, const float* __restrict__ mu,
                           const float* __restrict__ m2, float* __restrict__ Y){
  int r = blockIdx.y; int c = blockIdx.x*256 + threadIdx.x;
  float m = mu[r];
  float v = m2[r]*(1.f/2048.f) - m*m;
  float inv = rsqrtf(v + 1e-5f);
  long idx = (long)r*2048 + c;
  Y[idx] = (X[idx] - m)*inv;
}

__global__ void k_meanx(const float* __restrict__ frel, float* __restrict__ mx){
  int b = blockIdx.y; int c = blockIdx.x*256 + threadIdx.x;
  const float* base = frel + (long)b*16*2048 + c;
  float s=0.f;
  #pragma unroll
  for (int q=0;q<16;++q) s += base[(long)q*2048];
  mx[(long)b*2048 + c] = s * (1.f/16.f);
}

__global__ void k_sigma(const float* __restrict__ pm, const float* __restrict__ mu_p,
                        const float* __restrict__ m2_p, const float* __restrict__ mu_m,
                        const float* __restrict__ m2_m, float* __restrict__ sigma){
  int b = blockIdx.y; int n = blockIdx.x*256 + threadIdx.x;
  float mp = mu_p[n], mm = mu_m[b];
  float vp = m2_p[n]*(1.f/2048.f) - mp*mp;
  float vm = m2_m[b]*(1.f/2048.f) - mm*mm;
  float cov = pm[(long)b*2048+n]*(1.f/2048.f) - mp*mm;
  sigma[(long)b*2048+n] = sqrtf(fmaxf(vp + vm - 2.f*cov, 0.f) + 1e-5f);
}

// X[r][d] -= mu_row[r] * (mu_w[d]*2048)   (LN mean correction through W projection)
__global__ void k_fixrow(float* __restrict__ X, const float* __restrict__ mu_row,
                         const float* __restrict__ mu_w){
  int r = blockIdx.y; int d = blockIdx.x*256 + threadIdx.x;
  X[(long)r*2048 + d] -= mu_row[r] * mu_w[d] * 2048.f;
}

// qm[r] = dot(relq2[r], Mx[b]) , b=r/16
__global__ __launch_bounds__(256) void k_qm(const float* __restrict__ relq2,
                                            const float* __restrict__ Mx, float* __restrict__ qm){
  int r = blockIdx.x; int b = r >> 4;
  const float* a = relq2 + (long)r*2048;
  const float* m = Mx + (long)b*2048;
  float s=0.f;
  for (int c = threadIdx.x*4; c < 2048; c += 1024){
    float4 va=*(const float4*)(a+c), vm=*(const float4*)(m+c);
    s += va.x*vm.x+va.y*vm.y+va.z*vm.z+va.w*vm.w;
  }
  __shared__ float red[8];
  s = block_sum(s, red);
  if (threadIdx.x==0) qm[r]=s;
}

// scores s[n]=scale*(QP[r][n]-qm[r])/sigma[b][n]; softmax; write w=p/sigma in place;
// W1[r]=sum w; Wmu[r]=sum w*mu_p
__global__ __launch_bounds__(256) void k_score2(float* __restrict__ QPw, const float* __restrict__ qm,
                                                const float* __restrict__ sigma, const float* __restrict__ mu_p,
                                                float* __restrict__ W1, float* __restrict__ Wmu, float scale){
  int r = blockIdx.x; int b = r >> 4;
  float* row = QPw + (long)r*2048;
  const float* sg = sigma + (long)b*2048;
  int tid = threadIdx.x;
  __shared__ float red[8];
  float qmr = qm[r];
  float lv[8], ls[8];
  #pragma unroll
  for (int i=0;i<8;++i){
    int n = tid + i*256;
    float sgn = sg[n];
    ls[i] = sgn;
    lv[i] = scale * (row[n] - qmr) / sgn;
  }
  float mx = -1e30f;
  #pragma unroll
  for (int i=0;i<8;++i) mx = fmaxf(mx, lv[i]);
  mx = block_max(mx, red);
  float se=0.f, sw=0.f, swm=0.f;
  #pragma unroll
  for (int i=0;i<8;++i){
    int n = tid + i*256;
    float e = expf(lv[i]-mx);
    lv[i] = e; se += e;
    float wv = e/ls[i];
    sw += wv; swm += wv*mu_p[n];
  }
  se  = block_sum(se,  red);
  sw  = block_sum(sw,  red);
  swm = block_sum(swm, red);
  float inv = 1.f/se;
  #pragma unroll
  for (int i=0;i<8;++i){ int n = tid + i*256; row[n] = lv[i]*inv/ls[i]; }
  if (tid==0){ W1[r]=sw*inv; Wmu[r]=swm*inv; }
}

// f_pro = f_rel + out2 - meanx*W1 - Wmu + mu_m*W1 ; fout = wsm[q]*f_pro
__global__ void k_fpro_final(const float* __restrict__ frel, const float* __restrict__ out2,
                             const float* __restrict__ meanx, const float* __restrict__ mu_m,
                             const float* __restrict__ W1, const float* __restrict__ Wmu,
                             const float* __restrict__ wsm,
                             float* __restrict__ fpro, float* __restrict__ fout){
  int r = blockIdx.y; int c = blockIdx.x*256 + threadIdx.x;
  int b = r >> 4, q = r & 15;
  long idx = (long)r*2048 + c;
  float w1 = W1[r];
  float v = frel[idx] + out2[idx] - meanx[(long)b*2048+c]*w1 - Wmu[r] + mu_m[b]*w1;
  fpro[idx] = v;
  fout[idx] = wsm[q] * v;
}

__global__ void k_camb(const float* __restrict__ cam_table, const int* __restrict__ cam_ids,
                       float* __restrict__ camb){
  int b = blockIdx.y; int c = blockIdx.x*256 + threadIdx.x;
  camb[(long)b*2048 + c] = cam_table[(long)(cam_ids[b]-1)*2048 + c];
}

__global__ void k_wsoft(const float* __restrict__ w, float* __restrict__ wsm){
  if (threadIdx.x==0){
    float mx=-1e30f;
    for (int i=0;i<16;++i) mx=fmaxf(mx,w[i]);
    float e[16], s=0.f;
    for (int i=0;i<16;++i){ e[i]=expf(w[i]-mx); s+=e[i]; }
    for (int i=0;i<16;++i) wsm[i]=e[i]/s;
  }
}

// stable argsort of sub (False first), build gather row indices for f_cor
__global__ void k_perm(const void* __restrict__ subp, int* __restrict__ gidx){
  __shared__ int perm[32];
  if (threadIdx.x==0){
    const int* pi = (const int*)subp;
    const float* pf = (const float*)subp;
    const unsigned char* pb = (const unsigned char*)subp;
    int sv[32]; bool okI=true, okF=true;
    for (int i=0;i<32;++i){ int v=pi[i]; if (v!=0 && v!=1) okI=false; }
    for (int i=0;i<32;++i){ float f=pf[i]; if (f!=0.f && f!=1.f) okF=false; }
    for (int i=0;i<32;++i){
      if (okI) sv[i]=pi[i];
      else if (okF) sv[i]=(pf[i]!=0.f)?1:0;
      else sv[i]=(pb[i]!=0)?1:0;
    }
    int pos=0;
    for (int i=0;i<32;++i) if (!sv[i]) perm[pos++]=i;
    for (int i=0;i<32;++i) if ( sv[i]) perm[pos++]=i;
  }
  __syncthreads();
  for (int idx = threadIdx.x; idx < 32*1152; idx += blockDim.x){
    int b = idx / 1152, rem = idx % 1152, j = rem / 288, n = rem % 288;
    int src = ((perm[b] >> 2) << 2) + j;      // (perm[b]//4)*4 + j
    gidx[idx] = src*288 + n;                  // row into [32*288, 2048] gmix/relg
  }
}

// ---------------- launcher ----------------
extern "C" void kernel_launch(void* const* d_in, const int* in_sizes, int n_in,
                              void* d_out, int out_size, void* d_ws, size_t ws_size,
                              hipStream_t stream) {
  const float* x        = (const float*)d_in[0];   // [32,2048,24,12]
  const int*   cam_ids  = (const int*)d_in[1];     // [32]
  const void*  subp     = d_in[2];                 // [32] bool (dtype-robust parse)
  const float* query_v  = (const float*)d_in[3];   // [1,16,2048]
  const float* proto    = (const float*)d_in[4];   // [1,2048,2048]
  const float* weights  = (const float*)d_in[5];   // [1,16,1]
  const float* cam_tab  = (const float*)d_in[6];   // [6,1,2048]
  const float* Wcq      = (const float*)d_in[8];
  const float* Wcg      = (const float*)d_in[9];
  const float* Wdq      = (const float*)d_in[10];
  const float* Wdg      = (const float*)d_in[11];
  float* out = (float*)d_out;                      // f_rel | f_pro/16 | f_rec | f_cor
  float* ws  = (float*)d_ws;

  // workspace layout (floats); RELG aliases XS (xs dead after gmix)
  size_t o = 0;
  float* XS    = ws + o; o += 18874368;  float* RELG = XS;
  float* GMIX  = ws + o; o += 18874368;
  float* S     = ws + o; o += 2654208;
  float* MU_XS = ws + o; o += 9216;
  float* M2_XS = ws + o; o += 9216;
  float* CAMB  = ws + o; o += 65536;
  float* RQ0   = ws + o; o += 32768;
  float* SREL  = ws + o; o += 147456;
  float* MU_FR = ws + o; o += 512;
  float* M2_FR = ws + o; o += 512;
  float* QLN   = ws + o; o += 1048576;
  float* RELQ2 = ws + o; o += 1048576;
  float* MEANX = ws + o; o += 65536;
  float* MU_P  = ws + o; o += 2048;
  float* M2_P  = ws + o; o += 2048;
  float* MU_M  = ws + o; o += 64;
  float* M2_M  = ws + o; o += 64;
  float* MU_W  = ws + o; o += 2048;
  float* M2_W  = ws + o; o += 2048;
  float* PM    = ws + o; o += 65536;
  float* SIGMA = ws + o; o += 65536;
  float* P     = ws + o; o += 4194304;
  float* MX    = ws + o; o += 65536;
  float* QP    = ws + o; o += 1048576;
  float* QM    = ws + o; o += 512;
  float* W1    = ws + o; o += 512;
  float* WMU   = ws + o; o += 512;
  float* OUT2  = ws + o; o += 1048576;
  float* FPRO  = ws + o; o += 1048576;
  float* RQ2   = ws + o; o += 1048576;
  float* SREC  = ws + o; o += 147456;
  float* SCOR  = ws + o; o += 589824;
  float* WSM   = ws + o; o += 16;
  int*   GIDX  = (int*)(ws + o); o += 36864;

  float* F_REL = out;
  float* F_PRO = out + 1048576;
  float* F_REC = out + 2097152;
  float* F_COR = out + 3145728;

  // ---- Phase A: per-batch patch self-attention (shared by all catcher calls) ----
  k_transpose<<<dim3(9,64,32), dim3(32,8), 0, stream>>>(x, XS);
  k_rowstats<<<9216, 256, 0, stream>>>(XS, 2048, 2048, MU_XS, M2_XS);
  // gram: Sraw[b] = xs[b] . xs[b]^T
  gemm_nt<<<dim3(5,5,32), 256, 0, stream>>>(S, XS, XS, 288,288,2048, 2048,2048,288,
                                            589824,589824,82944, 1.f, nullptr,0, nullptr,0);
  k_softmax_gram<<<9216, 256, 0, stream>>>(S, M2_XS);
  // gmix[b] = S[b] . xs[b]
  gemm_nn<<<dim3(32,5,32), 256, 0, stream>>>(GMIX, S, XS, 288,2048,288, 288,2048,2048,
                                             82944,589824,589824, 1.f, nullptr,0);
  k_camb<<<dim3(8,32), 256, 0, stream>>>(cam_tab, cam_ids, CAMB);
  // relg[b] = (gmix[b] + camb[b]) . Wcg^T   (overwrites XS)
  gemm_nt<<<dim3(32,5,32), 256, 0, stream>>>(RELG, GMIX, Wcg, 288,2048,2048, 2048,2048,2048,
                                             589824,0,589824, 1.f, CAMB,2048, nullptr,0);

  // ---- f_rel ----
  gemm_nt<<<dim3(32,1,1), 256, 0, stream>>>(RQ0, query_v, Wcq, 16,2048,2048, 2048,2048,2048,
                                            0,0,0, 1.f, nullptr,0, nullptr,0);
  gemm_nt<<<dim3(5,1,32), 256, 0, stream>>>(SREL, RQ0, RELG, 16,288,2048, 2048,2048,288,
                                            0,589824,4608, SCALE, nullptr,0, nullptr,0);
  k_softmax_plain<<<512, 256, 0, stream>>>(SREL, 288);
  gemm_nn<<<dim3(32,1,32), 256, 0, stream>>>(F_REL, SREL, GMIX, 16,2048,288, 288,2048,2048,
                                             4608,589824,32768, 1.f, nullptr,0);

  // ---- deltaor (decomposed LN algebra) ----
  k_rowstats<<<512, 256, 0, stream>>>(F_REL, 2048, 2048, MU_FR, M2_FR);
  k_ln_apply<<<dim3(8,512), 256, 0, stream>>>(F_REL, MU_FR, M2_FR, QLN);
  k_meanx<<<dim3(8,32), 256, 0, stream>>>(F_REL, MEANX);
  k_rowstats<<<32,   256, 0, stream>>>(MEANX, 2048, 2048, MU_M, M2_M);
  k_rowstats<<<2048, 256, 0, stream>>>(proto, 2048, 2048, MU_P, M2_P);
  k_rowstats<<<2048, 256, 0, stream>>>(Wdg,   2048, 2048, MU_W, M2_W);
  gemm_nt<<<dim3(32,8,1), 256, 0, stream>>>(RELQ2, QLN, Wdq, 512,2048,2048, 2048,2048,2048,
                                            0,0,0, 1.f, nullptr,0, nullptr,0);
  gemm_nt<<<dim3(32,1,1), 256, 0, stream>>>(PM, MEANX, proto, 32,2048,2048, 2048,2048,2048,
                                            0,0,0, 1.f, nullptr,0, nullptr,0);
  k_sigma<<<dim3(8,32), 256, 0, stream>>>(PM, MU_P, M2_P, MU_M, M2_M, SIGMA);
  gemm_nt<<<dim3(32,32,1), 256, 0, stream>>>(P, proto, Wdg, 2048,2048,2048, 2048,2048,2048,
                                             0,0,0, 1.f, nullptr,0, nullptr,0);
  k_fixrow<<<dim3(8,2048), 256, 0, stream>>>(P, MU_P, MU_W);
  gemm_nt<<<dim3(32,1,1), 256, 0, stream>>>(MX, MEANX, Wdg, 32,2048,2048, 2048,2048,2048,
                                            0,0,0, 1.f, nullptr,0, nullptr,0);
  k_fixrow<<<dim3(8,32), 256, 0, stream>>>(MX, MU_M, MU_W);
  gemm_nt<<<dim3(32,8,1), 256, 0, stream>>>(QP, RELQ2, P, 512,2048,2048, 2048,2048,2048,
                                            0,0,0, 1.f, nullptr,0, nullptr,0);
  k_qm<<<512, 256, 0, stream>>>(RELQ2, MX, QM);
  k_score2<<<512, 256, 0, stream>>>(QP, QM, SIGMA, MU_P, W1, WMU, SCALE);
  gemm_nn<<<dim3(32,1,32), 256, 0, stream>>>(OUT2, QP, proto, 16,2048,2048, 2048,2048,2048,
                                             32768,0,32768, 1.f, nullptr,0);
  k_wsoft<<<1, 64, 0, stream>>>(weights, WSM);
  k_fpro_final<<<dim3(8,512), 256, 0, stream>>>(F_REL, OUT2, MEANX, MU_M, W1, WMU, WSM,
                                                FPRO, F_PRO);

  // ---- f_rec ----
  gemm_nt<<<dim3(32,8,1), 256, 0, stream>>>(RQ2, FPRO, Wcq, 512,2048,2048, 2048,2048,2048,
                                            0,0,0, 1.f, nullptr,0, nullptr,0);
  gemm_nt<<<dim3(5,1,32), 256, 0, stream>>>(SREC, RQ2, RELG, 16,288,2048, 2048,2048,288,
                                            32768,589824,4608, SCALE, nullptr,0, nullptr,0);
  k_softmax_plain<<<512, 256, 0, stream>>>(SREC, 288);
  gemm_nn<<<dim3(32,1,32), 256, 0, stream>>>(F_REC, SREC, GMIX, 16,2048,288, 288,2048,2048,
                                             4608,589824,32768, 1.f, nullptr,0);

  // ---- f_cor (gathered groups via perm of sub) ----
  k_perm<<<1, 256, 0, stream>>>(subp, GIDX);
  gemm_nt<<<dim3(18,1,32), 256, 0, stream>>>(SCOR, RQ2, RELG, 16,1152,2048, 2048,2048,1152,
                                             32768,0,18432, SCALE, nullptr,0, GIDX,1152);
  k_softmax_plain<<<512, 256, 0, stream>>>(SCOR, 1152);
  gemm_nn<<<dim3(32,1,32), 256, 0, stream>>>(F_COR, SCOR, GMIX, 16,2048,1152, 1152,2048,2048,
                                             18432,0,32768, 1.f, GIDX,1152);
}

// Round 2
// 1914.600 us; speedup vs baseline: 2.1285x; 2.1285x over previous
//
#include <hip/hip_runtime.h>
#include <math.h>

// B=32, C=2048, N=288(==PATCH), Q=16, proto tokens=2048
#define BK 16
#define BT 64

static constexpr float SCALE = 0.022097086912079612f; // 2048^-0.5

typedef __bf16 bf16x4 __attribute__((ext_vector_type(4)));
typedef __bf16 bf16x8 __attribute__((ext_vector_type(8)));
typedef float  f32x4  __attribute__((ext_vector_type(4)));

// ---------------- reduction helpers ----------------
__device__ __forceinline__ float wred_sum(float v){
  #pragma unroll
  for (int o=32;o>0;o>>=1) v += __shfl_down(v,o,64);
  return v;
}
__device__ __forceinline__ float wred_max(float v){
  #pragma unroll
  for (int o=32;o>0;o>>=1) v = fmaxf(v, __shfl_down(v,o,64));
  return v;
}
__device__ __forceinline__ float block_sum(float v, float* red){
  int tid=threadIdx.x, w=tid>>6, l=tid&63, nw=(int)(blockDim.x>>6);
  v = wred_sum(v);
  __syncthreads();
  if (l==0) red[w]=v;
  __syncthreads();
  float r=0.f;
  for (int i=0;i<nw;i++) r += red[i];
  return r;
}
__device__ __forceinline__ float block_max(float v, float* red){
  int tid=threadIdx.x, w=tid>>6, l=tid&63, nw=(int)(blockDim.x>>6);
  v = wred_max(v);
  __syncthreads();
  if (l==0) red[w]=v;
  __syncthreads();
  float r=red[0];
  for (int i=1;i<nw;i++) r = fmaxf(r, red[i]);
  return r;
}

// ---------------- MFMA split-bf16 NT GEMM ----------------
// C = alpha * A * B^T ; A [M,K] lda, B [N,K] ldb, C [M,N] ldc, batched via z.
// fp32 in/out; internally splits to bf16 hi/lo and does 3 MFMA products.
// browidx: optional per-z row gather for B (row n -> B[brow[n]*ldb + k]).
template<int MT, int NT, int WM, int WN>
__global__ __launch_bounds__(256, 2)
void gemm_nt_mfma(float* __restrict__ Cm, const float* __restrict__ Am,
                  const float* __restrict__ Bm, int M, int N, int K,
                  int lda, int ldb, int ldc, long sA, long sB, long sC,
                  float alpha, const int* __restrict__ browidx, long sBrow)
{
  constexpr int BM = MT*16*WM;
  constexpr int BN = NT*16*WN;
  constexpr int LDH = 40;             // bf16 row stride (80B: 16B-aligned, ~conflict-free)
  constexpr int AST = (BM+31)/32;
  constexpr int BST = (BN+31)/32;
  __shared__ __bf16 Ah[BM*LDH];
  __shared__ __bf16 Al[BM*LDH];
  __shared__ __bf16 Bh[BN*LDH];
  __shared__ __bf16 Bl[BN*LDH];
  int z = blockIdx.z;
  const float* A = Am + (long)z*sA;
  const float* B = Bm + (long)z*sB;
  float* C = Cm + (long)z*sC;
  const bool useB = (browidx != nullptr);
  const int* brow = useB ? (browidx + (long)z*sBrow) : nullptr;
  int m0 = blockIdx.y*BM, n0 = blockIdx.x*BN;
  int t = threadIdx.x;
  int srow = t>>3, skoff = (t&7)*4;

  float4 areg[AST], breg[BST];
  auto loadAB = [&](int k0){
    #pragma unroll
    for (int s=0;s<AST;++s){
      int row = srow + 32*s; int gm = m0+row;
      areg[s] = make_float4(0.f,0.f,0.f,0.f);
      if (row < BM && gm < M) areg[s] = *(const float4*)(A + (long)gm*lda + k0 + skoff);
    }
    #pragma unroll
    for (int s=0;s<BST;++s){
      int row = srow + 32*s; int gn = n0+row;
      breg[s] = make_float4(0.f,0.f,0.f,0.f);
      if (row < BN && gn < N){
        long r = useB ? (long)brow[gn] : (long)gn;
        breg[s] = *(const float4*)(B + r*ldb + k0 + skoff);
      }
    }
  };
  auto writeLDS = [&](){
    #pragma unroll
    for (int s=0;s<AST;++s){
      int row = srow + 32*s;
      if (row < BM){
        float vv[4] = {areg[s].x, areg[s].y, areg[s].z, areg[s].w};
        bf16x4 hv, lv;
        #pragma unroll
        for (int e=0;e<4;++e){
          __bf16 h = (__bf16)vv[e];
          hv[e] = h;
          lv[e] = (__bf16)(vv[e] - (float)h);
        }
        *(bf16x4*)&Ah[row*LDH + skoff] = hv;
        *(bf16x4*)&Al[row*LDH + skoff] = lv;
      }
    }
    #pragma unroll
    for (int s=0;s<BST;++s){
      int row = srow + 32*s;
      if (row < BN){
        float vv[4] = {breg[s].x, breg[s].y, breg[s].z, breg[s].w};
        bf16x4 hv, lv;
        #pragma unroll
        for (int e=0;e<4;++e){
          __bf16 h = (__bf16)vv[e];
          hv[e] = h;
          lv[e] = (__bf16)(vv[e] - (float)h);
        }
        *(bf16x4*)&Bh[row*LDH + skoff] = hv;
        *(bf16x4*)&Bl[row*LDH + skoff] = lv;
      }
    }
  };

  int lane = t & 63, wid = t >> 6;
  int wm = (WM==1) ? 0 : (wid / WN);
  int wn = wid % WN;
  int mw = wm*MT*16, nw = wn*NT*16;
  int fr = lane & 15, fq = (lane>>4)*8;

  f32x4 acc[MT][NT];
  #pragma unroll
  for (int i=0;i<MT;++i)
    #pragma unroll
    for (int j=0;j<NT;++j) acc[i][j] = (f32x4){0.f,0.f,0.f,0.f};

  loadAB(0);
  for (int k0=0; k0<K; k0+=32){
    writeLDS();
    __syncthreads();
    if (k0+32 < K) loadAB(k0+32);
    bf16x8 ah[MT], al[MT], bh[NT], bl[NT];
    #pragma unroll
    for (int i=0;i<MT;++i){
      ah[i] = *(const bf16x8*)&Ah[(mw+i*16+fr)*LDH + fq];
      al[i] = *(const bf16x8*)&Al[(mw+i*16+fr)*LDH + fq];
    }
    #pragma unroll
    for (int j=0;j<NT;++j){
      bh[j] = *(const bf16x8*)&Bh[(nw+j*16+fr)*LDH + fq];
      bl[j] = *(const bf16x8*)&Bl[(nw+j*16+fr)*LDH + fq];
    }
    #pragma unroll
    for (int i=0;i<MT;++i)
      #pragma unroll
      for (int j=0;j<NT;++j){
        acc[i][j] = __builtin_amdgcn_mfma_f32_16x16x32_bf16(ah[i], bh[j], acc[i][j], 0,0,0);
        acc[i][j] = __builtin_amdgcn_mfma_f32_16x16x32_bf16(ah[i], bl[j], acc[i][j], 0,0,0);
        acc[i][j] = __builtin_amdgcn_mfma_f32_16x16x32_bf16(al[i], bh[j], acc[i][j], 0,0,0);
      }
    __syncthreads();
  }
  int er = (lane>>4)*4, ec = lane & 15;
  #pragma unroll
  for (int i=0;i<MT;++i){
    int mbase = m0 + mw + i*16 + er;
    #pragma unroll
    for (int r=0;r<4;++r){
      int mm = mbase + r;
      if (mm < M){
        long cro = (long)mm*ldc;
        #pragma unroll
        for (int j=0;j<NT;++j){
          int nn = n0 + nw + j*16 + ec;
          if (nn < N) C[cro + nn] = alpha*acc[i][j][r];
        }
      }
    }
  }
}

// ---------------- fp32 NN GEMM (small PV epilogues only) ----------------
__global__ __launch_bounds__(256) void gemm_nn(
    float* __restrict__ Cm, const float* __restrict__ Am, const float* __restrict__ Bm,
    int M, int N, int K, int lda, int ldb, int ldc,
    long sA, long sB, long sC, float alpha,
    const int* __restrict__ browidx, long sBrow)
{
  __shared__ float As[BK][BT+4];
  __shared__ float Bs[BK][BT+4];
  int z = blockIdx.z;
  const float* A = Am + (long)z*sA;
  const float* B = Bm + (long)z*sB;
  float* C = Cm + (long)z*sC;
  const int* brow = browidx ? (browidx + (long)z*sBrow) : nullptr;
  int m0 = blockIdx.y*BT, n0 = blockIdx.x*BT;
  int t = threadIdx.x;
  int lrow = t >> 2;
  int lk4  = (t & 3) * 4;
  int kr = t >> 4;
  int nq = (t & 15) * 4;
  int tm = (t & 15) * 4;
  int tn = (t >> 4) * 4;
  float acc[4][4] = {};
  for (int k0 = 0; k0 < K; k0 += BK) {
    float4 av = make_float4(0.f,0.f,0.f,0.f);
    int am = m0 + lrow;
    if (am < M) av = *(const float4*)(A + (long)am*lda + k0 + lk4);
    As[lk4+0][lrow]=av.x; As[lk4+1][lrow]=av.y; As[lk4+2][lrow]=av.z; As[lk4+3][lrow]=av.w;
    long roff = brow ? (long)brow[k0+kr]*ldb : (long)(k0+kr)*ldb;
    const float* bp = B + roff + n0 + nq;
    if (n0 + nq + 3 < N) {
      float4 bv = *(const float4*)bp;
      Bs[kr][nq+0]=bv.x; Bs[kr][nq+1]=bv.y; Bs[kr][nq+2]=bv.z; Bs[kr][nq+3]=bv.w;
    } else {
      #pragma unroll
      for (int j=0;j<4;++j) Bs[kr][nq+j] = (n0+nq+j < N) ? bp[j] : 0.f;
    }
    __syncthreads();
    #pragma unroll
    for (int kk = 0; kk < BK; ++kk) {
      float4 a = *(const float4*)&As[kk][tm];
      float4 b = *(const float4*)&Bs[kk][tn];
      float aa[4]={a.x,a.y,a.z,a.w}, bb[4]={b.x,b.y,b.z,b.w};
      #pragma unroll
      for (int i=0;i<4;++i)
        #pragma unroll
        for (int j=0;j<4;++j) acc[i][j] += aa[i]*bb[j];
    }
    __syncthreads();
  }
  #pragma unroll
  for (int i=0;i<4;++i){
    int m = m0 + tm + i;
    if (m < M){
      long cro = (long)m*ldc;
      #pragma unroll
      for (int j=0;j<4;++j){
        int n = n0 + tn + j;
        if (n < N) C[cro + n] = alpha*acc[i][j];
      }
    }
  }
}

// ---------------- small kernels ----------------
// generic transpose: in [Z][R][C] -> out [Z][C][R]; R,C multiples of 32
__global__ void k_tr(const float* __restrict__ in, float* __restrict__ out, int R, int C){
  __shared__ float tile[32][33];
  long zo = (long)blockIdx.z * R * C;
  int r0 = blockIdx.y*32, c0 = blockIdx.x*32;
  int tx = threadIdx.x, ty = threadIdx.y;
  #pragma unroll
  for (int j=0;j<32;j+=8)
    tile[ty+j][tx] = in[zo + (long)(r0+ty+j)*C + c0+tx];
  __syncthreads();
  #pragma unroll
  for (int j=0;j<32;j+=8)
    out[zo + (long)(c0+ty+j)*R + r0+tx] = tile[tx][ty+j];
}

__global__ __launch_bounds__(256) void k_rowstats(const float* __restrict__ X, long ldx, int cols,
                                                  float* __restrict__ mu, float* __restrict__ m2){
  int r = blockIdx.x;
  const float* row = X + (long)r*ldx;
  float s=0.f, s2=0.f;
  for (int c = threadIdx.x*4; c < cols; c += 1024){
    float4 v = *(const float4*)(row+c);
    s  += v.x+v.y+v.z+v.w;
    s2 += v.x*v.x+v.y*v.y+v.z*v.z+v.w*v.w;
  }
  __shared__ float red[8];
  s  = block_sum(s,  red);
  s2 = block_sum(s2, red);
  if (threadIdx.x==0){ mu[r]=s/(float)cols; m2[r]=s2; }
}

__global__ __launch_bounds__(256) void k_softmax_gram(float* __restrict__ S, const float* __restrict__ m2xs){
  int r = blockIdx.x;
  int b = r / 288, p = r % 288;
  float* row = S + (long)r * 288;
  const float* m2 = m2xs + (long)b*288;
  float rp = 1.f / fmaxf(sqrtf(m2[p]), 1e-12f);
  int tid = threadIdx.x;
  __shared__ float red[8];
  float lv[2];
  #pragma unroll
  for (int i=0;i<2;++i){
    int q = tid + i*256;
    lv[i] = (q<288) ? row[q]*rp/fmaxf(sqrtf(m2[q]),1e-12f) : -1e30f;
  }
  float mx = fmaxf(lv[0], lv[1]);
  mx = block_max(mx, red);
  float s = 0.f;
  #pragma unroll
  for (int i=0;i<2;++i){
    int q = tid + i*256;
    float e = (q<288) ? expf(lv[i]-mx) : 0.f;
    lv[i]=e; s+=e;
  }
  s = block_sum(s, red);
  float inv = 1.f/s;
  #pragma unroll
  for (int i=0;i<2;++i){ int q = tid + i*256; if (q<288) row[q]=lv[i]*inv; }
}

__global__ __launch_bounds__(256) void k_softmax_plain(float* __restrict__ X, int L){
  int r = blockIdx.x;
  float* row = X + (long)r * L;
  int tid = threadIdx.x;
  __shared__ float red[8];
  float lv[8];
  #pragma unroll
  for (int i=0;i<8;++i){ int q = tid + i*256; lv[i] = (q<L) ? row[q] : -1e30f; }
  float mx = -1e30f;
  #pragma unroll
  for (int i=0;i<8;++i) mx = fmaxf(mx, lv[i]);
  mx = block_max(mx, red);
  float s = 0.f;
  #pragma unroll
  for (int i=0;i<8;++i){ int q = tid + i*256; float e = (q<L)?expf(lv[i]-mx):0.f; lv[i]=e; s+=e; }
  s = block_sum(s, red);
  float inv = 1.f/s;
  #pragma unroll
  for (int i=0;i<8;++i){ int q = tid + i*256; if (q<L) row[q]=lv[i]*inv; }
}

// softmax over L=1152 with per-288-segment additive bias scale*CC[r][SB[b][j]]
__global__ __launch_bounds__(256) void k_softmax_seg(float* __restrict__ X, const float* __restrict__ CC,
                                                     const int* __restrict__ SB, float scale){
  int r = blockIdx.x; int b = r>>4;
  float* row = X + (long)r*1152;
  float bias[4];
  #pragma unroll
  for (int j=0;j<4;++j) bias[j] = scale*CC[(long)r*32 + SB[b*4+j]];
  int tid = threadIdx.x;
  __shared__ float red[8];
  float lv[5];
  #pragma unroll
  for (int i=0;i<5;++i){
    int q = tid + i*256;
    lv[i] = (q<1152) ? row[q] + bias[q/288] : -1e30f;
  }
  float mx = -1e30f;
  #pragma unroll
  for (int i=0;i<5;++i) mx = fmaxf(mx, lv[i]);
  mx = block_max(mx, red);
  float s = 0.f;
  #pragma unroll
  for (int i=0;i<5;++i){ int q = tid + i*256; float e = (q<1152)?expf(lv[i]-mx):0.f; lv[i]=e; s+=e; }
  s = block_sum(s, red);
  float inv = 1.f/s;
  #pragma unroll
  for (int i=0;i<5;++i){ int q = tid + i*256; if (q<1152) row[q]=lv[i]*inv; }
}

__global__ void k_ln_apply(const float* __restrict__ X, const float* __restrict__ mu,
                           const float* __restrict__ m2, float* __restrict__ Y){
  int r = blockIdx.y; int c = blockIdx.x*256 + threadIdx.x;
  float m = mu[r];
  float v = m2[r]*(1.f/2048.f) - m*m;
  float inv = rsqrtf(v + 1e-5f);
  long idx = (long)r*2048 + c;
  Y[idx] = (X[idx] - m)*inv;
}

__global__ void k_meanx(const float* __restrict__ frel, float* __restrict__ mx){
  int b = blockIdx.y; int c = blockIdx.x*256 + threadIdx.x;
  const float* base = frel + (long)b*16*2048 + c;
  float s=0.f;
  #pragma unroll
  for (int q=0;q<16;++q) s += base[(long)q*2048];
  mx[(long)b*2048 + c] = s * (1.f/16.f);
}

__global__ void k_sigma(const float* __restrict__ pm, const float* __restrict__ mu_p,
                        const float* __restrict__ m2_p, const float* __restrict__ mu_m,
                        const float* __restrict__ m2_m, float* __restrict__ sigma){
  int b = blockIdx.y; int n = blockIdx.x*256 + threadIdx.x;
  float mp = mu_p[n], mm = mu_m[b];
  float vp = m2_p[n]*(1.f/2048.f) - mp*mp;
  float vm = m2_m[b]*(1.f/2048.f) - mm*mm;
  float cov = pm[(long)b*2048+n]*(1.f/2048.f) - mp*mm;
  sigma[(long)b*2048+n] = sqrtf(fmaxf(vp + vm - 2.f*cov, 0.f) + 1e-5f);
}

__global__ void k_fixrow(float* __restrict__ X, const float* __restrict__ mu_row,
                         const float* __restrict__ mu_w){
  int r = blockIdx.y; int d = blockIdx.x*256 + threadIdx.x;
  X[(long)r*2048 + d] -= mu_row[r] * mu_w[d] * 2048.f;
}

__global__ __launch_bounds__(256) void k_qm(const float* __restrict__ relq2,
                                            const float* __restrict__ Mx, float* __restrict__ qm){
  int r = blockIdx.x; int b = r >> 4;
  const float* a = relq2 + (long)r*2048;
  const float* m = Mx + (long)b*2048;
  float s=0.f;
  for (int c = threadIdx.x*4; c < 2048; c += 1024){
    float4 va=*(const float4*)(a+c), vm=*(const float4*)(m+c);
    s += va.x*vm.x+va.y*vm.y+va.z*vm.z+va.w*vm.w;
  }
  __shared__ float red[8];
  s = block_sum(s, red);
  if (threadIdx.x==0) qm[r]=s;
}

__global__ __launch_bounds__(256) void k_score2(float* __restrict__ QPw, const float* __restrict__ qm,
                                                const float* __restrict__ sigma, const float* __restrict__ mu_p,
                                                float* __restrict__ W1, float* __restrict__ Wmu, float scale){
  int r = blockIdx.x; int b = r >> 4;
  float* row = QPw + (long)r*2048;
  const float* sg = sigma + (long)b*2048;
  int tid = threadIdx.x;
  __shared__ float red[8];
  float qmr = qm[r];
  float lv[8], ls[8];
  #pragma unroll
  for (int i=0;i<8;++i){
    int n = tid + i*256;
    float sgn = sg[n];
    ls[i] = sgn;
    lv[i] = scale * (row[n] - qmr) / sgn;
  }
  float mx = -1e30f;
  #pragma unroll
  for (int i=0;i<8;++i) mx = fmaxf(mx, lv[i]);
  mx = block_max(mx, red);
  float se=0.f, sw=0.f, swm=0.f;
  #pragma unroll
  for (int i=0;i<8;++i){
    int n = tid + i*256;
    float e = expf(lv[i]-mx);
    lv[i] = e; se += e;
    float wv = e/ls[i];
    sw += wv; swm += wv*mu_p[n];
  }
  se  = block_sum(se,  red);
  sw  = block_sum(sw,  red);
  swm = block_sum(swm, red);
  float inv = 1.f/se;
  #pragma unroll
  for (int i=0;i<8;++i){ int n = tid + i*256; row[n] = lv[i]*inv/ls[i]; }
  if (tid==0){ W1[r]=sw*inv; Wmu[r]=swm*inv; }
}

__global__ void k_fpro_final(const float* __restrict__ frel, const float* __restrict__ out2,
                             const float* __restrict__ meanx, const float* __restrict__ mu_m,
                             const float* __restrict__ W1, const float* __restrict__ Wmu,
                             const float* __restrict__ wsm,
                             float* __restrict__ fpro, float* __restrict__ fout){
  int r = blockIdx.y; int c = blockIdx.x*256 + threadIdx.x;
  int b = r >> 4, q = r & 15;
  long idx = (long)r*2048 + c;
  float w1 = W1[r];
  float v = frel[idx] + out2[idx] - meanx[(long)b*2048+c]*w1 - Wmu[r] + mu_m[b]*w1;
  fpro[idx] = v;
  fout[idx] = wsm[q] * v;
}

__global__ void k_camb(const float* __restrict__ cam_table, const int* __restrict__ cam_ids,
                       float* __restrict__ camb){
  int b = blockIdx.y; int c = blockIdx.x*256 + threadIdx.x;
  camb[(long)b*2048 + c] = cam_table[(long)(cam_ids[b]-1)*2048 + c];
}

__global__ void k_wsoft(const float* __restrict__ w, float* __restrict__ wsm){
  if (threadIdx.x==0){
    float mx=-1e30f;
    for (int i=0;i<16;++i) mx=fmaxf(mx,w[i]);
    float e[16], s=0.f;
    for (int i=0;i<16;++i){ e[i]=expf(w[i]-mx); s+=e[i]; }
    for (int i=0;i<16;++i) wsm[i]=e[i]/s;
  }
}

// stable argsort of sub (False first) -> row gather indices + source-batch table
__global__ void k_perm(const void* __restrict__ subp, int* __restrict__ gidx, int* __restrict__ SB){
  __shared__ int perm[32];
  if (threadIdx.x==0){
    const int* pi = (const int*)subp;
    const float* pf = (const float*)subp;
    const unsigned char* pb = (const unsigned char*)subp;
    int sv[32]; bool okI=true, okF=true;
    for (int i=0;i<32;++i){ int v=pi[i]; if (v!=0 && v!=1) okI=false; }
    for (int i=0;i<32;++i){ float f=pf[i]; if (f!=0.f && f!=1.f) okF=false; }
    for (int i=0;i<32;++i){
      if (okI) sv[i]=pi[i];
      else if (okF) sv[i]=(pf[i]!=0.f)?1:0;
      else sv[i]=(pb[i]!=0)?1:0;
    }
    int pos=0;
    for (int i=0;i<32;++i) if (!sv[i]) perm[pos++]=i;
    for (int i=0;i<32;++i) if ( sv[i]) perm[pos++]=i;
  }
  __syncthreads();
  for (int i = threadIdx.x; i < 128; i += blockDim.x){
    int b = i>>2, j = i&3;
    SB[i] = ((perm[b]>>2)<<2) + j;
  }
  for (int idx = threadIdx.x; idx < 32*1152; idx += blockDim.x){
    int b = idx / 1152, rem = idx % 1152, j = rem / 288, n = rem % 288;
    int src = ((perm[b] >> 2) << 2) + j;
    gidx[idx] = src*288 + n;
  }
}

// ---------------- launcher ----------------
extern "C" void kernel_launch(void* const* d_in, const int* in_sizes, int n_in,
                              void* d_out, int out_size, void* d_ws, size_t ws_size,
                              hipStream_t stream) {
  const float* x        = (const float*)d_in[0];   // [32,2048,288]
  const int*   cam_ids  = (const int*)d_in[1];
  const void*  subp     = d_in[2];
  const float* query_v  = (const float*)d_in[3];   // [16,2048]
  const float* proto    = (const float*)d_in[4];   // [2048,2048]
  const float* weights  = (const float*)d_in[5];   // [16]
  const float* cam_tab  = (const float*)d_in[6];   // [6,2048]
  const float* Wcq      = (const float*)d_in[8];
  const float* Wcg      = (const float*)d_in[9];
  const float* Wdq      = (const float*)d_in[10];
  const float* Wdg      = (const float*)d_in[11];
  float* out = (float*)d_out;
  float* ws  = (float*)d_ws;

  // workspace (floats). XS region (18.9M) is reused for WCGT/PROTOT/P after gram S.
  size_t o = 0;
  float* XS    = ws + o; o += 18874368;
  float* WCGT  = XS;                    // alias: valid after S computed
  float* PROTOT= XS + 4194304;
  float* P     = XS + 8388608;
  float* GMIX  = ws + o; o += 18874368;
  float* S     = ws + o; o += 2654208;
  float* MU_XS = ws + o; o += 9216;
  float* M2_XS = ws + o; o += 9216;
  float* CAMB  = ws + o; o += 65536;
  float* RQ0   = ws + o; o += 32768;
  float* RQW   = ws + o; o += 32768;
  float* SREL  = ws + o; o += 147456;
  float* MU_FR = ws + o; o += 512;
  float* M2_FR = ws + o; o += 512;
  float* QLN   = ws + o; o += 1048576;
  float* RELQ2 = ws + o; o += 1048576;
  float* MEANX = ws + o; o += 65536;
  float* MU_P  = ws + o; o += 2048;
  float* M2_P  = ws + o; o += 2048;
  float* MU_M  = ws + o; o += 64;
  float* M2_M  = ws + o; o += 64;
  float* MU_W  = ws + o; o += 2048;
  float* M2_W  = ws + o; o += 2048;
  float* PM    = ws + o; o += 65536;
  float* SIGMA = ws + o; o += 65536;
  float* MX    = ws + o; o += 65536;
  float* QP    = ws + o; o += 1048576;
  float* QM    = ws + o; o += 512;
  float* W1    = ws + o; o += 512;
  float* WMU   = ws + o; o += 512;
  float* OUT2  = ws + o; o += 1048576;
  float* FPRO  = ws + o; o += 1048576;
  float* RQ2   = ws + o; o += 1048576;
  float* RQW2  = ws + o; o += 1048576;
  float* SREC  = ws + o; o += 147456;
  float* SCOR  = ws + o; o += 589824;
  float* CC    = ws + o; o += 16384;
  float* WSM   = ws + o; o += 16;
  int*   GIDX  = (int*)(ws + o); o += 36864;
  int*   SB    = (int*)(ws + o); o += 128;

  float* F_REL = out;
  float* F_PRO = out + 1048576;
  float* F_REC = out + 2097152;
  float* F_COR = out + 3145728;

  // ---- Phase A: shared patch self-attention ----
  k_tr<<<dim3(9,64,32), dim3(32,8), 0, stream>>>(x, XS, 2048, 288);     // XS [b][288][2048]
  k_rowstats<<<9216, 256, 0, stream>>>(XS, 2048, 2048, MU_XS, M2_XS);
  gemm_nt_mfma<3,3,2,2><<<dim3(3,3,32), 256, 0, stream>>>(S, XS, XS, 288,288,2048,
      2048,2048,288, 589824,589824,82944, 1.f, nullptr,0);
  k_softmax_gram<<<9216, 256, 0, stream>>>(S, M2_XS);
  // gmix[b] = S[b] . xs[b]  ==  NT(S[b], x[b])  (x is [2048][288] per batch)
  gemm_nt_mfma<3,4,2,2><<<dim3(16,3,32), 256, 0, stream>>>(GMIX, S, x, 288,2048,288,
      288,288,2048, 82944,589824,589824, 1.f, nullptr,0);
  // XS dead: reuse region for transposes + P
  k_tr<<<dim3(64,64,1), dim3(32,8), 0, stream>>>(Wcg, WCGT, 2048, 2048);
  k_tr<<<dim3(64,64,1), dim3(32,8), 0, stream>>>(proto, PROTOT, 2048, 2048);
  k_camb<<<dim3(8,32), 256, 0, stream>>>(cam_tab, cam_ids, CAMB);
  k_perm<<<1, 256, 0, stream>>>(subp, GIDX, SB);

  // ---- f_rel (relg eliminated: Q.relg^T = (Q.Wcg).(gmix)^T + row-const) ----
  gemm_nt_mfma<1,4,1,4><<<dim3(8,1,1), 256, 0, stream>>>(RQ0, query_v, Wcq, 16,2048,2048,
      2048,2048,2048, 0,0,0, 1.f, nullptr,0);
  gemm_nt_mfma<1,4,1,4><<<dim3(8,1,1), 256, 0, stream>>>(RQW, RQ0, WCGT, 16,2048,2048,
      2048,2048,2048, 0,0,0, 1.f, nullptr,0);
  gemm_nt_mfma<1,4,1,4><<<dim3(2,1,32), 256, 0, stream>>>(SREL, RQW, GMIX, 16,288,2048,
      2048,2048,288, 0,589824,4608, SCALE, nullptr,0);
  k_softmax_plain<<<512, 256, 0, stream>>>(SREL, 288);
  gemm_nn<<<dim3(32,1,32), 256, 0, stream>>>(F_REL, SREL, GMIX, 16,2048,288, 288,2048,2048,
                                             4608,589824,32768, 1.f, nullptr,0);

  // ---- deltaor (decomposed LN algebra) ----
  k_rowstats<<<512, 256, 0, stream>>>(F_REL, 2048, 2048, MU_FR, M2_FR);
  k_ln_apply<<<dim3(8,512), 256, 0, stream>>>(F_REL, MU_FR, M2_FR, QLN);
  k_meanx<<<dim3(8,32), 256, 0, stream>>>(F_REL, MEANX);
  k_rowstats<<<32,   256, 0, stream>>>(MEANX, 2048, 2048, MU_M, M2_M);
  k_rowstats<<<2048, 256, 0, stream>>>(proto, 2048, 2048, MU_P, M2_P);
  k_rowstats<<<2048, 256, 0, stream>>>(Wdg,   2048, 2048, MU_W, M2_W);
  gemm_nt_mfma<2,4,2,2><<<dim3(16,8,1), 256, 0, stream>>>(RELQ2, QLN, Wdq, 512,2048,2048,
      2048,2048,2048, 0,0,0, 1.f, nullptr,0);
  gemm_nt_mfma<1,4,1,4><<<dim3(8,2,1), 256, 0, stream>>>(PM, MEANX, proto, 32,2048,2048,
      2048,2048,2048, 0,0,0, 1.f, nullptr,0);
  k_sigma<<<dim3(8,32), 256, 0, stream>>>(PM, MU_P, M2_P, MU_M, M2_M, SIGMA);
  gemm_nt_mfma<4,4,2,2><<<dim3(16,16,1), 256, 0, stream>>>(P, proto, Wdg, 2048,2048,2048,
      2048,2048,2048, 0,0,0, 1.f, nullptr,0);
  k_fixrow<<<dim3(8,2048), 256, 0, stream>>>(P, MU_P, MU_W);
  gemm_nt_mfma<1,4,1,4><<<dim3(8,2,1), 256, 0, stream>>>(MX, MEANX, Wdg, 32,2048,2048,
      2048,2048,2048, 0,0,0, 1.f, nullptr,0);
  k_fixrow<<<dim3(8,32), 256, 0, stream>>>(MX, MU_M, MU_W);
  gemm_nt_mfma<2,4,2,2><<<dim3(16,8,1), 256, 0, stream>>>(QP, RELQ2, P, 512,2048,2048,
      2048,2048,2048, 0,0,0, 1.f, nullptr,0);
  k_qm<<<512, 256, 0, stream>>>(RELQ2, MX, QM);
  k_score2<<<512, 256, 0, stream>>>(QP, QM, SIGMA, MU_P, W1, WMU, SCALE);
  gemm_nt_mfma<2,4,2,2><<<dim3(16,8,1), 256, 0, stream>>>(OUT2, QP, PROTOT, 512,2048,2048,
      2048,2048,2048, 0,0,0, 1.f, nullptr,0);
  k_wsoft<<<1, 64, 0, stream>>>(weights, WSM);
  k_fpro_final<<<dim3(8,512), 256, 0, stream>>>(F_REL, OUT2, MEANX, MU_M, W1, WMU, WSM,
                                                FPRO, F_PRO);

  // ---- f_rec ----
  gemm_nt_mfma<2,4,2,2><<<dim3(16,8,1), 256, 0, stream>>>(RQ2, FPRO, Wcq, 512,2048,2048,
      2048,2048,2048, 0,0,0, 1.f, nullptr,0);
  gemm_nt_mfma<2,4,2,2><<<dim3(16,8,1), 256, 0, stream>>>(RQW2, RQ2, WCGT, 512,2048,2048,
      2048,2048,2048, 0,0,0, 1.f, nullptr,0);
  gemm_nt_mfma<1,4,1,4><<<dim3(2,1,32), 256, 0, stream>>>(SREC, RQW2, GMIX, 16,288,2048,
      2048,2048,288, 32768,589824,4608, SCALE, nullptr,0);
  k_softmax_plain<<<512, 256, 0, stream>>>(SREC, 288);
  gemm_nn<<<dim3(32,1,32), 256, 0, stream>>>(F_REC, SREC, GMIX, 16,2048,288, 288,2048,2048,
                                             4608,589824,32768, 1.f, nullptr,0);

  // ---- f_cor ----
  gemm_nt_mfma<1,4,1,4><<<dim3(1,32,1), 256, 0, stream>>>(CC, RQW2, CAMB, 512,32,2048,
      2048,2048,32, 0,0,0, 1.f, nullptr,0);
  gemm_nt_mfma<1,4,1,4><<<dim3(5,1,32), 256, 0, stream>>>(SCOR, RQW2, GMIX, 16,1152,2048,
      2048,2048,1152, 32768,0,18432, SCALE, GIDX,1152);
  k_softmax_seg<<<512, 256, 0, stream>>>(SCOR, CC, SB, SCALE);
  gemm_nn<<<dim3(32,1,32), 256, 0, stream>>>(F_COR, SCOR, GMIX, 16,2048,1152, 1152,2048,2048,
                                             18432,0,32768, 1.f, GIDX,1152);
}

// Round 3
// 1193.776 us; speedup vs baseline: 3.4138x; 1.6038x over previous
//
#include <hip/hip_runtime.h>
#include <math.h>

// B=32, C=2048, N=288(==PATCH), Q=16, proto tokens=2048
#define BK 16
#define BT 64

static constexpr float SCALE = 0.022097086912079612f; // 2048^-0.5

typedef __bf16 bf16x4 __attribute__((ext_vector_type(4)));
typedef __bf16 bf16x8 __attribute__((ext_vector_type(8)));
typedef float  f32x4  __attribute__((ext_vector_type(4)));

// ---------------- reduction helpers ----------------
__device__ __forceinline__ float wred_sum(float v){
  #pragma unroll
  for (int o=32;o>0;o>>=1) v += __shfl_down(v,o,64);
  return v;
}
__device__ __forceinline__ float wred_max(float v){
  #pragma unroll
  for (int o=32;o>0;o>>=1) v = fmaxf(v, __shfl_down(v,o,64));
  return v;
}
__device__ __forceinline__ float block_sum(float v, float* red){
  int tid=threadIdx.x, w=tid>>6, l=tid&63, nw=(int)(blockDim.x>>6);
  v = wred_sum(v);
  __syncthreads();
  if (l==0) red[w]=v;
  __syncthreads();
  float r=0.f;
  for (int i=0;i<nw;i++) r += red[i];
  return r;
}
__device__ __forceinline__ float block_max(float v, float* red){
  int tid=threadIdx.x, w=tid>>6, l=tid&63, nw=(int)(blockDim.x>>6);
  v = wred_max(v);
  __syncthreads();
  if (l==0) red[w]=v;
  __syncthreads();
  float r=red[0];
  for (int i=1;i<nw;i++) r = fmaxf(r, red[i]);
  return r;
}

// ---------------- MFMA split-bf16 NT GEMM with split-K ----------------
// C = alpha * A * B^T ; A [M,K] lda, B [N,K] ldb, C [M,N] ldc, batched via z.
// Split-K: gridDim.z = Z*KS; ks==0 writes raw acc to C, ks>0 to Part
// (layout [(ks-1)*Z + z][M][N]); k_reduce sums and applies alpha.
// Requires ldc==N and sC==M*N when KS>1 (true for all call sites).
template<int MT, int NT, int WM, int WN>
__global__ __launch_bounds__(256, 2)
void gemm_nt_mfma(float* __restrict__ Cm, const float* __restrict__ Am,
                  const float* __restrict__ Bm, int M, int N, int K,
                  int lda, int ldb, int ldc, long sA, long sB, long sC,
                  float alpha, const int* __restrict__ browidx, long sBrow,
                  int KS, float* __restrict__ Part)
{
  constexpr int BM = MT*16*WM;
  constexpr int BN = NT*16*WN;
  constexpr int LDH = 40;             // bf16 row stride (80B: 16B-aligned, ~conflict-free)
  constexpr int AST = (BM+31)/32;
  constexpr int BST = (BN+31)/32;
  __shared__ __bf16 Ah[BM*LDH];
  __shared__ __bf16 Al[BM*LDH];
  __shared__ __bf16 Bh[BN*LDH];
  __shared__ __bf16 Bl[BN*LDH];
  int ZZ = gridDim.z / KS;
  int z  = blockIdx.z % ZZ;
  int ks = blockIdx.z / ZZ;
  const float* A = Am + (long)z*sA;
  const float* B = Bm + (long)z*sB;
  float* C = Cm + (long)z*sC;
  const bool useB = (browidx != nullptr);
  const int* brow = useB ? (browidx + (long)z*sBrow) : nullptr;
  int Kc = ((K + KS*32 - 1) / (KS*32)) * 32;
  int kbeg = ks*Kc;
  int kend = min(K, kbeg + Kc);
  int m0 = blockIdx.y*BM, n0 = blockIdx.x*BN;
  int t = threadIdx.x;
  int srow = t>>3, skoff = (t&7)*4;

  float4 areg[AST], breg[BST];
  auto loadAB = [&](int k0){
    #pragma unroll
    for (int s=0;s<AST;++s){
      int row = srow + 32*s; int gm = m0+row;
      areg[s] = make_float4(0.f,0.f,0.f,0.f);
      if (row < BM && gm < M) areg[s] = *(const float4*)(A + (long)gm*lda + k0 + skoff);
    }
    #pragma unroll
    for (int s=0;s<BST;++s){
      int row = srow + 32*s; int gn = n0+row;
      breg[s] = make_float4(0.f,0.f,0.f,0.f);
      if (row < BN && gn < N){
        long r = useB ? (long)brow[gn] : (long)gn;
        breg[s] = *(const float4*)(B + r*ldb + k0 + skoff);
      }
    }
  };
  auto writeLDS = [&](){
    #pragma unroll
    for (int s=0;s<AST;++s){
      int row = srow + 32*s;
      if (row < BM){
        float vv[4] = {areg[s].x, areg[s].y, areg[s].z, areg[s].w};
        bf16x4 hv, lv;
        #pragma unroll
        for (int e=0;e<4;++e){
          __bf16 h = (__bf16)vv[e];
          hv[e] = h;
          lv[e] = (__bf16)(vv[e] - (float)h);
        }
        *(bf16x4*)&Ah[row*LDH + skoff] = hv;
        *(bf16x4*)&Al[row*LDH + skoff] = lv;
      }
    }
    #pragma unroll
    for (int s=0;s<BST;++s){
      int row = srow + 32*s;
      if (row < BN){
        float vv[4] = {breg[s].x, breg[s].y, breg[s].z, breg[s].w};
        bf16x4 hv, lv;
        #pragma unroll
        for (int e=0;e<4;++e){
          __bf16 h = (__bf16)vv[e];
          hv[e] = h;
          lv[e] = (__bf16)(vv[e] - (float)h);
        }
        *(bf16x4*)&Bh[row*LDH + skoff] = hv;
        *(bf16x4*)&Bl[row*LDH + skoff] = lv;
      }
    }
  };

  int lane = t & 63, wid = t >> 6;
  int wm = (WM==1) ? 0 : (wid / WN);
  int wn = wid % WN;
  int mw = wm*MT*16, nw = wn*NT*16;
  int fr = lane & 15, fq = (lane>>4)*8;

  f32x4 acc[MT][NT];
  #pragma unroll
  for (int i=0;i<MT;++i)
    #pragma unroll
    for (int j=0;j<NT;++j) acc[i][j] = (f32x4){0.f,0.f,0.f,0.f};

  if (kbeg < kend) loadAB(kbeg);
  for (int k0=kbeg; k0<kend; k0+=32){
    writeLDS();
    __syncthreads();
    if (k0+32 < kend) loadAB(k0+32);
    bf16x8 ah[MT], al[MT], bh[NT], bl[NT];
    #pragma unroll
    for (int i=0;i<MT;++i){
      ah[i] = *(const bf16x8*)&Ah[(mw+i*16+fr)*LDH + fq];
      al[i] = *(const bf16x8*)&Al[(mw+i*16+fr)*LDH + fq];
    }
    #pragma unroll
    for (int j=0;j<NT;++j){
      bh[j] = *(const bf16x8*)&Bh[(nw+j*16+fr)*LDH + fq];
      bl[j] = *(const bf16x8*)&Bl[(nw+j*16+fr)*LDH + fq];
    }
    #pragma unroll
    for (int i=0;i<MT;++i)
      #pragma unroll
      for (int j=0;j<NT;++j){
        acc[i][j] = __builtin_amdgcn_mfma_f32_16x16x32_bf16(ah[i], bh[j], acc[i][j], 0,0,0);
        acc[i][j] = __builtin_amdgcn_mfma_f32_16x16x32_bf16(ah[i], bl[j], acc[i][j], 0,0,0);
        acc[i][j] = __builtin_amdgcn_mfma_f32_16x16x32_bf16(al[i], bh[j], acc[i][j], 0,0,0);
      }
    __syncthreads();
  }
  float wf = (KS==1) ? alpha : 1.f;
  float* Cw = C; int ldw = ldc;
  if (ks > 0){ Cw = Part + ((long)(ks-1)*ZZ + z)*(long)M*N; ldw = N; }
  int er = (lane>>4)*4, ec = lane & 15;
  #pragma unroll
  for (int i=0;i<MT;++i){
    int mbase = m0 + mw + i*16 + er;
    #pragma unroll
    for (int r=0;r<4;++r){
      int mm = mbase + r;
      if (mm < M){
        long cro = (long)mm*ldw;
        #pragma unroll
        for (int j=0;j<NT;++j){
          int nn = n0 + nw + j*16 + ec;
          if (nn < N) Cw[cro + nn] = wf*acc[i][j][r];
        }
      }
    }
  }
}

// C[i] = alpha * (C[i] + sum_s Part[s*total + i])
__global__ __launch_bounds__(256) void k_reduce(float* __restrict__ C, const float* __restrict__ Part,
                                                long total, int S, float alpha){
  for (long i = (long)blockIdx.x*blockDim.x + threadIdx.x; i < total;
       i += (long)gridDim.x*blockDim.x){
    float v = C[i];
    for (int s=0;s<S;++s) v += Part[(long)s*total + i];
    C[i] = alpha*v;
  }
}

// ---------------- fp32 NN GEMM (small PV epilogues only) ----------------
__global__ __launch_bounds__(256) void gemm_nn(
    float* __restrict__ Cm, const float* __restrict__ Am, const float* __restrict__ Bm,
    int M, int N, int K, int lda, int ldb, int ldc,
    long sA, long sB, long sC, float alpha,
    const int* __restrict__ browidx, long sBrow)
{
  __shared__ float As[BK][BT+4];
  __shared__ float Bs[BK][BT+4];
  int z = blockIdx.z;
  const float* A = Am + (long)z*sA;
  const float* B = Bm + (long)z*sB;
  float* C = Cm + (long)z*sC;
  const int* brow = browidx ? (browidx + (long)z*sBrow) : nullptr;
  int m0 = blockIdx.y*BT, n0 = blockIdx.x*BT;
  int t = threadIdx.x;
  int lrow = t >> 2;
  int lk4  = (t & 3) * 4;
  int kr = t >> 4;
  int nq = (t & 15) * 4;
  int tm = (t & 15) * 4;
  int tn = (t >> 4) * 4;
  float acc[4][4] = {};
  for (int k0 = 0; k0 < K; k0 += BK) {
    float4 av = make_float4(0.f,0.f,0.f,0.f);
    int am = m0 + lrow;
    if (am < M) av = *(const float4*)(A + (long)am*lda + k0 + lk4);
    As[lk4+0][lrow]=av.x; As[lk4+1][lrow]=av.y; As[lk4+2][lrow]=av.z; As[lk4+3][lrow]=av.w;
    long roff = brow ? (long)brow[k0+kr]*ldb : (long)(k0+kr)*ldb;
    const float* bp = B + roff + n0 + nq;
    if (n0 + nq + 3 < N) {
      float4 bv = *(const float4*)bp;
      Bs[kr][nq+0]=bv.x; Bs[kr][nq+1]=bv.y; Bs[kr][nq+2]=bv.z; Bs[kr][nq+3]=bv.w;
    } else {
      #pragma unroll
      for (int j=0;j<4;++j) Bs[kr][nq+j] = (n0+nq+j < N) ? bp[j] : 0.f;
    }
    __syncthreads();
    #pragma unroll
    for (int kk = 0; kk < BK; ++kk) {
      float4 a = *(const float4*)&As[kk][tm];
      float4 b = *(const float4*)&Bs[kk][tn];
      float aa[4]={a.x,a.y,a.z,a.w}, bb[4]={b.x,b.y,b.z,b.w};
      #pragma unroll
      for (int i=0;i<4;++i)
        #pragma unroll
        for (int j=0;j<4;++j) acc[i][j] += aa[i]*bb[j];
    }
    __syncthreads();
  }
  #pragma unroll
  for (int i=0;i<4;++i){
    int m = m0 + tm + i;
    if (m < M){
      long cro = (long)m*ldc;
      #pragma unroll
      for (int j=0;j<4;++j){
        int n = n0 + tn + j;
        if (n < N) C[cro + n] = alpha*acc[i][j];
      }
    }
  }
}

// ---------------- small kernels ----------------
__global__ void k_tr(const float* __restrict__ in, float* __restrict__ out, int R, int C){
  __shared__ float tile[32][33];
  long zo = (long)blockIdx.z * R * C;
  int r0 = blockIdx.y*32, c0 = blockIdx.x*32;
  int tx = threadIdx.x, ty = threadIdx.y;
  #pragma unroll
  for (int j=0;j<32;j+=8)
    tile[ty+j][tx] = in[zo + (long)(r0+ty+j)*C + c0+tx];
  __syncthreads();
  #pragma unroll
  for (int j=0;j<32;j+=8)
    out[zo + (long)(c0+ty+j)*R + r0+tx] = tile[tx][ty+j];
}

__global__ __launch_bounds__(256) void k_rowstats(const float* __restrict__ X, long ldx, int cols,
                                                  float* __restrict__ mu, float* __restrict__ m2){
  int r = blockIdx.x;
  const float* row = X + (long)r*ldx;
  float s=0.f, s2=0.f;
  for (int c = threadIdx.x*4; c < cols; c += 1024){
    float4 v = *(const float4*)(row+c);
    s  += v.x+v.y+v.z+v.w;
    s2 += v.x*v.x+v.y*v.y+v.z*v.z+v.w*v.w;
  }
  __shared__ float red[8];
  s  = block_sum(s,  red);
  s2 = block_sum(s2, red);
  if (threadIdx.x==0){ mu[r]=s/(float)cols; m2[r]=s2; }
}

__global__ __launch_bounds__(256) void k_softmax_gram(float* __restrict__ S, const float* __restrict__ m2xs){
  int r = blockIdx.x;
  int b = r / 288, p = r % 288;
  float* row = S + (long)r * 288;
  const float* m2 = m2xs + (long)b*288;
  float rp = 1.f / fmaxf(sqrtf(m2[p]), 1e-12f);
  int tid = threadIdx.x;
  __shared__ float red[8];
  float lv[2];
  #pragma unroll
  for (int i=0;i<2;++i){
    int q = tid + i*256;
    lv[i] = (q<288) ? row[q]*rp/fmaxf(sqrtf(m2[q]),1e-12f) : -1e30f;
  }
  float mx = fmaxf(lv[0], lv[1]);
  mx = block_max(mx, red);
  float s = 0.f;
  #pragma unroll
  for (int i=0;i<2;++i){
    int q = tid + i*256;
    float e = (q<288) ? expf(lv[i]-mx) : 0.f;
    lv[i]=e; s+=e;
  }
  s = block_sum(s, red);
  float inv = 1.f/s;
  #pragma unroll
  for (int i=0;i<2;++i){ int q = tid + i*256; if (q<288) row[q]=lv[i]*inv; }
}

__global__ __launch_bounds__(256) void k_softmax_plain(float* __restrict__ X, int L){
  int r = blockIdx.x;
  float* row = X + (long)r * L;
  int tid = threadIdx.x;
  __shared__ float red[8];
  float lv[8];
  #pragma unroll
  for (int i=0;i<8;++i){ int q = tid + i*256; lv[i] = (q<L) ? row[q] : -1e30f; }
  float mx = -1e30f;
  #pragma unroll
  for (int i=0;i<8;++i) mx = fmaxf(mx, lv[i]);
  mx = block_max(mx, red);
  float s = 0.f;
  #pragma unroll
  for (int i=0;i<8;++i){ int q = tid + i*256; float e = (q<L)?expf(lv[i]-mx):0.f; lv[i]=e; s+=e; }
  s = block_sum(s, red);
  float inv = 1.f/s;
  #pragma unroll
  for (int i=0;i<8;++i){ int q = tid + i*256; if (q<L) row[q]=lv[i]*inv; }
}

// softmax over L=1152 with per-288-segment additive bias scale*CC[r][SB[b][j]]
__global__ __launch_bounds__(256) void k_softmax_seg(float* __restrict__ X, const float* __restrict__ CC,
                                                     const int* __restrict__ SB, float scale){
  int r = blockIdx.x; int b = r>>4;
  float* row = X + (long)r*1152;
  float bias[4];
  #pragma unroll
  for (int j=0;j<4;++j) bias[j] = scale*CC[(long)r*32 + SB[b*4+j]];
  int tid = threadIdx.x;
  __shared__ float red[8];
  float lv[5];
  #pragma unroll
  for (int i=0;i<5;++i){
    int q = tid + i*256;
    lv[i] = (q<1152) ? row[q] + bias[q/288] : -1e30f;
  }
  float mx = -1e30f;
  #pragma unroll
  for (int i=0;i<5;++i) mx = fmaxf(mx, lv[i]);
  mx = block_max(mx, red);
  float s = 0.f;
  #pragma unroll
  for (int i=0;i<5;++i){ int q = tid + i*256; float e = (q<1152)?expf(lv[i]-mx):0.f; lv[i]=e; s+=e; }
  s = block_sum(s, red);
  float inv = 1.f/s;
  #pragma unroll
  for (int i=0;i<5;++i){ int q = tid + i*256; if (q<1152) row[q]=lv[i]*inv; }
}

__global__ void k_ln_apply(const float* __restrict__ X, const float* __restrict__ mu,
                           const float* __restrict__ m2, float* __restrict__ Y){
  int r = blockIdx.y; int c = blockIdx.x*256 + threadIdx.x;
  float m = mu[r];
  float v = m2[r]*(1.f/2048.f) - m*m;
  float inv = rsqrtf(v + 1e-5f);
  long idx = (long)r*2048 + c;
  Y[idx] = (X[idx] - m)*inv;
}

__global__ void k_meanx(const float* __restrict__ frel, float* __restrict__ mx){
  int b = blockIdx.y; int c = blockIdx.x*256 + threadIdx.x;
  const float* base = frel + (long)b*16*2048 + c;
  float s=0.f;
  #pragma unroll
  for (int q=0;q<16;++q) s += base[(long)q*2048];
  mx[(long)b*2048 + c] = s * (1.f/16.f);
}

__global__ void k_sigma(const float* __restrict__ pm, const float* __restrict__ mu_p,
                        const float* __restrict__ m2_p, const float* __restrict__ mu_m,
                        const float* __restrict__ m2_m, float* __restrict__ sigma){
  int b = blockIdx.y; int n = blockIdx.x*256 + threadIdx.x;
  float mp = mu_p[n], mm = mu_m[b];
  float vp = m2_p[n]*(1.f/2048.f) - mp*mp;
  float vm = m2_m[b]*(1.f/2048.f) - mm*mm;
  float cov = pm[(long)b*2048+n]*(1.f/2048.f) - mp*mm;
  sigma[(long)b*2048+n] = sqrtf(fmaxf(vp + vm - 2.f*cov, 0.f) + 1e-5f);
}

__global__ void k_fixrow(float* __restrict__ X, const float* __restrict__ mu_row,
                         const float* __restrict__ mu_w){
  int r = blockIdx.y; int d = blockIdx.x*256 + threadIdx.x;
  X[(long)r*2048 + d] -= mu_row[r] * mu_w[d] * 2048.f;
}

__global__ __launch_bounds__(256) void k_qm(const float* __restrict__ relq2,
                                            const float* __restrict__ Mx, float* __restrict__ qm){
  int r = blockIdx.x; int b = r >> 4;
  const float* a = relq2 + (long)r*2048;
  const float* m = Mx + (long)b*2048;
  float s=0.f;
  for (int c = threadIdx.x*4; c < 2048; c += 1024){
    float4 va=*(const float4*)(a+c), vm=*(const float4*)(m+c);
    s += va.x*vm.x+va.y*vm.y+va.z*vm.z+va.w*vm.w;
  }
  __shared__ float red[8];
  s = block_sum(s, red);
  if (threadIdx.x==0) qm[r]=s;
}

__global__ __launch_bounds__(256) void k_score2(float* __restrict__ QPw, const float* __restrict__ qm,
                                                const float* __restrict__ sigma, const float* __restrict__ mu_p,
                                                float* __restrict__ W1, float* __restrict__ Wmu, float scale){
  int r = blockIdx.x; int b = r >> 4;
  float* row = QPw + (long)r*2048;
  const float* sg = sigma + (long)b*2048;
  int tid = threadIdx.x;
  __shared__ float red[8];
  float qmr = qm[r];
  float lv[8], ls[8];
  #pragma unroll
  for (int i=0;i<8;++i){
    int n = tid + i*256;
    float sgn = sg[n];
    ls[i] = sgn;
    lv[i] = scale * (row[n] - qmr) / sgn;
  }
  float mx = -1e30f;
  #pragma unroll
  for (int i=0;i<8;++i) mx = fmaxf(mx, lv[i]);
  mx = block_max(mx, red);
  float se=0.f, sw=0.f, swm=0.f;
  #pragma unroll
  for (int i=0;i<8;++i){
    int n = tid + i*256;
    float e = expf(lv[i]-mx);
    lv[i] = e; se += e;
    float wv = e/ls[i];
    sw += wv; swm += wv*mu_p[n];
  }
  se  = block_sum(se,  red);
  sw  = block_sum(sw,  red);
  swm = block_sum(swm, red);
  float inv = 1.f/se;
  #pragma unroll
  for (int i=0;i<8;++i){ int n = tid + i*256; row[n] = lv[i]*inv/ls[i]; }
  if (tid==0){ W1[r]=sw*inv; Wmu[r]=swm*inv; }
}

__global__ void k_fpro_final(const float* __restrict__ frel, const float* __restrict__ out2,
                             const float* __restrict__ meanx, const float* __restrict__ mu_m,
                             const float* __restrict__ W1, const float* __restrict__ Wmu,
                             const float* __restrict__ wsm,
                             float* __restrict__ fpro, float* __restrict__ fout){
  int r = blockIdx.y; int c = blockIdx.x*256 + threadIdx.x;
  int b = r >> 4, q = r & 15;
  long idx = (long)r*2048 + c;
  float w1 = W1[r];
  float v = frel[idx] + out2[idx] - meanx[(long)b*2048+c]*w1 - Wmu[r] + mu_m[b]*w1;
  fpro[idx] = v;
  fout[idx] = wsm[q] * v;
}

__global__ void k_camb(const float* __restrict__ cam_table, const int* __restrict__ cam_ids,
                       float* __restrict__ camb){
  int b = blockIdx.y; int c = blockIdx.x*256 + threadIdx.x;
  camb[(long)b*2048 + c] = cam_table[(long)(cam_ids[b]-1)*2048 + c];
}

__global__ void k_wsoft(const float* __restrict__ w, float* __restrict__ wsm){
  if (threadIdx.x==0){
    float mx=-1e30f;
    for (int i=0;i<16;++i) mx=fmaxf(mx,w[i]);
    float e[16], s=0.f;
    for (int i=0;i<16;++i){ e[i]=expf(w[i]-mx); s+=e[i]; }
    for (int i=0;i<16;++i) wsm[i]=e[i]/s;
  }
}

__global__ void k_perm(const void* __restrict__ subp, int* __restrict__ gidx, int* __restrict__ SB){
  __shared__ int perm[32];
  if (threadIdx.x==0){
    const int* pi = (const int*)subp;
    const float* pf = (const float*)subp;
    const unsigned char* pb = (const unsigned char*)subp;
    int sv[32]; bool okI=true, okF=true;
    for (int i=0;i<32;++i){ int v=pi[i]; if (v!=0 && v!=1) okI=false; }
    for (int i=0;i<32;++i){ float f=pf[i]; if (f!=0.f && f!=1.f) okF=false; }
    for (int i=0;i<32;++i){
      if (okI) sv[i]=pi[i];
      else if (okF) sv[i]=(pf[i]!=0.f)?1:0;
      else sv[i]=(pb[i]!=0)?1:0;
    }
    int pos=0;
    for (int i=0;i<32;++i) if (!sv[i]) perm[pos++]=i;
    for (int i=0;i<32;++i) if ( sv[i]) perm[pos++]=i;
  }
  __syncthreads();
  for (int i = threadIdx.x; i < 128; i += blockDim.x){
    int b = i>>2, j = i&3;
    SB[i] = ((perm[b]>>2)<<2) + j;
  }
  for (int idx = threadIdx.x; idx < 32*1152; idx += blockDim.x){
    int b = idx / 1152, rem = idx % 1152, j = rem / 288, n = rem % 288;
    int src = ((perm[b] >> 2) << 2) + j;
    gidx[idx] = src*288 + n;
  }
}

// ---------------- launcher ----------------
extern "C" void kernel_launch(void* const* d_in, const int* in_sizes, int n_in,
                              void* d_out, int out_size, void* d_ws, size_t ws_size,
                              hipStream_t stream) {
  const float* x        = (const float*)d_in[0];   // [32,2048,288]
  const int*   cam_ids  = (const int*)d_in[1];
  const void*  subp     = d_in[2];
  const float* query_v  = (const float*)d_in[3];   // [16,2048]
  const float* proto    = (const float*)d_in[4];   // [2048,2048]
  const float* weights  = (const float*)d_in[5];   // [16]
  const float* cam_tab  = (const float*)d_in[6];   // [6,2048]
  const float* Wcq      = (const float*)d_in[8];
  const float* Wcg      = (const float*)d_in[9];
  const float* Wdq      = (const float*)d_in[10];
  const float* Wdg      = (const float*)d_in[11];
  float* out = (float*)d_out;
  float* ws  = (float*)d_ws;

  // workspace (floats). XS region (18.9M) reused: WCGT/PROTOT/P + PART scratch.
  size_t o = 0;
  float* XS    = ws + o; o += 18874368;
  float* WCGT  = XS;                    // alias: valid after GMIX computed
  float* PROTOT= XS + 4194304;
  float* P     = XS + 8388608;
  float* PART  = XS + 12582912;         // 6.29M floats split-K partials scratch
  float* GMIX  = ws + o; o += 18874368; // gram partials live here pre-GMIX
  float* S     = ws + o; o += 2654208;
  float* MU_XS = ws + o; o += 9216;
  float* M2_XS = ws + o; o += 9216;
  float* CAMB  = ws + o; o += 65536;
  float* RQ0   = ws + o; o += 32768;
  float* RQW   = ws + o; o += 32768;
  float* SREL  = ws + o; o += 147456;
  float* MU_FR = ws + o; o += 512;
  float* M2_FR = ws + o; o += 512;
  float* QLN   = ws + o; o += 1048576;
  float* RELQ2 = ws + o; o += 1048576;
  float* MEANX = ws + o; o += 65536;
  float* MU_P  = ws + o; o += 2048;
  float* M2_P  = ws + o; o += 2048;
  float* MU_M  = ws + o; o += 64;
  float* M2_M  = ws + o; o += 64;
  float* MU_W  = ws + o; o += 2048;
  float* M2_W  = ws + o; o += 2048;
  float* PM    = ws + o; o += 65536;
  float* SIGMA = ws + o; o += 65536;
  float* MX    = ws + o; o += 65536;
  float* QP    = ws + o; o += 1048576;
  float* QM    = ws + o; o += 512;
  float* W1    = ws + o; o += 512;
  float* WMU   = ws + o; o += 512;
  float* OUT2  = ws + o; o += 1048576;
  float* FPRO  = ws + o; o += 1048576;
  float* RQ2   = ws + o; o += 1048576;
  float* RQW2  = ws + o; o += 1048576;
  float* SREC  = ws + o; o += 147456;
  float* SCOR  = ws + o; o += 589824;
  float* CC    = ws + o; o += 16384;
  float* WSM   = ws + o; o += 16;
  int*   GIDX  = (int*)(ws + o); o += 36864;
  int*   SB    = (int*)(ws + o); o += 128;

  float* F_REL = out;
  float* F_PRO = out + 1048576;
  float* F_REC = out + 2097152;
  float* F_COR = out + 3145728;

  // ---- Phase A: shared patch self-attention ----
  k_tr<<<dim3(9,64,32), dim3(32,8), 0, stream>>>(x, XS, 2048, 288);     // XS [b][288][2048]
  k_rowstats<<<9216, 256, 0, stream>>>(XS, 2048, 2048, MU_XS, M2_XS);
  // gram: S[b] = XS[b].XS[b]^T, split-K=8, partials in (dead) GMIX region
  gemm_nt_mfma<3,3,2,2><<<dim3(3,3,256), 256, 0, stream>>>(S, XS, XS, 288,288,2048,
      2048,2048,288, 589824,589824,82944, 1.f, nullptr,0, 8, GMIX);
  k_reduce<<<1024, 256, 0, stream>>>(S, GMIX, 2654208L, 7, 1.f);
  k_softmax_gram<<<9216, 256, 0, stream>>>(S, M2_XS);
  // gmix[b] = S[b] . xs[b]  ==  NT(S[b], x[b]); grid already 1536 blocks
  gemm_nt_mfma<3,4,2,2><<<dim3(16,3,32), 256, 0, stream>>>(GMIX, S, x, 288,2048,288,
      288,288,2048, 82944,589824,589824, 1.f, nullptr,0, 1, nullptr);
  // XS dead: reuse region
  k_tr<<<dim3(64,64,1), dim3(32,8), 0, stream>>>(Wcg, WCGT, 2048, 2048);
  k_tr<<<dim3(64,64,1), dim3(32,8), 0, stream>>>(proto, PROTOT, 2048, 2048);
  k_camb<<<dim3(8,32), 256, 0, stream>>>(cam_tab, cam_ids, CAMB);
  k_perm<<<1, 256, 0, stream>>>(subp, GIDX, SB);

  // ---- f_rel ----
  gemm_nt_mfma<1,4,1,4><<<dim3(8,1,8), 256, 0, stream>>>(RQ0, query_v, Wcq, 16,2048,2048,
      2048,2048,2048, 0,0,0, 1.f, nullptr,0, 8, PART);
  k_reduce<<<64, 256, 0, stream>>>(RQ0, PART, 32768L, 7, 1.f);
  gemm_nt_mfma<1,4,1,4><<<dim3(8,1,8), 256, 0, stream>>>(RQW, RQ0, WCGT, 16,2048,2048,
      2048,2048,2048, 0,0,0, 1.f, nullptr,0, 8, PART);
  k_reduce<<<64, 256, 0, stream>>>(RQW, PART, 32768L, 7, 1.f);
  gemm_nt_mfma<1,4,1,4><<<dim3(2,1,128), 256, 0, stream>>>(SREL, RQW, GMIX, 16,288,2048,
      2048,2048,288, 0,589824,4608, SCALE, nullptr,0, 4, PART);
  k_reduce<<<256, 256, 0, stream>>>(SREL, PART, 147456L, 3, SCALE);
  k_softmax_plain<<<512, 256, 0, stream>>>(SREL, 288);
  gemm_nn<<<dim3(32,1,32), 256, 0, stream>>>(F_REL, SREL, GMIX, 16,2048,288, 288,2048,2048,
                                             4608,589824,32768, 1.f, nullptr,0);

  // ---- deltaor (decomposed LN algebra) ----
  k_rowstats<<<512, 256, 0, stream>>>(F_REL, 2048, 2048, MU_FR, M2_FR);
  k_ln_apply<<<dim3(8,512), 256, 0, stream>>>(F_REL, MU_FR, M2_FR, QLN);
  k_meanx<<<dim3(8,32), 256, 0, stream>>>(F_REL, MEANX);
  k_rowstats<<<32,   256, 0, stream>>>(MEANX, 2048, 2048, MU_M, M2_M);
  k_rowstats<<<2048, 256, 0, stream>>>(proto, 2048, 2048, MU_P, M2_P);
  k_rowstats<<<2048, 256, 0, stream>>>(Wdg,   2048, 2048, MU_W, M2_W);
  gemm_nt_mfma<2,4,2,2><<<dim3(16,8,4), 256, 0, stream>>>(RELQ2, QLN, Wdq, 512,2048,2048,
      2048,2048,2048, 0,0,0, 1.f, nullptr,0, 4, PART);
  k_reduce<<<1024, 256, 0, stream>>>(RELQ2, PART, 1048576L, 3, 1.f);
  gemm_nt_mfma<1,4,1,4><<<dim3(8,2,8), 256, 0, stream>>>(PM, MEANX, proto, 32,2048,2048,
      2048,2048,2048, 0,0,0, 1.f, nullptr,0, 8, PART);
  k_reduce<<<256, 256, 0, stream>>>(PM, PART, 65536L, 7, 1.f);
  k_sigma<<<dim3(8,32), 256, 0, stream>>>(PM, MU_P, M2_P, MU_M, M2_M, SIGMA);
  gemm_nt_mfma<4,4,2,2><<<dim3(16,16,2), 256, 0, stream>>>(P, proto, Wdg, 2048,2048,2048,
      2048,2048,2048, 0,0,0, 1.f, nullptr,0, 2, PART);
  k_reduce<<<1024, 256, 0, stream>>>(P, PART, 4194304L, 1, 1.f);
  k_fixrow<<<dim3(8,2048), 256, 0, stream>>>(P, MU_P, MU_W);
  gemm_nt_mfma<1,4,1,4><<<dim3(8,2,8), 256, 0, stream>>>(MX, MEANX, Wdg, 32,2048,2048,
      2048,2048,2048, 0,0,0, 1.f, nullptr,0, 8, PART);
  k_reduce<<<256, 256, 0, stream>>>(MX, PART, 65536L, 7, 1.f);
  k_fixrow<<<dim3(8,32), 256, 0, stream>>>(MX, MU_M, MU_W);
  gemm_nt_mfma<2,4,2,2><<<dim3(16,8,4), 256, 0, stream>>>(QP, RELQ2, P, 512,2048,2048,
      2048,2048,2048, 0,0,0, 1.f, nullptr,0, 4, PART);
  k_reduce<<<1024, 256, 0, stream>>>(QP, PART, 1048576L, 3, 1.f);
  k_qm<<<512, 256, 0, stream>>>(RELQ2, MX, QM);
  k_score2<<<512, 256, 0, stream>>>(QP, QM, SIGMA, MU_P, W1, WMU, SCALE);
  gemm_nt_mfma<2,4,2,2><<<dim3(16,8,4), 256, 0, stream>>>(OUT2, QP, PROTOT, 512,2048,2048,
      2048,2048,2048, 0,0,0, 1.f, nullptr,0, 4, PART);
  k_reduce<<<1024, 256, 0, stream>>>(OUT2, PART, 1048576L, 3, 1.f);
  k_wsoft<<<1, 64, 0, stream>>>(weights, WSM);
  k_fpro_final<<<dim3(8,512), 256, 0, stream>>>(F_REL, OUT2, MEANX, MU_M, W1, WMU, WSM,
                                                FPRO, F_PRO);

  // ---- f_rec ----
  gemm_nt_mfma<2,4,2,2><<<dim3(16,8,4), 256, 0, stream>>>(RQ2, FPRO, Wcq, 512,2048,2048,
      2048,2048,2048, 0,0,0, 1.f, nullptr,0, 4, PART);
  k_reduce<<<1024, 256, 0, stream>>>(RQ2, PART, 1048576L, 3, 1.f);
  gemm_nt_mfma<2,4,2,2><<<dim3(16,8,4), 256, 0, stream>>>(RQW2, RQ2, WCGT, 512,2048,2048,
      2048,2048,2048, 0,0,0, 1.f, nullptr,0, 4, PART);
  k_reduce<<<1024, 256, 0, stream>>>(RQW2, PART, 1048576L, 3, 1.f);
  gemm_nt_mfma<1,4,1,4><<<dim3(2,1,128), 256, 0, stream>>>(SREC, RQW2, GMIX, 16,288,2048,
      2048,2048,288, 32768,589824,4608, SCALE, nullptr,0, 4, PART);
  k_reduce<<<256, 256, 0, stream>>>(SREC, PART, 147456L, 3, SCALE);
  k_softmax_plain<<<512, 256, 0, stream>>>(SREC, 288);
  gemm_nn<<<dim3(32,1,32), 256, 0, stream>>>(F_REC, SREC, GMIX, 16,2048,288, 288,2048,2048,
                                             4608,589824,32768, 1.f, nullptr,0);

  // ---- f_cor ----
  gemm_nt_mfma<1,4,1,4><<<dim3(1,32,8), 256, 0, stream>>>(CC, RQW2, CAMB, 512,32,2048,
      2048,2048,32, 0,0,0, 1.f, nullptr,0, 8, PART);
  k_reduce<<<64, 256, 0, stream>>>(CC, PART, 16384L, 7, 1.f);
  gemm_nt_mfma<1,4,1,4><<<dim3(5,1,64), 256, 0, stream>>>(SCOR, RQW2, GMIX, 16,1152,2048,
      2048,2048,1152, 32768,0,18432, SCALE, GIDX,1152, 2, PART);
  k_reduce<<<512, 256, 0, stream>>>(SCOR, PART, 589824L, 1, SCALE);
  k_softmax_seg<<<512, 256, 0, stream>>>(SCOR, CC, SB, SCALE);
  gemm_nn<<<dim3(32,1,32), 256, 0, stream>>>(F_COR, SCOR, GMIX, 16,2048,1152, 1152,2048,2048,
                                             18432,0,32768, 1.f, GIDX,1152);
}

// Round 4
// 1166.986 us; speedup vs baseline: 3.4922x; 1.0230x over previous
//
#include <hip/hip_runtime.h>
#include <math.h>

// B=32, C=2048, N=288(==PATCH), Q=16, proto tokens=2048
static constexpr float SCALE = 0.022097086912079612f; // 2048^-0.5

typedef __bf16 bf16x4 __attribute__((ext_vector_type(4)));
typedef __bf16 bf16x8 __attribute__((ext_vector_type(8)));
typedef float  f32x4  __attribute__((ext_vector_type(4)));

// ---------------- reduction helpers ----------------
__device__ __forceinline__ float wred_sum(float v){
  #pragma unroll
  for (int o=32;o>0;o>>=1) v += __shfl_down(v,o,64);
  return v;
}
__device__ __forceinline__ float wred_max(float v){
  #pragma unroll
  for (int o=32;o>0;o>>=1) v = fmaxf(v, __shfl_down(v,o,64));
  return v;
}
__device__ __forceinline__ float block_sum(float v, float* red){
  int tid=threadIdx.x, w=tid>>6, l=tid&63, nw=(int)(blockDim.x>>6);
  v = wred_sum(v);
  __syncthreads();
  if (l==0) red[w]=v;
  __syncthreads();
  float r=0.f;
  for (int i=0;i<nw;i++) r += red[i];
  return r;
}
__device__ __forceinline__ float block_max(float v, float* red){
  int tid=threadIdx.x, w=tid>>6, l=tid&63, nw=(int)(blockDim.x>>6);
  v = wred_max(v);
  __syncthreads();
  if (l==0) red[w]=v;
  __syncthreads();
  float r=red[0];
  for (int i=1;i<nw;i++) r = fmaxf(r, red[i]);
  return r;
}

// ---------------- MFMA split-bf16 NT GEMM with split-K ----------------
template<int MT, int NT, int WM, int WN>
__global__ __launch_bounds__(256, 2)
void gemm_nt_mfma(float* __restrict__ Cm, const float* __restrict__ Am,
                  const float* __restrict__ Bm, int M, int N, int K,
                  int lda, int ldb, int ldc, long sA, long sB, long sC,
                  float alpha, const int* __restrict__ browidx, long sBrow,
                  int KS, float* __restrict__ Part)
{
  constexpr int BM = MT*16*WM;
  constexpr int BN = NT*16*WN;
  constexpr int LDH = 40;
  constexpr int AST = (BM+31)/32;
  constexpr int BST = (BN+31)/32;
  __shared__ __bf16 Ah[BM*LDH];
  __shared__ __bf16 Al[BM*LDH];
  __shared__ __bf16 Bh[BN*LDH];
  __shared__ __bf16 Bl[BN*LDH];
  int ZZ = gridDim.z / KS;
  int z  = blockIdx.z % ZZ;
  int ks = blockIdx.z / ZZ;
  const float* A = Am + (long)z*sA;
  const float* B = Bm + (long)z*sB;
  float* C = Cm + (long)z*sC;
  const bool useB = (browidx != nullptr);
  const int* brow = useB ? (browidx + (long)z*sBrow) : nullptr;
  int Kc = ((K + KS*32 - 1) / (KS*32)) * 32;
  int kbeg = ks*Kc;
  int kend = min(K, kbeg + Kc);
  int m0 = blockIdx.y*BM, n0 = blockIdx.x*BN;
  int t = threadIdx.x;
  int srow = t>>3, skoff = (t&7)*4;

  float4 areg[AST], breg[BST];
  auto loadAB = [&](int k0){
    #pragma unroll
    for (int s=0;s<AST;++s){
      int row = srow + 32*s; int gm = m0+row;
      areg[s] = make_float4(0.f,0.f,0.f,0.f);
      if (row < BM && gm < M) areg[s] = *(const float4*)(A + (long)gm*lda + k0 + skoff);
    }
    #pragma unroll
    for (int s=0;s<BST;++s){
      int row = srow + 32*s; int gn = n0+row;
      breg[s] = make_float4(0.f,0.f,0.f,0.f);
      if (row < BN && gn < N){
        long r = useB ? (long)brow[gn] : (long)gn;
        breg[s] = *(const float4*)(B + r*ldb + k0 + skoff);
      }
    }
  };
  auto writeLDS = [&](){
    #pragma unroll
    for (int s=0;s<AST;++s){
      int row = srow + 32*s;
      if (row < BM){
        float vv[4] = {areg[s].x, areg[s].y, areg[s].z, areg[s].w};
        bf16x4 hv, lv;
        #pragma unroll
        for (int e=0;e<4;++e){
          __bf16 h = (__bf16)vv[e];
          hv[e] = h;
          lv[e] = (__bf16)(vv[e] - (float)h);
        }
        *(bf16x4*)&Ah[row*LDH + skoff] = hv;
        *(bf16x4*)&Al[row*LDH + skoff] = lv;
      }
    }
    #pragma unroll
    for (int s=0;s<BST;++s){
      int row = srow + 32*s;
      if (row < BN){
        float vv[4] = {breg[s].x, breg[s].y, breg[s].z, breg[s].w};
        bf16x4 hv, lv;
        #pragma unroll
        for (int e=0;e<4;++e){
          __bf16 h = (__bf16)vv[e];
          hv[e] = h;
          lv[e] = (__bf16)(vv[e] - (float)h);
        }
        *(bf16x4*)&Bh[row*LDH + skoff] = hv;
        *(bf16x4*)&Bl[row*LDH + skoff] = lv;
      }
    }
  };

  int lane = t & 63, wid = t >> 6;
  int wm = (WM==1) ? 0 : (wid / WN);
  int wn = wid % WN;
  int mw = wm*MT*16, nw = wn*NT*16;
  int fr = lane & 15, fq = (lane>>4)*8;

  f32x4 acc[MT][NT];
  #pragma unroll
  for (int i=0;i<MT;++i)
    #pragma unroll
    for (int j=0;j<NT;++j) acc[i][j] = (f32x4){0.f,0.f,0.f,0.f};

  if (kbeg < kend) loadAB(kbeg);
  for (int k0=kbeg; k0<kend; k0+=32){
    writeLDS();
    __syncthreads();
    if (k0+32 < kend) loadAB(k0+32);
    bf16x8 ah[MT], al[MT], bh[NT], bl[NT];
    #pragma unroll
    for (int i=0;i<MT;++i){
      ah[i] = *(const bf16x8*)&Ah[(mw+i*16+fr)*LDH + fq];
      al[i] = *(const bf16x8*)&Al[(mw+i*16+fr)*LDH + fq];
    }
    #pragma unroll
    for (int j=0;j<NT;++j){
      bh[j] = *(const bf16x8*)&Bh[(nw+j*16+fr)*LDH + fq];
      bl[j] = *(const bf16x8*)&Bl[(nw+j*16+fr)*LDH + fq];
    }
    #pragma unroll
    for (int i=0;i<MT;++i)
      #pragma unroll
      for (int j=0;j<NT;++j){
        acc[i][j] = __builtin_amdgcn_mfma_f32_16x16x32_bf16(ah[i], bh[j], acc[i][j], 0,0,0);
        acc[i][j] = __builtin_amdgcn_mfma_f32_16x16x32_bf16(ah[i], bl[j], acc[i][j], 0,0,0);
        acc[i][j] = __builtin_amdgcn_mfma_f32_16x16x32_bf16(al[i], bh[j], acc[i][j], 0,0,0);
      }
    __syncthreads();
  }
  float wf = (KS==1) ? alpha : 1.f;
  float* Cw = C; int ldw = ldc;
  if (ks > 0){ Cw = Part + ((long)(ks-1)*ZZ + z)*(long)M*N; ldw = N; }
  int er = (lane>>4)*4, ec = lane & 15;
  #pragma unroll
  for (int i=0;i<MT;++i){
    int mbase = m0 + mw + i*16 + er;
    #pragma unroll
    for (int r=0;r<4;++r){
      int mm = mbase + r;
      if (mm < M){
        long cro = (long)mm*ldw;
        #pragma unroll
        for (int j=0;j<NT;++j){
          int nn = n0 + nw + j*16 + ec;
          if (nn < N) Cw[cro + nn] = wf*acc[i][j][r];
        }
      }
    }
  }
}

// C[i] = alpha * (C[i] + sum_s Part[s*total + i])
__global__ __launch_bounds__(256) void k_reduce(float* __restrict__ C, const float* __restrict__ Part,
                                                long total, int S, float alpha){
  for (long i = (long)blockIdx.x*blockDim.x + threadIdx.x; i < total;
       i += (long)gridDim.x*blockDim.x){
    float v = C[i];
    for (int s=0;s<S;++s) v += Part[(long)s*total + i];
    C[i] = alpha*v;
  }
}

// ---------------- fused skinny PV: C[b][16][2048] = P[b][16][K] . G[rows][2048] ----
// G rows per k: segment j=k/288 (SB gather if SB!=null, else batch b), row k%288.
// Split-K via blockIdx.z (KS=2): ks==0 -> C, ks==1 -> Part (same layout).
__global__ __launch_bounds__(256) void k_pv(
    float* __restrict__ C, float* __restrict__ Part,
    const float* __restrict__ Pm, long sP, int K,
    const float* __restrict__ G, long sG, const int* __restrict__ SB)
{
  extern __shared__ float Pl[];   // [16][Kc]
  int b = blockIdx.y, ks = blockIdx.z, KS = gridDim.z;
  int c = blockIdx.x*256 + threadIdx.x;
  int Kc = K / KS;
  int kbeg = ks * Kc;
  const float* Pb = Pm + (long)b*sP;
  for (int i = threadIdx.x; i < 16*Kc; i += 256){
    int q = i / Kc, kk = i - q*Kc;
    Pl[q*Kc + kk] = Pb[(long)q*K + kbeg + kk];
  }
  __syncthreads();
  float acc[16];
  #pragma unroll
  for (int q=0;q<16;++q) acc[q]=0.f;
  for (int kk=0; kk<Kc; kk+=4){
    int kg = kbeg + kk;
    int seg = kg / 288, row = kg - seg*288;
    const float* base = SB ? (G + (long)SB[(b<<2)+seg]*sG) : (G + (long)b*sG);
    float g0 = base[(long)(row+0)*2048 + c];
    float g1 = base[(long)(row+1)*2048 + c];
    float g2 = base[(long)(row+2)*2048 + c];
    float g3 = base[(long)(row+3)*2048 + c];
    #pragma unroll
    for (int q=0;q<16;++q){
      f32x4 p = *(const f32x4*)&Pl[q*Kc + kk];
      acc[q] += p[0]*g0 + p[1]*g1 + p[2]*g2 + p[3]*g3;
    }
  }
  float* Cw = (ks==0) ? C : Part;
  long base = (long)b*16*2048 + c;
  #pragma unroll
  for (int q=0;q<16;++q) Cw[base + (long)q*2048] = acc[q];
}

// ---------------- small kernels ----------------
__global__ void k_tr(const float* __restrict__ in, float* __restrict__ out, int R, int C){
  __shared__ float tile[32][33];
  long zo = (long)blockIdx.z * R * C;
  int r0 = blockIdx.y*32, c0 = blockIdx.x*32;
  int tx = threadIdx.x, ty = threadIdx.y;
  #pragma unroll
  for (int j=0;j<32;j+=8)
    tile[ty+j][tx] = in[zo + (long)(r0+ty+j)*C + c0+tx];
  __syncthreads();
  #pragma unroll
  for (int j=0;j<32;j+=8)
    out[zo + (long)(c0+ty+j)*R + r0+tx] = tile[tx][ty+j];
}

__global__ __launch_bounds__(256) void k_rowstats(const float* __restrict__ X, long ldx, int cols,
                                                  float* __restrict__ mu, float* __restrict__ m2){
  int r = blockIdx.x;
  const float* row = X + (long)r*ldx;
  float s=0.f, s2=0.f;
  for (int c = threadIdx.x*4; c < cols; c += 1024){
    float4 v = *(const float4*)(row+c);
    s  += v.x+v.y+v.z+v.w;
    s2 += v.x*v.x+v.y*v.y+v.z*v.z+v.w*v.w;
  }
  __shared__ float red[8];
  s  = block_sum(s,  red);
  s2 = block_sum(s2, red);
  if (threadIdx.x==0){ mu[r]=s/(float)cols; m2[r]=s2; }
}

__global__ __launch_bounds__(256) void k_softmax_gram(float* __restrict__ S, const float* __restrict__ m2xs){
  int r = blockIdx.x;
  int b = r / 288, p = r % 288;
  float* row = S + (long)r * 288;
  const float* m2 = m2xs + (long)b*288;
  float rp = 1.f / fmaxf(sqrtf(m2[p]), 1e-12f);
  int tid = threadIdx.x;
  __shared__ float red[8];
  float lv[2];
  #pragma unroll
  for (int i=0;i<2;++i){
    int q = tid + i*256;
    lv[i] = (q<288) ? row[q]*rp/fmaxf(sqrtf(m2[q]),1e-12f) : -1e30f;
  }
  float mx = fmaxf(lv[0], lv[1]);
  mx = block_max(mx, red);
  float s = 0.f;
  #pragma unroll
  for (int i=0;i<2;++i){
    int q = tid + i*256;
    float e = (q<288) ? expf(lv[i]-mx) : 0.f;
    lv[i]=e; s+=e;
  }
  s = block_sum(s, red);
  float inv = 1.f/s;
  #pragma unroll
  for (int i=0;i<2;++i){ int q = tid + i*256; if (q<288) row[q]=lv[i]*inv; }
}

__global__ __launch_bounds__(256) void k_softmax_plain(float* __restrict__ X, int L){
  int r = blockIdx.x;
  float* row = X + (long)r * L;
  int tid = threadIdx.x;
  __shared__ float red[8];
  float lv[8];
  #pragma unroll
  for (int i=0;i<8;++i){ int q = tid + i*256; lv[i] = (q<L) ? row[q] : -1e30f; }
  float mx = -1e30f;
  #pragma unroll
  for (int i=0;i<8;++i) mx = fmaxf(mx, lv[i]);
  mx = block_max(mx, red);
  float s = 0.f;
  #pragma unroll
  for (int i=0;i<8;++i){ int q = tid + i*256; float e = (q<L)?expf(lv[i]-mx):0.f; lv[i]=e; s+=e; }
  s = block_sum(s, red);
  float inv = 1.f/s;
  #pragma unroll
  for (int i=0;i<8;++i){ int q = tid + i*256; if (q<L) row[q]=lv[i]*inv; }
}

__global__ __launch_bounds__(256) void k_softmax_seg(float* __restrict__ X, const float* __restrict__ CC,
                                                     const int* __restrict__ SB, float scale){
  int r = blockIdx.x; int b = r>>4;
  float* row = X + (long)r*1152;
  float bias[4];
  #pragma unroll
  for (int j=0;j<4;++j) bias[j] = scale*CC[(long)r*32 + SB[b*4+j]];
  int tid = threadIdx.x;
  __shared__ float red[8];
  float lv[5];
  #pragma unroll
  for (int i=0;i<5;++i){
    int q = tid + i*256;
    lv[i] = (q<1152) ? row[q] + bias[q/288] : -1e30f;
  }
  float mx = -1e30f;
  #pragma unroll
  for (int i=0;i<5;++i) mx = fmaxf(mx, lv[i]);
  mx = block_max(mx, red);
  float s = 0.f;
  #pragma unroll
  for (int i=0;i<5;++i){ int q = tid + i*256; float e = (q<1152)?expf(lv[i]-mx):0.f; lv[i]=e; s+=e; }
  s = block_sum(s, red);
  float inv = 1.f/s;
  #pragma unroll
  for (int i=0;i<5;++i){ int q = tid + i*256; if (q<1152) row[q]=lv[i]*inv; }
}

__global__ void k_ln_apply(const float* __restrict__ X, const float* __restrict__ mu,
                           const float* __restrict__ m2, float* __restrict__ Y){
  int r = blockIdx.y; int c = blockIdx.x*256 + threadIdx.x;
  float m = mu[r];
  float v = m2[r]*(1.f/2048.f) - m*m;
  float inv = rsqrtf(v + 1e-5f);
  long idx = (long)r*2048 + c;
  Y[idx] = (X[idx] - m)*inv;
}

__global__ void k_meanx(const float* __restrict__ frel, float* __restrict__ mx){
  int b = blockIdx.y; int c = blockIdx.x*256 + threadIdx.x;
  const float* base = frel + (long)b*16*2048 + c;
  float s=0.f;
  #pragma unroll
  for (int q=0;q<16;++q) s += base[(long)q*2048];
  mx[(long)b*2048 + c] = s * (1.f/16.f);
}

__global__ void k_sigma(const float* __restrict__ pm, const float* __restrict__ mu_p,
                        const float* __restrict__ m2_p, const float* __restrict__ mu_m,
                        const float* __restrict__ m2_m, float* __restrict__ sigma){
  int b = blockIdx.y; int n = blockIdx.x*256 + threadIdx.x;
  float mp = mu_p[n], mm = mu_m[b];
  float vp = m2_p[n]*(1.f/2048.f) - mp*mp;
  float vm = m2_m[b]*(1.f/2048.f) - mm*mm;
  float cov = pm[(long)b*2048+n]*(1.f/2048.f) - mp*mm;
  sigma[(long)b*2048+n] = sqrtf(fmaxf(vp + vm - 2.f*cov, 0.f) + 1e-5f);
}

__global__ void k_fixrow(float* __restrict__ X, const float* __restrict__ mu_row,
                         const float* __restrict__ mu_w){
  int r = blockIdx.y; int d = blockIdx.x*256 + threadIdx.x;
  X[(long)r*2048 + d] -= mu_row[r] * mu_w[d] * 2048.f;
}

__global__ __launch_bounds__(256) void k_qm(const float* __restrict__ relq2,
                                            const float* __restrict__ Mx, float* __restrict__ qm){
  int r = blockIdx.x; int b = r >> 4;
  const float* a = relq2 + (long)r*2048;
  const float* m = Mx + (long)b*2048;
  float s=0.f;
  for (int c = threadIdx.x*4; c < 2048; c += 1024){
    float4 va=*(const float4*)(a+c), vm=*(const float4*)(m+c);
    s += va.x*vm.x+va.y*vm.y+va.z*vm.z+va.w*vm.w;
  }
  __shared__ float red[8];
  s = block_sum(s, red);
  if (threadIdx.x==0) qm[r]=s;
}

__global__ __launch_bounds__(256) void k_score2(float* __restrict__ QPw, const float* __restrict__ qm,
                                                const float* __restrict__ sigma, const float* __restrict__ mu_p,
                                                float* __restrict__ W1, float* __restrict__ Wmu, float scale){
  int r = blockIdx.x; int b = r >> 4;
  float* row = QPw + (long)r*2048;
  const float* sg = sigma + (long)b*2048;
  int tid = threadIdx.x;
  __shared__ float red[8];
  float qmr = qm[r];
  float lv[8], ls[8];
  #pragma unroll
  for (int i=0;i<8;++i){
    int n = tid + i*256;
    float sgn = sg[n];
    ls[i] = sgn;
    lv[i] = scale * (row[n] - qmr) / sgn;
  }
  float mx = -1e30f;
  #pragma unroll
  for (int i=0;i<8;++i) mx = fmaxf(mx, lv[i]);
  mx = block_max(mx, red);
  float se=0.f, sw=0.f, swm=0.f;
  #pragma unroll
  for (int i=0;i<8;++i){
    int n = tid + i*256;
    float e = expf(lv[i]-mx);
    lv[i] = e; se += e;
    float wv = e/ls[i];
    sw += wv; swm += wv*mu_p[n];
  }
  se  = block_sum(se,  red);
  sw  = block_sum(sw,  red);
  swm = block_sum(swm, red);
  float inv = 1.f/se;
  #pragma unroll
  for (int i=0;i<8;++i){ int n = tid + i*256; row[n] = lv[i]*inv/ls[i]; }
  if (tid==0){ W1[r]=sw*inv; Wmu[r]=swm*inv; }
}

__global__ void k_fpro_final(const float* __restrict__ frel, const float* __restrict__ out2,
                             const float* __restrict__ meanx, const float* __restrict__ mu_m,
                             const float* __restrict__ W1, const float* __restrict__ Wmu,
                             const float* __restrict__ wsm,
                             float* __restrict__ fpro, float* __restrict__ fout){
  int r = blockIdx.y; int c = blockIdx.x*256 + threadIdx.x;
  int b = r >> 4, q = r & 15;
  long idx = (long)r*2048 + c;
  float w1 = W1[r];
  float v = frel[idx] + out2[idx] - meanx[(long)b*2048+c]*w1 - Wmu[r] + mu_m[b]*w1;
  fpro[idx] = v;
  fout[idx] = wsm[q] * v;
}

__global__ void k_camb(const float* __restrict__ cam_table, const int* __restrict__ cam_ids,
                       float* __restrict__ camb){
  int b = blockIdx.y; int c = blockIdx.x*256 + threadIdx.x;
  camb[(long)b*2048 + c] = cam_table[(long)(cam_ids[b]-1)*2048 + c];
}

__global__ void k_wsoft(const float* __restrict__ w, float* __restrict__ wsm){
  if (threadIdx.x==0){
    float mx=-1e30f;
    for (int i=0;i<16;++i) mx=fmaxf(mx,w[i]);
    float e[16], s=0.f;
    for (int i=0;i<16;++i){ e[i]=expf(w[i]-mx); s+=e[i]; }
    for (int i=0;i<16;++i) wsm[i]=e[i]/s;
  }
}

__global__ void k_perm(const void* __restrict__ subp, int* __restrict__ gidx, int* __restrict__ SB){
  __shared__ int perm[32];
  if (threadIdx.x==0){
    const int* pi = (const int*)subp;
    const float* pf = (const float*)subp;
    const unsigned char* pb = (const unsigned char*)subp;
    int sv[32]; bool okI=true, okF=true;
    for (int i=0;i<32;++i){ int v=pi[i]; if (v!=0 && v!=1) okI=false; }
    for (int i=0;i<32;++i){ float f=pf[i]; if (f!=0.f && f!=1.f) okF=false; }
    for (int i=0;i<32;++i){
      if (okI) sv[i]=pi[i];
      else if (okF) sv[i]=(pf[i]!=0.f)?1:0;
      else sv[i]=(pb[i]!=0)?1:0;
    }
    int pos=0;
    for (int i=0;i<32;++i) if (!sv[i]) perm[pos++]=i;
    for (int i=0;i<32;++i) if ( sv[i]) perm[pos++]=i;
  }
  __syncthreads();
  for (int i = threadIdx.x; i < 128; i += blockDim.x){
    int b = i>>2, j = i&3;
    SB[i] = ((perm[b]>>2)<<2) + j;
  }
  for (int idx = threadIdx.x; idx < 32*1152; idx += blockDim.x){
    int b = idx / 1152, rem = idx % 1152, j = rem / 288, n = rem % 288;
    int src = ((perm[b] >> 2) << 2) + j;
    gidx[idx] = src*288 + n;
  }
}

// ---------------- launcher ----------------
extern "C" void kernel_launch(void* const* d_in, const int* in_sizes, int n_in,
                              void* d_out, int out_size, void* d_ws, size_t ws_size,
                              hipStream_t stream) {
  const float* x        = (const float*)d_in[0];   // [32,2048,288]
  const int*   cam_ids  = (const int*)d_in[1];
  const void*  subp     = d_in[2];
  const float* query_v  = (const float*)d_in[3];   // [16,2048]
  const float* proto    = (const float*)d_in[4];   // [2048,2048]
  const float* weights  = (const float*)d_in[5];   // [16]
  const float* cam_tab  = (const float*)d_in[6];   // [6,2048]
  const float* Wcq      = (const float*)d_in[8];
  const float* Wcg      = (const float*)d_in[9];
  const float* Wdq      = (const float*)d_in[10];
  const float* Wdg      = (const float*)d_in[11];
  float* out = (float*)d_out;
  float* ws  = (float*)d_ws;

  // workspace (floats). XS region (18.9M) reused: WCGT/PROTOT/P + PART scratch.
  size_t o = 0;
  float* XS    = ws + o; o += 18874368;
  float* WCGT  = XS;
  float* PROTOT= XS + 4194304;
  float* P     = XS + 8388608;
  float* PART  = XS + 12582912;
  float* GMIX  = ws + o; o += 18874368;
  float* S     = ws + o; o += 2654208;
  float* MU_XS = ws + o; o += 9216;
  float* M2_XS = ws + o; o += 9216;
  float* CAMB  = ws + o; o += 65536;
  float* RQ0   = ws + o; o += 32768;
  float* RQW   = ws + o; o += 32768;
  float* SREL  = ws + o; o += 147456;
  float* MU_FR = ws + o; o += 512;
  float* M2_FR = ws + o; o += 512;
  float* QLN   = ws + o; o += 1048576;
  float* RELQ2 = ws + o; o += 1048576;
  float* MEANX = ws + o; o += 65536;
  float* MU_P  = ws + o; o += 2048;
  float* M2_P  = ws + o; o += 2048;
  float* MU_M  = ws + o; o += 64;
  float* M2_M  = ws + o; o += 64;
  float* MU_W  = ws + o; o += 2048;
  float* M2_W  = ws + o; o += 2048;
  float* PM    = ws + o; o += 65536;
  float* SIGMA = ws + o; o += 65536;
  float* MX    = ws + o; o += 65536;
  float* QP    = ws + o; o += 1048576;
  float* QM    = ws + o; o += 512;
  float* W1    = ws + o; o += 512;
  float* WMU   = ws + o; o += 512;
  float* OUT2  = ws + o; o += 1048576;
  float* FPRO  = ws + o; o += 1048576;
  float* RQ2   = ws + o; o += 1048576;
  float* RQW2  = ws + o; o += 1048576;
  float* SREC  = ws + o; o += 147456;
  float* SCOR  = ws + o; o += 589824;
  float* CC    = ws + o; o += 16384;
  float* WSM   = ws + o; o += 16;
  int*   GIDX  = (int*)(ws + o); o += 36864;
  int*   SB    = (int*)(ws + o); o += 128;

  float* F_REL = out;
  float* F_PRO = out + 1048576;
  float* F_REC = out + 2097152;
  float* F_COR = out + 3145728;

  // ---- Phase A: shared patch self-attention ----
  k_tr<<<dim3(9,64,32), dim3(32,8), 0, stream>>>(x, XS, 2048, 288);
  k_rowstats<<<9216, 256, 0, stream>>>(XS, 2048, 2048, MU_XS, M2_XS);
  gemm_nt_mfma<3,3,2,2><<<dim3(3,3,256), 256, 0, stream>>>(S, XS, XS, 288,288,2048,
      2048,2048,288, 589824,589824,82944, 1.f, nullptr,0, 8, GMIX);
  k_reduce<<<1024, 256, 0, stream>>>(S, GMIX, 2654208L, 7, 1.f);
  k_softmax_gram<<<9216, 256, 0, stream>>>(S, M2_XS);
  gemm_nt_mfma<3,4,2,2><<<dim3(16,3,32), 256, 0, stream>>>(GMIX, S, x, 288,2048,288,
      288,288,2048, 82944,589824,589824, 1.f, nullptr,0, 1, nullptr);
  k_tr<<<dim3(64,64,1), dim3(32,8), 0, stream>>>(Wcg, WCGT, 2048, 2048);
  k_tr<<<dim3(64,64,1), dim3(32,8), 0, stream>>>(proto, PROTOT, 2048, 2048);
  k_camb<<<dim3(8,32), 256, 0, stream>>>(cam_tab, cam_ids, CAMB);
  k_perm<<<1, 256, 0, stream>>>(subp, GIDX, SB);

  // ---- f_rel ----
  gemm_nt_mfma<1,4,1,4><<<dim3(8,1,8), 256, 0, stream>>>(RQ0, query_v, Wcq, 16,2048,2048,
      2048,2048,2048, 0,0,0, 1.f, nullptr,0, 8, PART);
  k_reduce<<<64, 256, 0, stream>>>(RQ0, PART, 32768L, 7, 1.f);
  gemm_nt_mfma<1,4,1,4><<<dim3(8,1,8), 256, 0, stream>>>(RQW, RQ0, WCGT, 16,2048,2048,
      2048,2048,2048, 0,0,0, 1.f, nullptr,0, 8, PART);
  k_reduce<<<64, 256, 0, stream>>>(RQW, PART, 32768L, 7, 1.f);
  gemm_nt_mfma<1,4,1,4><<<dim3(2,1,128), 256, 0, stream>>>(SREL, RQW, GMIX, 16,288,2048,
      2048,2048,288, 0,589824,4608, SCALE, nullptr,0, 4, PART);
  k_reduce<<<256, 256, 0, stream>>>(SREL, PART, 147456L, 3, SCALE);
  k_softmax_plain<<<512, 256, 0, stream>>>(SREL, 288);
  k_pv<<<dim3(8,32,2), 256, 16*144*4, stream>>>(F_REL, PART, SREL, 4608, 288,
      GMIX, 589824, nullptr);
  k_reduce<<<1024, 256, 0, stream>>>(F_REL, PART, 1048576L, 1, 1.f);

  // ---- deltaor (decomposed LN algebra) ----
  k_rowstats<<<512, 256, 0, stream>>>(F_REL, 2048, 2048, MU_FR, M2_FR);
  k_ln_apply<<<dim3(8,512), 256, 0, stream>>>(F_REL, MU_FR, M2_FR, QLN);
  k_meanx<<<dim3(8,32), 256, 0, stream>>>(F_REL, MEANX);
  k_rowstats<<<32,   256, 0, stream>>>(MEANX, 2048, 2048, MU_M, M2_M);
  k_rowstats<<<2048, 256, 0, stream>>>(proto, 2048, 2048, MU_P, M2_P);
  k_rowstats<<<2048, 256, 0, stream>>>(Wdg,   2048, 2048, MU_W, M2_W);
  gemm_nt_mfma<2,4,2,2><<<dim3(16,8,4), 256, 0, stream>>>(RELQ2, QLN, Wdq, 512,2048,2048,
      2048,2048,2048, 0,0,0, 1.f, nullptr,0, 4, PART);
  k_reduce<<<1024, 256, 0, stream>>>(RELQ2, PART, 1048576L, 3, 1.f);
  gemm_nt_mfma<1,4,1,4><<<dim3(8,2,8), 256, 0, stream>>>(PM, MEANX, proto, 32,2048,2048,
      2048,2048,2048, 0,0,0, 1.f, nullptr,0, 8, PART);
  k_reduce<<<256, 256, 0, stream>>>(PM, PART, 65536L, 7, 1.f);
  k_sigma<<<dim3(8,32), 256, 0, stream>>>(PM, MU_P, M2_P, MU_M, M2_M, SIGMA);
  gemm_nt_mfma<4,4,2,2><<<dim3(16,16,2), 256, 0, stream>>>(P, proto, Wdg, 2048,2048,2048,
      2048,2048,2048, 0,0,0, 1.f, nullptr,0, 2, PART);
  k_reduce<<<1024, 256, 0, stream>>>(P, PART, 4194304L, 1, 1.f);
  k_fixrow<<<dim3(8,2048), 256, 0, stream>>>(P, MU_P, MU_W);
  gemm_nt_mfma<1,4,1,4><<<dim3(8,2,8), 256, 0, stream>>>(MX, MEANX, Wdg, 32,2048,2048,
      2048,2048,2048, 0,0,0, 1.f, nullptr,0, 8, PART);
  k_reduce<<<256, 256, 0, stream>>>(MX, PART, 65536L, 7, 1.f);
  k_fixrow<<<dim3(8,32), 256, 0, stream>>>(MX, MU_M, MU_W);
  gemm_nt_mfma<2,4,2,2><<<dim3(16,8,4), 256, 0, stream>>>(QP, RELQ2, P, 512,2048,2048,
      2048,2048,2048, 0,0,0, 1.f, nullptr,0, 4, PART);
  k_reduce<<<1024, 256, 0, stream>>>(QP, PART, 1048576L, 3, 1.f);
  k_qm<<<512, 256, 0, stream>>>(RELQ2, MX, QM);
  k_score2<<<512, 256, 0, stream>>>(QP, QM, SIGMA, MU_P, W1, WMU, SCALE);
  gemm_nt_mfma<2,4,2,2><<<dim3(16,8,4), 256, 0, stream>>>(OUT2, QP, PROTOT, 512,2048,2048,
      2048,2048,2048, 0,0,0, 1.f, nullptr,0, 4, PART);
  k_reduce<<<1024, 256, 0, stream>>>(OUT2, PART, 1048576L, 3, 1.f);
  k_wsoft<<<1, 64, 0, stream>>>(weights, WSM);
  k_fpro_final<<<dim3(8,512), 256, 0, stream>>>(F_REL, OUT2, MEANX, MU_M, W1, WMU, WSM,
                                                FPRO, F_PRO);

  // ---- f_rec ----
  gemm_nt_mfma<2,4,2,2><<<dim3(16,8,4), 256, 0, stream>>>(RQ2, FPRO, Wcq, 512,2048,2048,
      2048,2048,2048, 0,0,0, 1.f, nullptr,0, 4, PART);
  k_reduce<<<1024, 256, 0, stream>>>(RQ2, PART, 1048576L, 3, 1.f);
  gemm_nt_mfma<2,4,2,2><<<dim3(16,8,4), 256, 0, stream>>>(RQW2, RQ2, WCGT, 512,2048,2048,
      2048,2048,2048, 0,0,0, 1.f, nullptr,0, 4, PART);
  k_reduce<<<1024, 256, 0, stream>>>(RQW2, PART, 1048576L, 3, 1.f);
  gemm_nt_mfma<1,4,1,4><<<dim3(2,1,128), 256, 0, stream>>>(SREC, RQW2, GMIX, 16,288,2048,
      2048,2048,288, 32768,589824,4608, SCALE, nullptr,0, 4, PART);
  k_reduce<<<256, 256, 0, stream>>>(SREC, PART, 147456L, 3, SCALE);
  k_softmax_plain<<<512, 256, 0, stream>>>(SREC, 288);
  k_pv<<<dim3(8,32,2), 256, 16*144*4, stream>>>(F_REC, PART, SREC, 4608, 288,
      GMIX, 589824, nullptr);
  k_reduce<<<1024, 256, 0, stream>>>(F_REC, PART, 1048576L, 1, 1.f);

  // ---- f_cor ----
  gemm_nt_mfma<1,4,1,4><<<dim3(1,32,8), 256, 0, stream>>>(CC, RQW2, CAMB, 512,32,2048,
      2048,2048,32, 0,0,0, 1.f, nullptr,0, 8, PART);
  k_reduce<<<64, 256, 0, stream>>>(CC, PART, 16384L, 7, 1.f);
  gemm_nt_mfma<1,4,1,4><<<dim3(5,1,64), 256, 0, stream>>>(SCOR, RQW2, GMIX, 16,1152,2048,
      2048,2048,1152, 32768,0,18432, SCALE, GIDX,1152, 2, PART);
  k_reduce<<<512, 256, 0, stream>>>(SCOR, PART, 589824L, 1, SCALE);
  k_softmax_seg<<<512, 256, 0, stream>>>(SCOR, CC, SB, SCALE);
  k_pv<<<dim3(8,32,2), 256, 16*576*4, stream>>>(F_COR, PART, SCOR, 18432, 1152,
      GMIX, 589824, SB);
  k_reduce<<<1024, 256, 0, stream>>>(F_COR, PART, 1048576L, 1, 1.f);
}

// Round 5
// 1151.182 us; speedup vs baseline: 3.5401x; 1.0137x over previous
//
#include <hip/hip_runtime.h>
#include <math.h>

// B=32, C=2048, N=288(==PATCH), Q=16, proto tokens=2048
static constexpr float SCALE = 0.022097086912079612f; // 2048^-0.5

typedef __bf16 bf16x4 __attribute__((ext_vector_type(4)));
typedef __bf16 bf16x8 __attribute__((ext_vector_type(8)));
typedef float  f32x4  __attribute__((ext_vector_type(4)));

// ---------------- reduction helpers ----------------
__device__ __forceinline__ float wred_sum(float v){
  #pragma unroll
  for (int o=32;o>0;o>>=1) v += __shfl_down(v,o,64);
  return v;
}
__device__ __forceinline__ float wred_max(float v){
  #pragma unroll
  for (int o=32;o>0;o>>=1) v = fmaxf(v, __shfl_down(v,o,64));
  return v;
}
__device__ __forceinline__ float block_sum(float v, float* red){
  int tid=threadIdx.x, w=tid>>6, l=tid&63, nw=(int)(blockDim.x>>6);
  v = wred_sum(v);
  __syncthreads();
  if (l==0) red[w]=v;
  __syncthreads();
  float r=0.f;
  for (int i=0;i<nw;i++) r += red[i];
  return r;
}
__device__ __forceinline__ float block_max(float v, float* red){
  int tid=threadIdx.x, w=tid>>6, l=tid&63, nw=(int)(blockDim.x>>6);
  v = wred_max(v);
  __syncthreads();
  if (l==0) red[w]=v;
  __syncthreads();
  float r=red[0];
  for (int i=1;i<nw;i++) r = fmaxf(r, red[i]);
  return r;
}

// ---------------- MFMA split-bf16 NT GEMM with split-K ----------------
template<int MT, int NT, int WM, int WN>
__global__ __launch_bounds__(256, 2)
void gemm_nt_mfma(float* __restrict__ Cm, const float* __restrict__ Am,
                  const float* __restrict__ Bm, int M, int N, int K,
                  int lda, int ldb, int ldc, long sA, long sB, long sC,
                  float alpha, const int* __restrict__ browidx, long sBrow,
                  int KS, float* __restrict__ Part)
{
  constexpr int BM = MT*16*WM;
  constexpr int BN = NT*16*WN;
  constexpr int LDH = 40;
  constexpr int AST = (BM+31)/32;
  constexpr int BST = (BN+31)/32;
  __shared__ __bf16 Ah[BM*LDH];
  __shared__ __bf16 Al[BM*LDH];
  __shared__ __bf16 Bh[BN*LDH];
  __shared__ __bf16 Bl[BN*LDH];
  int ZZ = gridDim.z / KS;
  int z  = blockIdx.z % ZZ;
  int ks = blockIdx.z / ZZ;
  const float* A = Am + (long)z*sA;
  const float* B = Bm + (long)z*sB;
  float* C = Cm + (long)z*sC;
  const bool useB = (browidx != nullptr);
  const int* brow = useB ? (browidx + (long)z*sBrow) : nullptr;
  int Kc = ((K + KS*32 - 1) / (KS*32)) * 32;
  int kbeg = ks*Kc;
  int kend = min(K, kbeg + Kc);
  int m0 = blockIdx.y*BM, n0 = blockIdx.x*BN;
  int t = threadIdx.x;
  int srow = t>>3, skoff = (t&7)*4;

  float4 areg[AST], breg[BST];
  auto loadAB = [&](int k0){
    #pragma unroll
    for (int s=0;s<AST;++s){
      int row = srow + 32*s; int gm = m0+row;
      areg[s] = make_float4(0.f,0.f,0.f,0.f);
      if (row < BM && gm < M) areg[s] = *(const float4*)(A + (long)gm*lda + k0 + skoff);
    }
    #pragma unroll
    for (int s=0;s<BST;++s){
      int row = srow + 32*s; int gn = n0+row;
      breg[s] = make_float4(0.f,0.f,0.f,0.f);
      if (row < BN && gn < N){
        long r = useB ? (long)brow[gn] : (long)gn;
        breg[s] = *(const float4*)(B + r*ldb + k0 + skoff);
      }
    }
  };
  auto writeLDS = [&](){
    #pragma unroll
    for (int s=0;s<AST;++s){
      int row = srow + 32*s;
      if (row < BM){
        float vv[4] = {areg[s].x, areg[s].y, areg[s].z, areg[s].w};
        bf16x4 hv, lv;
        #pragma unroll
        for (int e=0;e<4;++e){
          __bf16 h = (__bf16)vv[e];
          hv[e] = h;
          lv[e] = (__bf16)(vv[e] - (float)h);
        }
        *(bf16x4*)&Ah[row*LDH + skoff] = hv;
        *(bf16x4*)&Al[row*LDH + skoff] = lv;
      }
    }
    #pragma unroll
    for (int s=0;s<BST;++s){
      int row = srow + 32*s;
      if (row < BN){
        float vv[4] = {breg[s].x, breg[s].y, breg[s].z, breg[s].w};
        bf16x4 hv, lv;
        #pragma unroll
        for (int e=0;e<4;++e){
          __bf16 h = (__bf16)vv[e];
          hv[e] = h;
          lv[e] = (__bf16)(vv[e] - (float)h);
        }
        *(bf16x4*)&Bh[row*LDH + skoff] = hv;
        *(bf16x4*)&Bl[row*LDH + skoff] = lv;
      }
    }
  };

  int lane = t & 63, wid = t >> 6;
  int wm = (WM==1) ? 0 : (wid / WN);
  int wn = wid % WN;
  int mw = wm*MT*16, nw = wn*NT*16;
  int fr = lane & 15, fq = (lane>>4)*8;

  f32x4 acc[MT][NT];
  #pragma unroll
  for (int i=0;i<MT;++i)
    #pragma unroll
    for (int j=0;j<NT;++j) acc[i][j] = (f32x4){0.f,0.f,0.f,0.f};

  if (kbeg < kend) loadAB(kbeg);
  for (int k0=kbeg; k0<kend; k0+=32){
    writeLDS();
    __syncthreads();
    if (k0+32 < kend) loadAB(k0+32);
    bf16x8 ah[MT], al[MT], bh[NT], bl[NT];
    #pragma unroll
    for (int i=0;i<MT;++i){
      ah[i] = *(const bf16x8*)&Ah[(mw+i*16+fr)*LDH + fq];
      al[i] = *(const bf16x8*)&Al[(mw+i*16+fr)*LDH + fq];
    }
    #pragma unroll
    for (int j=0;j<NT;++j){
      bh[j] = *(const bf16x8*)&Bh[(nw+j*16+fr)*LDH + fq];
      bl[j] = *(const bf16x8*)&Bl[(nw+j*16+fr)*LDH + fq];
    }
    #pragma unroll
    for (int i=0;i<MT;++i)
      #pragma unroll
      for (int j=0;j<NT;++j){
        acc[i][j] = __builtin_amdgcn_mfma_f32_16x16x32_bf16(ah[i], bh[j], acc[i][j], 0,0,0);
        acc[i][j] = __builtin_amdgcn_mfma_f32_16x16x32_bf16(ah[i], bl[j], acc[i][j], 0,0,0);
        acc[i][j] = __builtin_amdgcn_mfma_f32_16x16x32_bf16(al[i], bh[j], acc[i][j], 0,0,0);
      }
    __syncthreads();
  }
  float wf = (KS==1) ? alpha : 1.f;
  float* Cw = C; int ldw = ldc;
  if (ks > 0){ Cw = Part + ((long)(ks-1)*ZZ + z)*(long)M*N; ldw = N; }
  int er = (lane>>4)*4, ec = lane & 15;
  #pragma unroll
  for (int i=0;i<MT;++i){
    int mbase = m0 + mw + i*16 + er;
    #pragma unroll
    for (int r=0;r<4;++r){
      int mm = mbase + r;
      if (mm < M){
        long cro = (long)mm*ldw;
        #pragma unroll
        for (int j=0;j<NT;++j){
          int nn = n0 + nw + j*16 + ec;
          if (nn < N) Cw[cro + nn] = wf*acc[i][j][r];
        }
      }
    }
  }
}

// C[i] = alpha * (C[i] + sum_s Part[s*total + i])
__global__ __launch_bounds__(256) void k_reduce(float* __restrict__ C, const float* __restrict__ Part,
                                                long total, int S, float alpha){
  for (long i = (long)blockIdx.x*blockDim.x + threadIdx.x; i < total;
       i += (long)gridDim.x*blockDim.x){
    float v = C[i];
    for (int s=0;s<S;++s) v += Part[(long)s*total + i];
    C[i] = alpha*v;
  }
}

// ---------------- fused skinny PV ----------------
__global__ __launch_bounds__(256) void k_pv(
    float* __restrict__ C, float* __restrict__ Part,
    const float* __restrict__ Pm, long sP, int K,
    const float* __restrict__ G, long sG, const int* __restrict__ SB)
{
  extern __shared__ float Pl[];   // [16][Kc]
  int b = blockIdx.y, ks = blockIdx.z, KS = gridDim.z;
  int c = blockIdx.x*256 + threadIdx.x;
  int Kc = K / KS;
  int kbeg = ks * Kc;
  const float* Pb = Pm + (long)b*sP;
  for (int i = threadIdx.x; i < 16*Kc; i += 256){
    int q = i / Kc, kk = i - q*Kc;
    Pl[q*Kc + kk] = Pb[(long)q*K + kbeg + kk];
  }
  __syncthreads();
  float acc[16];
  #pragma unroll
  for (int q=0;q<16;++q) acc[q]=0.f;
  for (int kk=0; kk<Kc; kk+=4){
    int kg = kbeg + kk;
    int seg = kg / 288, row = kg - seg*288;
    const float* base = SB ? (G + (long)SB[(b<<2)+seg]*sG) : (G + (long)b*sG);
    float g0 = base[(long)(row+0)*2048 + c];
    float g1 = base[(long)(row+1)*2048 + c];
    float g2 = base[(long)(row+2)*2048 + c];
    float g3 = base[(long)(row+3)*2048 + c];
    #pragma unroll
    for (int q=0;q<16;++q){
      f32x4 p = *(const f32x4*)&Pl[q*Kc + kk];
      acc[q] += p[0]*g0 + p[1]*g1 + p[2]*g2 + p[3]*g3;
    }
  }
  float* Cw = (ks==0) ? C : Part;
  long base = (long)b*16*2048 + c;
  #pragma unroll
  for (int q=0;q<16;++q) Cw[base + (long)q*2048] = acc[q];
}

// ---------------- small kernels ----------------
__global__ void k_tr(const float* __restrict__ in, float* __restrict__ out, int R, int C){
  __shared__ float tile[32][33];
  long zo = (long)blockIdx.z * R * C;
  int r0 = blockIdx.y*32, c0 = blockIdx.x*32;
  int tx = threadIdx.x, ty = threadIdx.y;
  #pragma unroll
  for (int j=0;j<32;j+=8)
    tile[ty+j][tx] = in[zo + (long)(r0+ty+j)*C + c0+tx];
  __syncthreads();
  #pragma unroll
  for (int j=0;j<32;j+=8)
    out[zo + (long)(c0+ty+j)*R + r0+tx] = tile[tx][ty+j];
}

__global__ __launch_bounds__(256) void k_rowstats(const float* __restrict__ X, long ldx, int cols,
                                                  float* __restrict__ mu, float* __restrict__ m2){
  int r = blockIdx.x;
  const float* row = X + (long)r*ldx;
  float s=0.f, s2=0.f;
  for (int c = threadIdx.x*4; c < cols; c += 1024){
    float4 v = *(const float4*)(row+c);
    s  += v.x+v.y+v.z+v.w;
    s2 += v.x*v.x+v.y*v.y+v.z*v.z+v.w*v.w;
  }
  __shared__ float red[8];
  s  = block_sum(s,  red);
  s2 = block_sum(s2, red);
  if (threadIdx.x==0){ mu[r]=s/(float)cols; m2[r]=s2; }
}

__global__ __launch_bounds__(256) void k_softmax_gram(float* __restrict__ S, const float* __restrict__ m2xs){
  int r = blockIdx.x;
  int b = r / 288, p = r % 288;
  float* row = S + (long)r * 288;
  const float* m2 = m2xs + (long)b*288;
  float rp = 1.f / fmaxf(sqrtf(m2[p]), 1e-12f);
  int tid = threadIdx.x;
  __shared__ float red[8];
  float lv[2];
  #pragma unroll
  for (int i=0;i<2;++i){
    int q = tid + i*256;
    lv[i] = (q<288) ? row[q]*rp/fmaxf(sqrtf(m2[q]),1e-12f) : -1e30f;
  }
  float mx = fmaxf(lv[0], lv[1]);
  mx = block_max(mx, red);
  float s = 0.f;
  #pragma unroll
  for (int i=0;i<2;++i){
    int q = tid + i*256;
    float e = (q<288) ? expf(lv[i]-mx) : 0.f;
    lv[i]=e; s+=e;
  }
  s = block_sum(s, red);
  float inv = 1.f/s;
  #pragma unroll
  for (int i=0;i<2;++i){ int q = tid + i*256; if (q<288) row[q]=lv[i]*inv; }
}

__global__ __launch_bounds__(256) void k_softmax_plain(float* __restrict__ X, int L){
  int r = blockIdx.x;
  float* row = X + (long)r * L;
  int tid = threadIdx.x;
  __shared__ float red[8];
  float lv[8];
  #pragma unroll
  for (int i=0;i<8;++i){ int q = tid + i*256; lv[i] = (q<L) ? row[q] : -1e30f; }
  float mx = -1e30f;
  #pragma unroll
  for (int i=0;i<8;++i) mx = fmaxf(mx, lv[i]);
  mx = block_max(mx, red);
  float s = 0.f;
  #pragma unroll
  for (int i=0;i<8;++i){ int q = tid + i*256; float e = (q<L)?expf(lv[i]-mx):0.f; lv[i]=e; s+=e; }
  s = block_sum(s, red);
  float inv = 1.f/s;
  #pragma unroll
  for (int i=0;i<8;++i){ int q = tid + i*256; if (q<L) row[q]=lv[i]*inv; }
}

__global__ __launch_bounds__(256) void k_softmax_seg(float* __restrict__ X, const float* __restrict__ CC,
                                                     const int* __restrict__ SB, float scale){
  int r = blockIdx.x; int b = r>>4;
  float* row = X + (long)r*1152;
  float bias[4];
  #pragma unroll
  for (int j=0;j<4;++j) bias[j] = scale*CC[(long)r*32 + SB[b*4+j]];
  int tid = threadIdx.x;
  __shared__ float red[8];
  float lv[5];
  #pragma unroll
  for (int i=0;i<5;++i){
    int q = tid + i*256;
    lv[i] = (q<1152) ? row[q] + bias[q/288] : -1e30f;
  }
  float mx = -1e30f;
  #pragma unroll
  for (int i=0;i<5;++i) mx = fmaxf(mx, lv[i]);
  mx = block_max(mx, red);
  float s = 0.f;
  #pragma unroll
  for (int i=0;i<5;++i){ int q = tid + i*256; float e = (q<1152)?expf(lv[i]-mx):0.f; lv[i]=e; s+=e; }
  s = block_sum(s, red);
  float inv = 1.f/s;
  #pragma unroll
  for (int i=0;i<5;++i){ int q = tid + i*256; if (q<1152) row[q]=lv[i]*inv; }
}

__global__ void k_ln_apply(const float* __restrict__ X, const float* __restrict__ mu,
                           const float* __restrict__ m2, float* __restrict__ Y){
  int r = blockIdx.y; int c = blockIdx.x*256 + threadIdx.x;
  float m = mu[r];
  float v = m2[r]*(1.f/2048.f) - m*m;
  float inv = rsqrtf(v + 1e-5f);
  long idx = (long)r*2048 + c;
  Y[idx] = (X[idx] - m)*inv;
}

__global__ void k_meanx(const float* __restrict__ frel, float* __restrict__ mx){
  int b = blockIdx.y; int c = blockIdx.x*256 + threadIdx.x;
  const float* base = frel + (long)b*16*2048 + c;
  float s=0.f;
  #pragma unroll
  for (int q=0;q<16;++q) s += base[(long)q*2048];
  mx[(long)b*2048 + c] = s * (1.f/16.f);
}

__global__ void k_sigma(const float* __restrict__ pm, const float* __restrict__ mu_p,
                        const float* __restrict__ m2_p, const float* __restrict__ mu_m,
                        const float* __restrict__ m2_m, float* __restrict__ sigma){
  int b = blockIdx.y; int n = blockIdx.x*256 + threadIdx.x;
  float mp = mu_p[n], mm = mu_m[b];
  float vp = m2_p[n]*(1.f/2048.f) - mp*mp;
  float vm = m2_m[b]*(1.f/2048.f) - mm*mm;
  float cov = pm[(long)b*2048+n]*(1.f/2048.f) - mp*mm;
  sigma[(long)b*2048+n] = sqrtf(fmaxf(vp + vm - 2.f*cov, 0.f) + 1e-5f);
}

__global__ void k_fixrow(float* __restrict__ X, const float* __restrict__ mu_row,
                         const float* __restrict__ mu_w){
  int r = blockIdx.y; int d = blockIdx.x*256 + threadIdx.x;
  X[(long)r*2048 + d] -= mu_row[r] * mu_w[d] * 2048.f;
}

__global__ __launch_bounds__(256) void k_qm(const float* __restrict__ relq2,
                                            const float* __restrict__ Mx, float* __restrict__ qm){
  int r = blockIdx.x; int b = r >> 4;
  const float* a = relq2 + (long)r*2048;
  const float* m = Mx + (long)b*2048;
  float s=0.f;
  for (int c = threadIdx.x*4; c < 2048; c += 1024){
    float4 va=*(const float4*)(a+c), vm=*(const float4*)(m+c);
    s += va.x*vm.x+va.y*vm.y+va.z*vm.z+va.w*vm.w;
  }
  __shared__ float red[8];
  s = block_sum(s, red);
  if (threadIdx.x==0) qm[r]=s;
}

__global__ __launch_bounds__(256) void k_score2(float* __restrict__ QPw, const float* __restrict__ qm,
                                                const float* __restrict__ sigma, const float* __restrict__ mu_p,
                                                float* __restrict__ W1, float* __restrict__ Wmu, float scale){
  int r = blockIdx.x; int b = r >> 4;
  float* row = QPw + (long)r*2048;
  const float* sg = sigma + (long)b*2048;
  int tid = threadIdx.x;
  __shared__ float red[8];
  float qmr = qm[r];
  float lv[8], ls[8];
  #pragma unroll
  for (int i=0;i<8;++i){
    int n = tid + i*256;
    float sgn = sg[n];
    ls[i] = sgn;
    lv[i] = scale * (row[n] - qmr) / sgn;
  }
  float mx = -1e30f;
  #pragma unroll
  for (int i=0;i<8;++i) mx = fmaxf(mx, lv[i]);
  mx = block_max(mx, red);
  float se=0.f, sw=0.f, swm=0.f;
  #pragma unroll
  for (int i=0;i<8;++i){
    int n = tid + i*256;
    float e = expf(lv[i]-mx);
    lv[i] = e; se += e;
    float wv = e/ls[i];
    sw += wv; swm += wv*mu_p[n];
  }
  se  = block_sum(se,  red);
  sw  = block_sum(sw,  red);
  swm = block_sum(swm, red);
  float inv = 1.f/se;
  #pragma unroll
  for (int i=0;i<8;++i){ int n = tid + i*256; row[n] = lv[i]*inv/ls[i]; }
  if (tid==0){ W1[r]=sw*inv; Wmu[r]=swm*inv; }
}

__global__ void k_fpro_final(const float* __restrict__ frel, const float* __restrict__ out2,
                             const float* __restrict__ meanx, const float* __restrict__ mu_m,
                             const float* __restrict__ W1, const float* __restrict__ Wmu,
                             const float* __restrict__ wsm,
                             float* __restrict__ fpro, float* __restrict__ fout){
  int r = blockIdx.y; int c = blockIdx.x*256 + threadIdx.x;
  int b = r >> 4, q = r & 15;
  long idx = (long)r*2048 + c;
  float w1 = W1[r];
  float v = frel[idx] + out2[idx] - meanx[(long)b*2048+c]*w1 - Wmu[r] + mu_m[b]*w1;
  fpro[idx] = v;
  fout[idx] = wsm[q] * v;
}

__global__ void k_camb(const float* __restrict__ cam_table, const int* __restrict__ cam_ids,
                       float* __restrict__ camb){
  int b = blockIdx.y; int c = blockIdx.x*256 + threadIdx.x;
  camb[(long)b*2048 + c] = cam_table[(long)(cam_ids[b]-1)*2048 + c];
}

__global__ void k_wsoft(const float* __restrict__ w, float* __restrict__ wsm){
  if (threadIdx.x==0){
    float mx=-1e30f;
    for (int i=0;i<16;++i) mx=fmaxf(mx,w[i]);
    float e[16], s=0.f;
    for (int i=0;i<16;++i){ e[i]=expf(w[i]-mx); s+=e[i]; }
    for (int i=0;i<16;++i) wsm[i]=e[i]/s;
  }
}

__global__ void k_perm(const void* __restrict__ subp, int* __restrict__ gidx, int* __restrict__ SB){
  __shared__ int perm[32];
  if (threadIdx.x==0){
    const int* pi = (const int*)subp;
    const float* pf = (const float*)subp;
    const unsigned char* pb = (const unsigned char*)subp;
    int sv[32]; bool okI=true, okF=true;
    for (int i=0;i<32;++i){ int v=pi[i]; if (v!=0 && v!=1) okI=false; }
    for (int i=0;i<32;++i){ float f=pf[i]; if (f!=0.f && f!=1.f) okF=false; }
    for (int i=0;i<32;++i){
      if (okI) sv[i]=pi[i];
      else if (okF) sv[i]=(pf[i]!=0.f)?1:0;
      else sv[i]=(pb[i]!=0)?1:0;
    }
    int pos=0;
    for (int i=0;i<32;++i) if (!sv[i]) perm[pos++]=i;
    for (int i=0;i<32;++i) if ( sv[i]) perm[pos++]=i;
  }
  __syncthreads();
  for (int i = threadIdx.x; i < 128; i += blockDim.x){
    int b = i>>2, j = i&3;
    SB[i] = ((perm[b]>>2)<<2) + j;
  }
  for (int idx = threadIdx.x; idx < 32*1152; idx += blockDim.x){
    int b = idx / 1152, rem = idx % 1152, j = rem / 288, n = rem % 288;
    int src = ((perm[b] >> 2) << 2) + j;
    gidx[idx] = src*288 + n;
  }
}

// ---------------- launcher ----------------
extern "C" void kernel_launch(void* const* d_in, const int* in_sizes, int n_in,
                              void* d_out, int out_size, void* d_ws, size_t ws_size,
                              hipStream_t stream) {
  const float* x        = (const float*)d_in[0];   // [32,2048,288]
  const int*   cam_ids  = (const int*)d_in[1];
  const void*  subp     = d_in[2];
  const float* query_v  = (const float*)d_in[3];   // [16,2048]
  const float* proto    = (const float*)d_in[4];   // [2048,2048]
  const float* weights  = (const float*)d_in[5];   // [16]
  const float* cam_tab  = (const float*)d_in[6];   // [6,2048]
  const float* Wcq      = (const float*)d_in[8];
  const float* Wcg      = (const float*)d_in[9];
  const float* Wdq      = (const float*)d_in[10];
  const float* Wdg      = (const float*)d_in[11];
  float* out = (float*)d_out;
  float* ws  = (float*)d_ws;

  size_t o = 0;
  float* XS    = ws + o; o += 18874368;
  float* WCGT  = XS;
  float* PROTOT= XS + 4194304;
  float* P     = XS + 8388608;
  float* PART  = XS + 12582912;     // 6,291,456 floats
  float* GMIX  = ws + o; o += 18874368;
  float* S     = ws + o; o += 2654208;
  float* MU_XS = ws + o; o += 9216;
  float* M2_XS = ws + o; o += 9216;
  float* CAMB  = ws + o; o += 65536;
  float* RQ0   = ws + o; o += 32768;
  float* RQW   = ws + o; o += 32768;
  float* SREL  = ws + o; o += 147456;
  float* MU_FR = ws + o; o += 512;
  float* M2_FR = ws + o; o += 512;
  float* QLN   = ws + o; o += 1048576;
  float* RELQ2 = ws + o; o += 1048576;
  float* MEANX = ws + o; o += 65536;
  float* MU_P  = ws + o; o += 2048;
  float* M2_P  = ws + o; o += 2048;
  float* MU_M  = ws + o; o += 64;
  float* M2_M  = ws + o; o += 64;
  float* MU_W  = ws + o; o += 2048;
  float* M2_W  = ws + o; o += 2048;
  float* PM    = ws + o; o += 65536;
  float* SIGMA = ws + o; o += 65536;
  float* MX    = ws + o; o += 65536;
  float* QP    = ws + o; o += 1048576;
  float* QM    = ws + o; o += 512;
  float* W1    = ws + o; o += 512;
  float* WMU   = ws + o; o += 512;
  float* OUT2  = ws + o; o += 1048576;
  float* FPRO  = ws + o; o += 1048576;
  float* RQ2   = ws + o; o += 1048576;
  float* RQW2  = ws + o; o += 1048576;
  float* SREC  = ws + o; o += 147456;
  float* SCOR  = ws + o; o += 589824;
  float* CC    = ws + o; o += 16384;
  float* WSM   = ws + o; o += 16;
  int*   GIDX  = (int*)(ws + o); o += 36864;
  int*   SB    = (int*)(ws + o); o += 128;

  float* F_REL = out;
  float* F_PRO = out + 1048576;
  float* F_REC = out + 2097152;
  float* F_COR = out + 3145728;

  // ---- Phase A: shared patch self-attention ----
  k_tr<<<dim3(9,64,32), dim3(32,8), 0, stream>>>(x, XS, 2048, 288);
  k_rowstats<<<9216, 256, 0, stream>>>(XS, 2048, 2048, MU_XS, M2_XS);
  gemm_nt_mfma<3,3,2,2><<<dim3(3,3,256), 256, 0, stream>>>(S, XS, XS, 288,288,2048,
      2048,2048,288, 589824,589824,82944, 1.f, nullptr,0, 8, GMIX);
  k_reduce<<<1024, 256, 0, stream>>>(S, GMIX, 2654208L, 7, 1.f);
  k_softmax_gram<<<9216, 256, 0, stream>>>(S, M2_XS);
  gemm_nt_mfma<3,4,2,2><<<dim3(16,3,32), 256, 0, stream>>>(GMIX, S, x, 288,2048,288,
      288,288,2048, 82944,589824,589824, 1.f, nullptr,0, 1, nullptr);
  k_tr<<<dim3(64,64,1), dim3(32,8), 0, stream>>>(Wcg, WCGT, 2048, 2048);
  k_tr<<<dim3(64,64,1), dim3(32,8), 0, stream>>>(proto, PROTOT, 2048, 2048);
  k_camb<<<dim3(8,32), 256, 0, stream>>>(cam_tab, cam_ids, CAMB);
  k_perm<<<1, 256, 0, stream>>>(subp, GIDX, SB);

  // ---- f_rel ----
  gemm_nt_mfma<1,4,1,4><<<dim3(8,1,8), 256, 0, stream>>>(RQ0, query_v, Wcq, 16,2048,2048,
      2048,2048,2048, 0,0,0, 1.f, nullptr,0, 8, PART);
  k_reduce<<<64, 256, 0, stream>>>(RQ0, PART, 32768L, 7, 1.f);
  gemm_nt_mfma<1,4,1,4><<<dim3(8,1,8), 256, 0, stream>>>(RQW, RQ0, WCGT, 16,2048,2048,
      2048,2048,2048, 0,0,0, 1.f, nullptr,0, 8, PART);
  k_reduce<<<64, 256, 0, stream>>>(RQW, PART, 32768L, 7, 1.f);
  gemm_nt_mfma<1,4,1,4><<<dim3(2,1,256), 256, 0, stream>>>(SREL, RQW, GMIX, 16,288,2048,
      2048,2048,288, 0,589824,4608, SCALE, nullptr,0, 8, PART);
  k_reduce<<<256, 256, 0, stream>>>(SREL, PART, 147456L, 7, SCALE);
  k_softmax_plain<<<512, 256, 0, stream>>>(SREL, 288);
  k_pv<<<dim3(8,32,2), 256, 16*144*4, stream>>>(F_REL, PART, SREL, 4608, 288,
      GMIX, 589824, nullptr);
  k_reduce<<<1024, 256, 0, stream>>>(F_REL, PART, 1048576L, 1, 1.f);

  // ---- deltaor (decomposed LN algebra) ----
  k_rowstats<<<512, 256, 0, stream>>>(F_REL, 2048, 2048, MU_FR, M2_FR);
  k_ln_apply<<<dim3(8,512), 256, 0, stream>>>(F_REL, MU_FR, M2_FR, QLN);
  k_meanx<<<dim3(8,32), 256, 0, stream>>>(F_REL, MEANX);
  k_rowstats<<<32,   256, 0, stream>>>(MEANX, 2048, 2048, MU_M, M2_M);
  k_rowstats<<<2048, 256, 0, stream>>>(proto, 2048, 2048, MU_P, M2_P);
  k_rowstats<<<2048, 256, 0, stream>>>(Wdg,   2048, 2048, MU_W, M2_W);
  gemm_nt_mfma<2,4,2,2><<<dim3(16,8,7), 256, 0, stream>>>(RELQ2, QLN, Wdq, 512,2048,2048,
      2048,2048,2048, 0,0,0, 1.f, nullptr,0, 7, PART);
  k_reduce<<<1024, 256, 0, stream>>>(RELQ2, PART, 1048576L, 6, 1.f);
  gemm_nt_mfma<1,4,1,4><<<dim3(8,2,8), 256, 0, stream>>>(PM, MEANX, proto, 32,2048,2048,
      2048,2048,2048, 0,0,0, 1.f, nullptr,0, 8, PART);
  k_reduce<<<256, 256, 0, stream>>>(PM, PART, 65536L, 7, 1.f);
  k_sigma<<<dim3(8,32), 256, 0, stream>>>(PM, MU_P, M2_P, MU_M, M2_M, SIGMA);
  gemm_nt_mfma<2,4,2,2><<<dim3(16,32,2), 256, 0, stream>>>(P, proto, Wdg, 2048,2048,2048,
      2048,2048,2048, 0,0,0, 1.f, nullptr,0, 2, PART);
  k_reduce<<<1024, 256, 0, stream>>>(P, PART, 4194304L, 1, 1.f);
  k_fixrow<<<dim3(8,2048), 256, 0, stream>>>(P, MU_P, MU_W);
  gemm_nt_mfma<1,4,1,4><<<dim3(8,2,8), 256, 0, stream>>>(MX, MEANX, Wdg, 32,2048,2048,
      2048,2048,2048, 0,0,0, 1.f, nullptr,0, 8, PART);
  k_reduce<<<256, 256, 0, stream>>>(MX, PART, 65536L, 7, 1.f);
  k_fixrow<<<dim3(8,32), 256, 0, stream>>>(MX, MU_M, MU_W);
  gemm_nt_mfma<2,4,2,2><<<dim3(16,8,7), 256, 0, stream>>>(QP, RELQ2, P, 512,2048,2048,
      2048,2048,2048, 0,0,0, 1.f, nullptr,0, 7, PART);
  k_reduce<<<1024, 256, 0, stream>>>(QP, PART, 1048576L, 6, 1.f);
  k_qm<<<512, 256, 0, stream>>>(RELQ2, MX, QM);
  k_score2<<<512, 256, 0, stream>>>(QP, QM, SIGMA, MU_P, W1, WMU, SCALE);
  gemm_nt_mfma<2,4,2,2><<<dim3(16,8,7), 256, 0, stream>>>(OUT2, QP, PROTOT, 512,2048,2048,
      2048,2048,2048, 0,0,0, 1.f, nullptr,0, 7, PART);
  k_reduce<<<1024, 256, 0, stream>>>(OUT2, PART, 1048576L, 6, 1.f);
  k_wsoft<<<1, 64, 0, stream>>>(weights, WSM);
  k_fpro_final<<<dim3(8,512), 256, 0, stream>>>(F_REL, OUT2, MEANX, MU_M, W1, WMU, WSM,
                                                FPRO, F_PRO);

  // ---- f_rec ----
  gemm_nt_mfma<2,4,2,2><<<dim3(16,8,7), 256, 0, stream>>>(RQ2, FPRO, Wcq, 512,2048,2048,
      2048,2048,2048, 0,0,0, 1.f, nullptr,0, 7, PART);
  k_reduce<<<1024, 256, 0, stream>>>(RQ2, PART, 1048576L, 6, 1.f);
  gemm_nt_mfma<2,4,2,2><<<dim3(16,8,7), 256, 0, stream>>>(RQW2, RQ2, WCGT, 512,2048,2048,
      2048,2048,2048, 0,0,0, 1.f, nullptr,0, 7, PART);
  k_reduce<<<1024, 256, 0, stream>>>(RQW2, PART, 1048576L, 6, 1.f);
  gemm_nt_mfma<1,4,1,4><<<dim3(2,1,256), 256, 0, stream>>>(SREC, RQW2, GMIX, 16,288,2048,
      2048,2048,288, 32768,589824,4608, SCALE, nullptr,0, 8, PART);
  k_reduce<<<256, 256, 0, stream>>>(SREC, PART, 147456L, 7, SCALE);
  k_softmax_plain<<<512, 256, 0, stream>>>(SREC, 288);
  k_pv<<<dim3(8,32,2), 256, 16*144*4, stream>>>(F_REC, PART, SREC, 4608, 288,
      GMIX, 589824, nullptr);
  k_reduce<<<1024, 256, 0, stream>>>(F_REC, PART, 1048576L, 1, 1.f);

  // ---- f_cor ----
  gemm_nt_mfma<1,4,1,4><<<dim3(1,32,8), 256, 0, stream>>>(CC, RQW2, CAMB, 512,32,2048,
      2048,2048,32, 0,0,0, 1.f, nullptr,0, 8, PART);
  k_reduce<<<64, 256, 0, stream>>>(CC, PART, 16384L, 7, 1.f);
  gemm_nt_mfma<1,4,1,4><<<dim3(5,1,128), 256, 0, stream>>>(SCOR, RQW2, GMIX, 16,1152,2048,
      2048,2048,1152, 32768,0,18432, SCALE, GIDX,1152, 4, PART);
  k_reduce<<<512, 256, 0, stream>>>(SCOR, PART, 589824L, 3, SCALE);
  k_softmax_seg<<<512, 256, 0, stream>>>(SCOR, CC, SB, SCALE);
  k_pv<<<dim3(8,32,2), 256, 16*576*4, stream>>>(F_COR, PART, SCOR, 18432, 1152,
      GMIX, 589824, SB);
  k_reduce<<<1024, 256, 0, stream>>>(F_COR, PART, 1048576L, 1, 1.f);
}

// Round 6
// 1102.900 us; speedup vs baseline: 3.6951x; 1.0438x over previous
//
#include <hip/hip_runtime.h>
#include <math.h>

// B=32, C=2048, N=288(==PATCH), Q=16, proto tokens=2048
static constexpr float SCALE = 0.022097086912079612f; // 2048^-0.5

typedef __bf16 bf16x4 __attribute__((ext_vector_type(4)));
typedef __bf16 bf16x8 __attribute__((ext_vector_type(8)));
typedef float  f32x4  __attribute__((ext_vector_type(4)));

// ---------------- reduction helpers ----------------
__device__ __forceinline__ float wred_sum(float v){
  #pragma unroll
  for (int o=32;o>0;o>>=1) v += __shfl_down(v,o,64);
  return v;
}
__device__ __forceinline__ float wred_max(float v){
  #pragma unroll
  for (int o=32;o>0;o>>=1) v = fmaxf(v, __shfl_down(v,o,64));
  return v;
}
__device__ __forceinline__ float block_sum(float v, float* red){
  int tid=threadIdx.x, w=tid>>6, l=tid&63, nw=(int)(blockDim.x>>6);
  v = wred_sum(v);
  __syncthreads();
  if (l==0) red[w]=v;
  __syncthreads();
  float r=0.f;
  for (int i=0;i<nw;i++) r += red[i];
  return r;
}
__device__ __forceinline__ float block_max(float v, float* red){
  int tid=threadIdx.x, w=tid>>6, l=tid&63, nw=(int)(blockDim.x>>6);
  v = wred_max(v);
  __syncthreads();
  if (l==0) red[w]=v;
  __syncthreads();
  float r=red[0];
  for (int i=1;i<nw;i++) r = fmaxf(r, red[i]);
  return r;
}

// ---------------- MFMA split-bf16 NT GEMM with split-K ----------------
template<int MT, int NT, int WM, int WN>
__global__ __launch_bounds__(256, 2)
void gemm_nt_mfma(float* __restrict__ Cm, const float* __restrict__ Am,
                  const float* __restrict__ Bm, int M, int N, int K,
                  int lda, int ldb, int ldc, long sA, long sB, long sC,
                  float alpha, const int* __restrict__ browidx, long sBrow,
                  int KS, float* __restrict__ Part)
{
  constexpr int BM = MT*16*WM;
  constexpr int BN = NT*16*WN;
  constexpr int LDH = 40;
  constexpr int AST = (BM+31)/32;
  constexpr int BST = (BN+31)/32;
  __shared__ __bf16 Ah[BM*LDH];
  __shared__ __bf16 Al[BM*LDH];
  __shared__ __bf16 Bh[BN*LDH];
  __shared__ __bf16 Bl[BN*LDH];
  int ZZ = gridDim.z / KS;
  int z  = blockIdx.z % ZZ;
  int ks = blockIdx.z / ZZ;
  const float* A = Am + (long)z*sA;
  const float* B = Bm + (long)z*sB;
  float* C = Cm + (long)z*sC;
  const bool useB = (browidx != nullptr);
  const int* brow = useB ? (browidx + (long)z*sBrow) : nullptr;
  int Kc = ((K + KS*32 - 1) / (KS*32)) * 32;
  int kbeg = ks*Kc;
  int kend = min(K, kbeg + Kc);
  int m0 = blockIdx.y*BM, n0 = blockIdx.x*BN;
  int t = threadIdx.x;
  int srow = t>>3, skoff = (t&7)*4;

  float4 areg[AST], breg[BST];
  auto loadAB = [&](int k0){
    #pragma unroll
    for (int s=0;s<AST;++s){
      int row = srow + 32*s; int gm = m0+row;
      areg[s] = make_float4(0.f,0.f,0.f,0.f);
      if (row < BM && gm < M) areg[s] = *(const float4*)(A + (long)gm*lda + k0 + skoff);
    }
    #pragma unroll
    for (int s=0;s<BST;++s){
      int row = srow + 32*s; int gn = n0+row;
      breg[s] = make_float4(0.f,0.f,0.f,0.f);
      if (row < BN && gn < N){
        long r = useB ? (long)brow[gn] : (long)gn;
        breg[s] = *(const float4*)(B + r*ldb + k0 + skoff);
      }
    }
  };
  auto writeLDS = [&](){
    #pragma unroll
    for (int s=0;s<AST;++s){
      int row = srow + 32*s;
      if (row < BM){
        float vv[4] = {areg[s].x, areg[s].y, areg[s].z, areg[s].w};
        bf16x4 hv, lv;
        #pragma unroll
        for (int e=0;e<4;++e){
          __bf16 h = (__bf16)vv[e];
          hv[e] = h;
          lv[e] = (__bf16)(vv[e] - (float)h);
        }
        *(bf16x4*)&Ah[row*LDH + skoff] = hv;
        *(bf16x4*)&Al[row*LDH + skoff] = lv;
      }
    }
    #pragma unroll
    for (int s=0;s<BST;++s){
      int row = srow + 32*s;
      if (row < BN){
        float vv[4] = {breg[s].x, breg[s].y, breg[s].z, breg[s].w};
        bf16x4 hv, lv;
        #pragma unroll
        for (int e=0;e<4;++e){
          __bf16 h = (__bf16)vv[e];
          hv[e] = h;
          lv[e] = (__bf16)(vv[e] - (float)h);
        }
        *(bf16x4*)&Bh[row*LDH + skoff] = hv;
        *(bf16x4*)&Bl[row*LDH + skoff] = lv;
      }
    }
  };

  int lane = t & 63, wid = t >> 6;
  int wm = (WM==1) ? 0 : (wid / WN);
  int wn = wid % WN;
  int mw = wm*MT*16, nw = wn*NT*16;
  int fr = lane & 15, fq = (lane>>4)*8;

  f32x4 acc[MT][NT];
  #pragma unroll
  for (int i=0;i<MT;++i)
    #pragma unroll
    for (int j=0;j<NT;++j) acc[i][j] = (f32x4){0.f,0.f,0.f,0.f};

  if (kbeg < kend) loadAB(kbeg);
  for (int k0=kbeg; k0<kend; k0+=32){
    writeLDS();
    __syncthreads();
    if (k0+32 < kend) loadAB(k0+32);
    bf16x8 ah[MT], al[MT], bh[NT], bl[NT];
    #pragma unroll
    for (int i=0;i<MT;++i){
      ah[i] = *(const bf16x8*)&Ah[(mw+i*16+fr)*LDH + fq];
      al[i] = *(const bf16x8*)&Al[(mw+i*16+fr)*LDH + fq];
    }
    #pragma unroll
    for (int j=0;j<NT;++j){
      bh[j] = *(const bf16x8*)&Bh[(nw+j*16+fr)*LDH + fq];
      bl[j] = *(const bf16x8*)&Bl[(nw+j*16+fr)*LDH + fq];
    }
    #pragma unroll
    for (int i=0;i<MT;++i)
      #pragma unroll
      for (int j=0;j<NT;++j){
        acc[i][j] = __builtin_amdgcn_mfma_f32_16x16x32_bf16(ah[i], bh[j], acc[i][j], 0,0,0);
        acc[i][j] = __builtin_amdgcn_mfma_f32_16x16x32_bf16(ah[i], bl[j], acc[i][j], 0,0,0);
        acc[i][j] = __builtin_amdgcn_mfma_f32_16x16x32_bf16(al[i], bh[j], acc[i][j], 0,0,0);
      }
    __syncthreads();
  }
  float wf = (KS==1) ? alpha : 1.f;
  float* Cw = C; int ldw = ldc;
  if (ks > 0){ Cw = Part + ((long)(ks-1)*ZZ + z)*(long)M*N; ldw = N; }
  int er = (lane>>4)*4, ec = lane & 15;
  #pragma unroll
  for (int i=0;i<MT;++i){
    int mbase = m0 + mw + i*16 + er;
    #pragma unroll
    for (int r=0;r<4;++r){
      int mm = mbase + r;
      if (mm < M){
        long cro = (long)mm*ldw;
        #pragma unroll
        for (int j=0;j<NT;++j){
          int nn = n0 + nw + j*16 + ec;
          if (nn < N) Cw[cro + nn] = wf*acc[i][j][r];
        }
      }
    }
  }
}

// C[i] = alpha * (C[i] + sum_s Part[s*total + i])
__global__ __launch_bounds__(256) void k_reduce(float* __restrict__ C, const float* __restrict__ Part,
                                                long total, int S, float alpha){
  for (long i = (long)blockIdx.x*blockDim.x + threadIdx.x; i < total;
       i += (long)gridDim.x*blockDim.x){
    float v = C[i];
    for (int s=0;s<S;++s) v += Part[(long)s*total + i];
    C[i] = alpha*v;
  }
}

// ---------------- fused skinny PV v2 ----------------
// C[b][16][2048] = P[b][16][K] . G[rows][2048]; 4 cols/thread (float4),
// split-K chunks of Kc (mult of 4), segment-walk pointers (no per-iter div).
// ks==0 -> C, ks>0 -> Part slice (ks-1), each slice [32][16][2048].
__global__ __launch_bounds__(256, 2) void k_pv(
    float* __restrict__ C, float* __restrict__ Part,
    const float* __restrict__ Pm, long sP, int K, int Kc,
    const float* __restrict__ G, long sG, const int* __restrict__ SB)
{
  extern __shared__ float Pl[];   // [16][Kc]
  int b = blockIdx.y, ks = blockIdx.z;
  int kbeg = ks * Kc;
  int kend = min(K, kbeg + Kc);
  int len = kend - kbeg;
  int c0 = blockIdx.x*1024 + threadIdx.x*4;
  const float* Pb = Pm + (long)b*sP;
  for (int i = threadIdx.x; i < 16*len; i += 256){
    int q = i / len, kk = i - q*len;
    Pl[q*Kc + kk] = Pb[(long)q*K + kbeg + kk];
  }
  __syncthreads();
  f32x4 acc[16];
  #pragma unroll
  for (int q=0;q<16;++q) acc[q] = (f32x4){0.f,0.f,0.f,0.f};
  int kk = 0;
  while (kk < len){
    int kg = kbeg + kk;
    int seg = kg / 288;
    int row = kg - seg*288;
    int nrow = min(288 - row, len - kk);
    const float* gp = (SB ? (G + (long)SB[(b<<2)+seg]*sG) : (G + (long)b*sG))
                      + (long)row*2048 + c0;
    for (int r = 0; r < nrow; r += 4, kk += 4){
      f32x4 g0 = *(const f32x4*)(gp);
      f32x4 g1 = *(const f32x4*)(gp + 2048);
      f32x4 g2 = *(const f32x4*)(gp + 4096);
      f32x4 g3 = *(const f32x4*)(gp + 6144);
      gp += 8192;
      #pragma unroll
      for (int q=0;q<16;++q){
        f32x4 p = *(const f32x4*)&Pl[q*Kc + kk];
        acc[q] += p[0]*g0;
        acc[q] += p[1]*g1;
        acc[q] += p[2]*g2;
        acc[q] += p[3]*g3;
      }
    }
  }
  float* Cw = (ks==0) ? C : (Part + (long)(ks-1)*1048576);
  long obase = (long)b*32768 + c0;
  #pragma unroll
  for (int q=0;q<16;++q) *(f32x4*)&Cw[obase + (long)q*2048] = acc[q];
}

// ---------------- small kernels ----------------
__global__ void k_tr(const float* __restrict__ in, float* __restrict__ out, int R, int C){
  __shared__ float tile[32][33];
  long zo = (long)blockIdx.z * R * C;
  int r0 = blockIdx.y*32, c0 = blockIdx.x*32;
  int tx = threadIdx.x, ty = threadIdx.y;
  #pragma unroll
  for (int j=0;j<32;j+=8)
    tile[ty+j][tx] = in[zo + (long)(r0+ty+j)*C + c0+tx];
  __syncthreads();
  #pragma unroll
  for (int j=0;j<32;j+=8)
    out[zo + (long)(c0+ty+j)*R + r0+tx] = tile[tx][ty+j];
}

__global__ __launch_bounds__(256) void k_rowstats(const float* __restrict__ X, long ldx, int cols,
                                                  float* __restrict__ mu, float* __restrict__ m2){
  int r = blockIdx.x;
  const float* row = X + (long)r*ldx;
  float s=0.f, s2=0.f;
  for (int c = threadIdx.x*4; c < cols; c += 1024){
    float4 v = *(const float4*)(row+c);
    s  += v.x+v.y+v.z+v.w;
    s2 += v.x*v.x+v.y*v.y+v.z*v.z+v.w*v.w;
  }
  __shared__ float red[8];
  s  = block_sum(s,  red);
  s2 = block_sum(s2, red);
  if (threadIdx.x==0){ mu[r]=s/(float)cols; m2[r]=s2; }
}

__global__ __launch_bounds__(256) void k_softmax_gram(float* __restrict__ S, const float* __restrict__ m2xs){
  int r = blockIdx.x;
  int b = r / 288, p = r % 288;
  float* row = S + (long)r * 288;
  const float* m2 = m2xs + (long)b*288;
  float rp = 1.f / fmaxf(sqrtf(m2[p]), 1e-12f);
  int tid = threadIdx.x;
  __shared__ float red[8];
  float lv[2];
  #pragma unroll
  for (int i=0;i<2;++i){
    int q = tid + i*256;
    lv[i] = (q<288) ? row[q]*rp/fmaxf(sqrtf(m2[q]),1e-12f) : -1e30f;
  }
  float mx = fmaxf(lv[0], lv[1]);
  mx = block_max(mx, red);
  float s = 0.f;
  #pragma unroll
  for (int i=0;i<2;++i){
    int q = tid + i*256;
    float e = (q<288) ? expf(lv[i]-mx) : 0.f;
    lv[i]=e; s+=e;
  }
  s = block_sum(s, red);
  float inv = 1.f/s;
  #pragma unroll
  for (int i=0;i<2;++i){ int q = tid + i*256; if (q<288) row[q]=lv[i]*inv; }
}

__global__ __launch_bounds__(256) void k_softmax_plain(float* __restrict__ X, int L){
  int r = blockIdx.x;
  float* row = X + (long)r * L;
  int tid = threadIdx.x;
  __shared__ float red[8];
  float lv[8];
  #pragma unroll
  for (int i=0;i<8;++i){ int q = tid + i*256; lv[i] = (q<L) ? row[q] : -1e30f; }
  float mx = -1e30f;
  #pragma unroll
  for (int i=0;i<8;++i) mx = fmaxf(mx, lv[i]);
  mx = block_max(mx, red);
  float s = 0.f;
  #pragma unroll
  for (int i=0;i<8;++i){ int q = tid + i*256; float e = (q<L)?expf(lv[i]-mx):0.f; lv[i]=e; s+=e; }
  s = block_sum(s, red);
  float inv = 1.f/s;
  #pragma unroll
  for (int i=0;i<8;++i){ int q = tid + i*256; if (q<L) row[q]=lv[i]*inv; }
}

__global__ __launch_bounds__(256) void k_softmax_seg(float* __restrict__ X, const float* __restrict__ CC,
                                                     const int* __restrict__ SB, float scale){
  int r = blockIdx.x; int b = r>>4;
  float* row = X + (long)r*1152;
  float bias[4];
  #pragma unroll
  for (int j=0;j<4;++j) bias[j] = scale*CC[(long)r*32 + SB[b*4+j]];
  int tid = threadIdx.x;
  __shared__ float red[8];
  float lv[5];
  #pragma unroll
  for (int i=0;i<5;++i){
    int q = tid + i*256;
    lv[i] = (q<1152) ? row[q] + bias[q/288] : -1e30f;
  }
  float mx = -1e30f;
  #pragma unroll
  for (int i=0;i<5;++i) mx = fmaxf(mx, lv[i]);
  mx = block_max(mx, red);
  float s = 0.f;
  #pragma unroll
  for (int i=0;i<5;++i){ int q = tid + i*256; float e = (q<1152)?expf(lv[i]-mx):0.f; lv[i]=e; s+=e; }
  s = block_sum(s, red);
  float inv = 1.f/s;
  #pragma unroll
  for (int i=0;i<5;++i){ int q = tid + i*256; if (q<1152) row[q]=lv[i]*inv; }
}

__global__ void k_ln_apply(const float* __restrict__ X, const float* __restrict__ mu,
                           const float* __restrict__ m2, float* __restrict__ Y){
  int r = blockIdx.y; int c = blockIdx.x*256 + threadIdx.x;
  float m = mu[r];
  float v = m2[r]*(1.f/2048.f) - m*m;
  float inv = rsqrtf(v + 1e-5f);
  long idx = (long)r*2048 + c;
  Y[idx] = (X[idx] - m)*inv;
}

__global__ void k_meanx(const float* __restrict__ frel, float* __restrict__ mx){
  int b = blockIdx.y; int c = blockIdx.x*256 + threadIdx.x;
  const float* base = frel + (long)b*16*2048 + c;
  float s=0.f;
  #pragma unroll
  for (int q=0;q<16;++q) s += base[(long)q*2048];
  mx[(long)b*2048 + c] = s * (1.f/16.f);
}

__global__ void k_sigma(const float* __restrict__ pm, const float* __restrict__ mu_p,
                        const float* __restrict__ m2_p, const float* __restrict__ mu_m,
                        const float* __restrict__ m2_m, float* __restrict__ sigma){
  int b = blockIdx.y; int n = blockIdx.x*256 + threadIdx.x;
  float mp = mu_p[n], mm = mu_m[b];
  float vp = m2_p[n]*(1.f/2048.f) - mp*mp;
  float vm = m2_m[b]*(1.f/2048.f) - mm*mm;
  float cov = pm[(long)b*2048+n]*(1.f/2048.f) - mp*mm;
  sigma[(long)b*2048+n] = sqrtf(fmaxf(vp + vm - 2.f*cov, 0.f) + 1e-5f);
}

__global__ void k_fixrow(float* __restrict__ X, const float* __restrict__ mu_row,
                         const float* __restrict__ mu_w){
  int r = blockIdx.y; int d = blockIdx.x*256 + threadIdx.x;
  X[(long)r*2048 + d] -= mu_row[r] * mu_w[d] * 2048.f;
}

__global__ __launch_bounds__(256) void k_qm(const float* __restrict__ relq2,
                                            const float* __restrict__ Mx, float* __restrict__ qm){
  int r = blockIdx.x; int b = r >> 4;
  const float* a = relq2 + (long)r*2048;
  const float* m = Mx + (long)b*2048;
  float s=0.f;
  for (int c = threadIdx.x*4; c < 2048; c += 1024){
    float4 va=*(const float4*)(a+c), vm=*(const float4*)(m+c);
    s += va.x*vm.x+va.y*vm.y+va.z*vm.z+va.w*vm.w;
  }
  __shared__ float red[8];
  s = block_sum(s, red);
  if (threadIdx.x==0) qm[r]=s;
}

__global__ __launch_bounds__(256) void k_score2(float* __restrict__ QPw, const float* __restrict__ qm,
                                                const float* __restrict__ sigma, const float* __restrict__ mu_p,
                                                float* __restrict__ W1, float* __restrict__ Wmu, float scale){
  int r = blockIdx.x; int b = r >> 4;
  float* row = QPw + (long)r*2048;
  const float* sg = sigma + (long)b*2048;
  int tid = threadIdx.x;
  __shared__ float red[8];
  float qmr = qm[r];
  float lv[8], ls[8];
  #pragma unroll
  for (int i=0;i<8;++i){
    int n = tid + i*256;
    float sgn = sg[n];
    ls[i] = sgn;
    lv[i] = scale * (row[n] - qmr) / sgn;
  }
  float mx = -1e30f;
  #pragma unroll
  for (int i=0;i<8;++i) mx = fmaxf(mx, lv[i]);
  mx = block_max(mx, red);
  float se=0.f, sw=0.f, swm=0.f;
  #pragma unroll
  for (int i=0;i<8;++i){
    int n = tid + i*256;
    float e = expf(lv[i]-mx);
    lv[i] = e; se += e;
    float wv = e/ls[i];
    sw += wv; swm += wv*mu_p[n];
  }
  se  = block_sum(se,  red);
  sw  = block_sum(sw,  red);
  swm = block_sum(swm, red);
  float inv = 1.f/se;
  #pragma unroll
  for (int i=0;i<8;++i){ int n = tid + i*256; row[n] = lv[i]*inv/ls[i]; }
  if (tid==0){ W1[r]=sw*inv; Wmu[r]=swm*inv; }
}

__global__ void k_fpro_final(const float* __restrict__ frel, const float* __restrict__ out2,
                             const float* __restrict__ meanx, const float* __restrict__ mu_m,
                             const float* __restrict__ W1, const float* __restrict__ Wmu,
                             const float* __restrict__ wsm,
                             float* __restrict__ fpro, float* __restrict__ fout){
  int r = blockIdx.y; int c = blockIdx.x*256 + threadIdx.x;
  int b = r >> 4, q = r & 15;
  long idx = (long)r*2048 + c;
  float w1 = W1[r];
  float v = frel[idx] + out2[idx] - meanx[(long)b*2048+c]*w1 - Wmu[r] + mu_m[b]*w1;
  fpro[idx] = v;
  fout[idx] = wsm[q] * v;
}

__global__ void k_camb(const float* __restrict__ cam_table, const int* __restrict__ cam_ids,
                       float* __restrict__ camb){
  int b = blockIdx.y; int c = blockIdx.x*256 + threadIdx.x;
  camb[(long)b*2048 + c] = cam_table[(long)(cam_ids[b]-1)*2048 + c];
}

__global__ void k_wsoft(const float* __restrict__ w, float* __restrict__ wsm){
  if (threadIdx.x==0){
    float mx=-1e30f;
    for (int i=0;i<16;++i) mx=fmaxf(mx,w[i]);
    float e[16], s=0.f;
    for (int i=0;i<16;++i){ e[i]=expf(w[i]-mx); s+=e[i]; }
    for (int i=0;i<16;++i) wsm[i]=e[i]/s;
  }
}

__global__ void k_perm(const void* __restrict__ subp, int* __restrict__ gidx, int* __restrict__ SB){
  __shared__ int perm[32];
  if (threadIdx.x==0){
    const int* pi = (const int*)subp;
    const float* pf = (const float*)subp;
    const unsigned char* pb = (const unsigned char*)subp;
    int sv[32]; bool okI=true, okF=true;
    for (int i=0;i<32;++i){ int v=pi[i]; if (v!=0 && v!=1) okI=false; }
    for (int i=0;i<32;++i){ float f=pf[i]; if (f!=0.f && f!=1.f) okF=false; }
    for (int i=0;i<32;++i){
      if (okI) sv[i]=pi[i];
      else if (okF) sv[i]=(pf[i]!=0.f)?1:0;
      else sv[i]=(pb[i]!=0)?1:0;
    }
    int pos=0;
    for (int i=0;i<32;++i) if (!sv[i]) perm[pos++]=i;
    for (int i=0;i<32;++i) if ( sv[i]) perm[pos++]=i;
  }
  __syncthreads();
  for (int i = threadIdx.x; i < 128; i += blockDim.x){
    int b = i>>2, j = i&3;
    SB[i] = ((perm[b]>>2)<<2) + j;
  }
  for (int idx = threadIdx.x; idx < 32*1152; idx += blockDim.x){
    int b = idx / 1152, rem = idx % 1152, j = rem / 288, n = rem % 288;
    int src = ((perm[b] >> 2) << 2) + j;
    gidx[idx] = src*288 + n;
  }
}

// ---------------- launcher ----------------
extern "C" void kernel_launch(void* const* d_in, const int* in_sizes, int n_in,
                              void* d_out, int out_size, void* d_ws, size_t ws_size,
                              hipStream_t stream) {
  const float* x        = (const float*)d_in[0];   // [32,2048,288]
  const int*   cam_ids  = (const int*)d_in[1];
  const void*  subp     = d_in[2];
  const float* query_v  = (const float*)d_in[3];   // [16,2048]
  const float* proto    = (const float*)d_in[4];   // [2048,2048]
  const float* weights  = (const float*)d_in[5];   // [16]
  const float* cam_tab  = (const float*)d_in[6];   // [6,2048]
  const float* Wcq      = (const float*)d_in[8];
  const float* Wcg      = (const float*)d_in[9];
  const float* Wdq      = (const float*)d_in[10];
  const float* Wdg      = (const float*)d_in[11];
  float* out = (float*)d_out;
  float* ws  = (float*)d_ws;

  size_t o = 0;
  float* XS    = ws + o; o += 18874368;
  float* WCGT  = XS;
  float* PROTOT= XS + 4194304;
  float* P     = XS + 8388608;
  float* PART  = XS + 12582912;     // 6,291,456 floats
  float* GMIX  = ws + o; o += 18874368;
  float* S     = ws + o; o += 2654208;
  float* MU_XS = ws + o; o += 9216;
  float* M2_XS = ws + o; o += 9216;
  float* CAMB  = ws + o; o += 65536;
  float* RQ0   = ws + o; o += 32768;
  float* RQW   = ws + o; o += 32768;
  float* SREL  = ws + o; o += 147456;
  float* MU_FR = ws + o; o += 512;
  float* M2_FR = ws + o; o += 512;
  float* QLN   = ws + o; o += 1048576;
  float* RELQ2 = ws + o; o += 1048576;
  float* MEANX = ws + o; o += 65536;
  float* MU_P  = ws + o; o += 2048;
  float* M2_P  = ws + o; o += 2048;
  float* MU_M  = ws + o; o += 64;
  float* M2_M  = ws + o; o += 64;
  float* MU_W  = ws + o; o += 2048;
  float* M2_W  = ws + o; o += 2048;
  float* PM    = ws + o; o += 65536;
  float* SIGMA = ws + o; o += 65536;
  float* MX    = ws + o; o += 65536;
  float* QP    = ws + o; o += 1048576;
  float* QM    = ws + o; o += 512;
  float* W1    = ws + o; o += 512;
  float* WMU   = ws + o; o += 512;
  float* OUT2  = ws + o; o += 1048576;
  float* FPRO  = ws + o; o += 1048576;
  float* RQ2   = ws + o; o += 1048576;
  float* RQW2  = ws + o; o += 1048576;
  float* SREC  = ws + o; o += 147456;
  float* SCOR  = ws + o; o += 589824;
  float* CC    = ws + o; o += 16384;
  float* WSM   = ws + o; o += 16;
  int*   GIDX  = (int*)(ws + o); o += 36864;
  int*   SB    = (int*)(ws + o); o += 128;

  float* F_REL = out;
  float* F_PRO = out + 1048576;
  float* F_REC = out + 2097152;
  float* F_COR = out + 3145728;

  // ---- Phase A: shared patch self-attention ----
  k_tr<<<dim3(9,64,32), dim3(32,8), 0, stream>>>(x, XS, 2048, 288);
  k_rowstats<<<9216, 256, 0, stream>>>(XS, 2048, 2048, MU_XS, M2_XS);
  gemm_nt_mfma<3,3,2,2><<<dim3(3,3,256), 256, 0, stream>>>(S, XS, XS, 288,288,2048,
      2048,2048,288, 589824,589824,82944, 1.f, nullptr,0, 8, GMIX);
  k_reduce<<<1024, 256, 0, stream>>>(S, GMIX, 2654208L, 7, 1.f);
  k_softmax_gram<<<9216, 256, 0, stream>>>(S, M2_XS);
  gemm_nt_mfma<3,4,2,2><<<dim3(16,3,32), 256, 0, stream>>>(GMIX, S, x, 288,2048,288,
      288,288,2048, 82944,589824,589824, 1.f, nullptr,0, 1, nullptr);
  k_tr<<<dim3(64,64,1), dim3(32,8), 0, stream>>>(Wcg, WCGT, 2048, 2048);
  k_tr<<<dim3(64,64,1), dim3(32,8), 0, stream>>>(proto, PROTOT, 2048, 2048);
  k_camb<<<dim3(8,32), 256, 0, stream>>>(cam_tab, cam_ids, CAMB);
  k_perm<<<1, 256, 0, stream>>>(subp, GIDX, SB);

  // ---- f_rel ----
  gemm_nt_mfma<1,4,1,4><<<dim3(8,1,8), 256, 0, stream>>>(RQ0, query_v, Wcq, 16,2048,2048,
      2048,2048,2048, 0,0,0, 1.f, nullptr,0, 8, PART);
  k_reduce<<<64, 256, 0, stream>>>(RQ0, PART, 32768L, 7, 1.f);
  gemm_nt_mfma<1,4,1,4><<<dim3(8,1,8), 256, 0, stream>>>(RQW, RQ0, WCGT, 16,2048,2048,
      2048,2048,2048, 0,0,0, 1.f, nullptr,0, 8, PART);
  k_reduce<<<64, 256, 0, stream>>>(RQW, PART, 32768L, 7, 1.f);
  gemm_nt_mfma<1,4,1,4><<<dim3(2,1,256), 256, 0, stream>>>(SREL, RQW, GMIX, 16,288,2048,
      2048,2048,288, 0,589824,4608, SCALE, nullptr,0, 8, PART);
  k_reduce<<<256, 256, 0, stream>>>(SREL, PART, 147456L, 7, SCALE);
  k_softmax_plain<<<512, 256, 0, stream>>>(SREL, 288);
  k_pv<<<dim3(2,32,7), 256, 16*44*4, stream>>>(F_REL, PART, SREL, 4608, 288, 44,
      GMIX, 589824, nullptr);
  k_reduce<<<1024, 256, 0, stream>>>(F_REL, PART, 1048576L, 6, 1.f);

  // ---- deltaor (decomposed LN algebra) ----
  k_rowstats<<<512, 256, 0, stream>>>(F_REL, 2048, 2048, MU_FR, M2_FR);
  k_ln_apply<<<dim3(8,512), 256, 0, stream>>>(F_REL, MU_FR, M2_FR, QLN);
  k_meanx<<<dim3(8,32), 256, 0, stream>>>(F_REL, MEANX);
  k_rowstats<<<32,   256, 0, stream>>>(MEANX, 2048, 2048, MU_M, M2_M);
  k_rowstats<<<2048, 256, 0, stream>>>(proto, 2048, 2048, MU_P, M2_P);
  k_rowstats<<<2048, 256, 0, stream>>>(Wdg,   2048, 2048, MU_W, M2_W);
  gemm_nt_mfma<2,4,2,2><<<dim3(16,8,7), 256, 0, stream>>>(RELQ2, QLN, Wdq, 512,2048,2048,
      2048,2048,2048, 0,0,0, 1.f, nullptr,0, 7, PART);
  k_reduce<<<1024, 256, 0, stream>>>(RELQ2, PART, 1048576L, 6, 1.f);
  gemm_nt_mfma<1,4,1,4><<<dim3(8,2,8), 256, 0, stream>>>(PM, MEANX, proto, 32,2048,2048,
      2048,2048,2048, 0,0,0, 1.f, nullptr,0, 8, PART);
  k_reduce<<<256, 256, 0, stream>>>(PM, PART, 65536L, 7, 1.f);
  k_sigma<<<dim3(8,32), 256, 0, stream>>>(PM, MU_P, M2_P, MU_M, M2_M, SIGMA);
  gemm_nt_mfma<2,4,2,2><<<dim3(16,32,2), 256, 0, stream>>>(P, proto, Wdg, 2048,2048,2048,
      2048,2048,2048, 0,0,0, 1.f, nullptr,0, 2, PART);
  k_reduce<<<1024, 256, 0, stream>>>(P, PART, 4194304L, 1, 1.f);
  k_fixrow<<<dim3(8,2048), 256, 0, stream>>>(P, MU_P, MU_W);
  gemm_nt_mfma<1,4,1,4><<<dim3(8,2,8), 256, 0, stream>>>(MX, MEANX, Wdg, 32,2048,2048,
      2048,2048,2048, 0,0,0, 1.f, nullptr,0, 8, PART);
  k_reduce<<<256, 256, 0, stream>>>(MX, PART, 65536L, 7, 1.f);
  k_fixrow<<<dim3(8,32), 256, 0, stream>>>(MX, MU_M, MU_W);
  gemm_nt_mfma<2,4,2,2><<<dim3(16,8,7), 256, 0, stream>>>(QP, RELQ2, P, 512,2048,2048,
      2048,2048,2048, 0,0,0, 1.f, nullptr,0, 7, PART);
  k_reduce<<<1024, 256, 0, stream>>>(QP, PART, 1048576L, 6, 1.f);
  k_qm<<<512, 256, 0, stream>>>(RELQ2, MX, QM);
  k_score2<<<512, 256, 0, stream>>>(QP, QM, SIGMA, MU_P, W1, WMU, SCALE);
  gemm_nt_mfma<2,4,2,2><<<dim3(16,8,7), 256, 0, stream>>>(OUT2, QP, PROTOT, 512,2048,2048,
      2048,2048,2048, 0,0,0, 1.f, nullptr,0, 7, PART);
  k_reduce<<<1024, 256, 0, stream>>>(OUT2, PART, 1048576L, 6, 1.f);
  k_wsoft<<<1, 64, 0, stream>>>(weights, WSM);
  k_fpro_final<<<dim3(8,512), 256, 0, stream>>>(F_REL, OUT2, MEANX, MU_M, W1, WMU, WSM,
                                                FPRO, F_PRO);

  // ---- f_rec ----
  gemm_nt_mfma<2,4,2,2><<<dim3(16,8,7), 256, 0, stream>>>(RQ2, FPRO, Wcq, 512,2048,2048,
      2048,2048,2048, 0,0,0, 1.f, nullptr,0, 7, PART);
  k_reduce<<<1024, 256, 0, stream>>>(RQ2, PART, 1048576L, 6, 1.f);
  gemm_nt_mfma<2,4,2,2><<<dim3(16,8,7), 256, 0, stream>>>(RQW2, RQ2, WCGT, 512,2048,2048,
      2048,2048,2048, 0,0,0, 1.f, nullptr,0, 7, PART);
  k_reduce<<<1024, 256, 0, stream>>>(RQW2, PART, 1048576L, 6, 1.f);
  gemm_nt_mfma<1,4,1,4><<<dim3(2,1,256), 256, 0, stream>>>(SREC, RQW2, GMIX, 16,288,2048,
      2048,2048,288, 32768,589824,4608, SCALE, nullptr,0, 8, PART);
  k_reduce<<<256, 256, 0, stream>>>(SREC, PART, 147456L, 7, SCALE);
  k_softmax_plain<<<512, 256, 0, stream>>>(SREC, 288);
  k_pv<<<dim3(2,32,7), 256, 16*44*4, stream>>>(F_REC, PART, SREC, 4608, 288, 44,
      GMIX, 589824, nullptr);
  k_reduce<<<1024, 256, 0, stream>>>(F_REC, PART, 1048576L, 6, 1.f);

  // ---- f_cor ----
  gemm_nt_mfma<1,4,1,4><<<dim3(1,32,8), 256, 0, stream>>>(CC, RQW2, CAMB, 512,32,2048,
      2048,2048,32, 0,0,0, 1.f, nullptr,0, 8, PART);
  k_reduce<<<64, 256, 0, stream>>>(CC, PART, 16384L, 7, 1.f);
  gemm_nt_mfma<1,4,1,4><<<dim3(5,1,128), 256, 0, stream>>>(SCOR, RQW2, GMIX, 16,1152,2048,
      2048,2048,1152, 32768,0,18432, SCALE, GIDX,1152, 4, PART);
  k_reduce<<<512, 256, 0, stream>>>(SCOR, PART, 589824L, 3, SCALE);
  k_softmax_seg<<<512, 256, 0, stream>>>(SCOR, CC, SB, SCALE);
  k_pv<<<dim3(2,32,7), 256, 16*168*4, stream>>>(F_COR, PART, SCOR, 18432, 1152, 168,
      GMIX, 589824, SB);
  k_reduce<<<1024, 256, 0, stream>>>(F_COR, PART, 1048576L, 6, 1.f);
}